// Round 3
// baseline (848.123 us; speedup 1.0000x reference)
//
#include <hip/hip_runtime.h>

#define Sn 500
#define Dn 10
#define Tn 40
#define FPn 3
#define FTn 512
#define Hn 64
#define G3 192
#define NHn 4

typedef __attribute__((ext_vector_type(8))) short bf8_t;   // 8 x bf16 bits
typedef __attribute__((ext_vector_type(4))) float f4_t;

__device__ __forceinline__ unsigned short f2bf(float f) {
    union { float f; unsigned int u; } v; v.f = f;
    unsigned int r = v.u + 0x7fffu + ((v.u >> 16) & 1u);   // round-to-nearest-even
    return (unsigned short)(r >> 16);
}
__device__ __forceinline__ float bflo(unsigned int u) {
    union { unsigned int u; float f; } v; v.u = u << 16; return v.f;
}
__device__ __forceinline__ float bfhi(unsigned int u) {
    union { unsigned int u; float f; } v; v.u = u & 0xffff0000u; return v.f;
}
__device__ __forceinline__ unsigned int cvtpk(float lo, float hi) {
    unsigned int r;
    asm("v_cvt_pk_bf16_f32 %0, %1, %2" : "=v"(r) : "v"(lo), "v"(hi));
    return r;
}
__device__ __forceinline__ float sigmoidf_(float x) { return 1.f / (1.f + __expf(-x)); }
__device__ __forceinline__ float tanhf_(float x) {
    x = fminf(15.f, fmaxf(-15.f, x));
    float e = __expf(2.f * x);
    return (e - 1.f) / (e + 1.f);
}
__device__ __forceinline__ float dot8(uint4 wv, f4_t hA, f4_t hB) {
    return bflo(wv.x) * hA[0] + bfhi(wv.x) * hA[1]
         + bflo(wv.y) * hA[2] + bfhi(wv.y) * hA[3]
         + bflo(wv.z) * hB[0] + bfhi(wv.z) * hB[1]
         + bflo(wv.w) * hB[2] + bfhi(wv.w) * hB[3];
}
union bfu { bf8_t v; unsigned int u[4]; };

// ---------------------------------------------------------------------------
// gi_gemm2: gi2 = permute(x @ Wih_t + bih_t). Block = (stock, m-half of 200
// rows), 4 waves, n-split 48 cols/wave. A staged as bf16 in LDS (converted
// during staging), reg-prefetch of next k-slice. Output layout is permuted to
// match the gru_fused MFMA C-layout:
//   gi2[((s*40+t)*48 + ntg*4 + (day&3))*64 + (day>>2)*16 + (col&15)]
// ---------------------------------------------------------------------------
__global__ __launch_bounds__(256, 2) void gi_gemm2(
    const float* __restrict__ text, const float* __restrict__ Wih,
    const float* __restrict__ bih, float* __restrict__ gi2)
{
    __shared__ __align__(16) unsigned char Asb[208 * 80];   // 208 rows x 32 k bf16 (pad 40)

    const int blk = blockIdx.x, s = blk >> 1, half = blk & 1;
    const int tid = threadIdx.x, w = tid >> 6, l = tid & 63;
    const int lr = l & 15, lg = l >> 4;

    const float* Wihs = Wih + (size_t)s * FTn * G3;
    const float* xrow = text + ((size_t)s * 400 + half * 200) * FTn;

    if (tid < 160) ((unsigned int*)(Asb + 200 * 80))[tid] = 0u;   // zero pad rows

    f4_t acc[13][3];
    #pragma unroll
    for (int a = 0; a < 13; a++)
        #pragma unroll
        for (int b = 0; b < 3; b++) acc[a][b] = (f4_t){0.f, 0.f, 0.f, 0.f};

    f4_t pa[4], pb[4];
    auto loadT = [&](int kk) {
        #pragma unroll
        for (int r4 = 0; r4 < 4; ++r4) {
            int tsk = tid + r4 * 256;
            if (tsk < 800) {
                int rw = tsk >> 2, ch = tsk & 3;
                const float* p = xrow + (size_t)rw * FTn + kk * 32 + ch * 8;
                pa[r4] = *(const f4_t*)p; pb[r4] = *(const f4_t*)(p + 4);
            }
        }
    };
    auto storeT = [&]() {
        #pragma unroll
        for (int r4 = 0; r4 < 4; ++r4) {
            int tsk = tid + r4 * 256;
            if (tsk < 800) {
                int rw = tsk >> 2, ch = tsk & 3;
                uint4 uu = { cvtpk(pa[r4][0], pa[r4][1]), cvtpk(pa[r4][2], pa[r4][3]),
                             cvtpk(pb[r4][0], pb[r4][1]), cvtpk(pb[r4][2], pb[r4][3]) };
                *(uint4*)(Asb + rw * 80 + ch * 16) = uu;
            }
        }
    };

    loadT(0);
    for (int kk = 0; kk < 16; ++kk) {
        __syncthreads();
        storeT();
        __syncthreads();
        if (kk < 15) loadT(kk + 1);

        bfu bfr[3];
        #pragma unroll
        for (int nc = 0; nc < 3; ++nc) {
            const int col = w * 48 + nc * 16 + lr;
            const float* bp = Wihs + (size_t)(kk * 32 + lg * 8) * G3 + col;
            float b0 = bp[0], b1 = bp[G3], b2 = bp[2 * G3], b3 = bp[3 * G3];
            float b4 = bp[4 * G3], b5 = bp[5 * G3], b6 = bp[6 * G3], b7 = bp[7 * G3];
            bfr[nc].u[0] = cvtpk(b0, b1); bfr[nc].u[1] = cvtpk(b2, b3);
            bfr[nc].u[2] = cvtpk(b4, b5); bfr[nc].u[3] = cvtpk(b6, b7);
        }
        #pragma unroll
        for (int mt = 0; mt < 13; ++mt) {
            bf8_t af = *(const bf8_t*)(Asb + (mt * 16 + lr) * 80 + lg * 16);
            #pragma unroll
            for (int nc = 0; nc < 3; ++nc)
                acc[mt][nc] = __builtin_amdgcn_mfma_f32_16x16x32_bf16(af, bfr[nc].v, acc[mt][nc], 0, 0, 0);
        }
    }

    #pragma unroll
    for (int nc = 0; nc < 3; ++nc) {
        const int col = w * 48 + nc * 16 + lr;
        const int ntg = col >> 4;
        const float bv = bih[(size_t)s * G3 + col];
        #pragma unroll
        for (int mt = 0; mt < 13; ++mt) {
            #pragma unroll
            for (int rg = 0; rg < 4; ++rg) {
                int rl = mt * 16 + lg * 4 + rg;
                if (rl < 200) {
                    int row = half * 200 + rl;
                    int day = row / 40, t = row - day * 40;
                    size_t idx = (((size_t)s * 40 + t) * 48 + ntg * 4 + (day & 3)) * 64
                               + ((day >> 2) << 4) + lr;
                    gi2[idx] = acc[mt][nc][rg] + bv;
                }
            }
        }
    }
}

// ---------------------------------------------------------------------------
// gru_fused: one 64-thread block per stock. Zero block barriers.
// Phase 1: text GRU, 10 days batched in MFMA M-dim; Whh held as 24 B-frags in
//          VGPRs; fused online-softmax attention pooling -> newsL (LDS).
// Phase 2: day-sequence GRU over newsL + pooling -> tvec.
// Phase 3: price GRU + pooling -> xprice.
// ---------------------------------------------------------------------------
__global__ __launch_bounds__(64, 1) void gru_fused(
    const float* __restrict__ gi2, const float* __restrict__ Whh,
    const float* __restrict__ bhh, const float* __restrict__ Wa,
    const float* __restrict__ va,
    const float* __restrict__ Wih_s, const float* __restrict__ Whh_s,
    const float* __restrict__ bih_s, const float* __restrict__ bhh_s,
    const float* __restrict__ Wa_s, const float* __restrict__ va_s,
    const float* __restrict__ price, const float* __restrict__ Wih_p,
    const float* __restrict__ Whh_p, const float* __restrict__ bih_p,
    const float* __restrict__ bhh_p, const float* __restrict__ Wa_p,
    const float* __restrict__ va_p,
    float* __restrict__ tvec, float* __restrict__ xprice)
{
    __shared__ __align__(16) unsigned char sm[60928];
    float* hrow = (float*)sm;                         // p1: [16][68] f32
    unsigned char* waT = sm + 4608;                   // p1: Wa^T bf16 swz [64][128B]
    unsigned char* whh2 = sm;                         // p2/p3: [192][128B]
    unsigned char* wih2 = sm + 24576;                 // p2: [192][128B]
    unsigned char* wa2 = sm + 49152;                  // p2/p3: [64][128B]
    float* newsL = (float*)(sm + 57600);              // [10][68] f32
    float* hbuf  = (float*)(sm + 60320);              // [68] f32
    float* priceL = (float*)(sm + 60608);             // [30] f32

    const int s = blockIdx.x, l = threadIdx.x;
    const int lr = l & 15, lg = l >> 4;

    // ---------------- phase 1: text GRU ----------------
    const float* Whhs = Whh + (size_t)s * Hn * G3;
    bfu bwhh[2][12];
    #pragma unroll
    for (int ks = 0; ks < 2; ++ks)
        #pragma unroll
        for (int nt = 0; nt < 12; ++nt) {
            const float* p = Whhs + (size_t)(ks * 32 + lg * 8) * G3 + nt * 16 + lr;
            float b0 = p[0], b1 = p[G3], b2 = p[2 * G3], b3 = p[3 * G3];
            float b4 = p[4 * G3], b5 = p[5 * G3], b6 = p[6 * G3], b7 = p[7 * G3];
            bwhh[ks][nt].u[0] = cvtpk(b0, b1); bwhh[ks][nt].u[1] = cvtpk(b2, b3);
            bwhh[ks][nt].u[2] = cvtpk(b4, b5); bwhh[ks][nt].u[3] = cvtpk(b6, b7);
        }
    float bhh_l[12];
    #pragma unroll
    for (int nt = 0; nt < 12; ++nt) bhh_l[nt] = bhh[(size_t)s * G3 + nt * 16 + lr];
    float va_l[4];
    #pragma unroll
    for (int nt = 0; nt < 4; ++nt) va_l[nt] = va[(size_t)s * Hn + nt * 16 + lr];

    {   // stage Wa^T bf16 swizzled; zero hrow
        const float* Was = Wa + (size_t)s * Hn * Hn;
        for (int r = 0; r < 64; ++r) {
            int e = l + r * 64, i = e >> 6, k = e & 63;
            *(unsigned short*)(waT + k * 128 + ((2 * i) ^ ((k & 7) << 4))) = f2bf(Was[e]);
        }
        #pragma unroll
        for (int r = 0; r < 17; ++r) hrow[l + r * 64] = 0.f;
    }
    __builtin_amdgcn_wave_barrier();

    float val[48], valn[48];
    {
        const float* gb = gi2 + (size_t)s * 40 * 3072 + l;
        #pragma unroll
        for (int j = 0; j < 48; ++j) val[j] = gb[j * 64];
    }
    bf8_t a0f, a1f;
    {   bfu z0; z0.u[0] = 0; z0.u[1] = 0; z0.u[2] = 0; z0.u[3] = 0; a0f = z0.v; a1f = z0.v; }

    float h[4][4], accv[4][4], den[4], m[4];
    #pragma unroll
    for (int nt = 0; nt < 4; ++nt)
        #pragma unroll
        for (int rr = 0; rr < 4; ++rr) { h[nt][rr] = 0.f; accv[nt][rr] = 0.f; }
    #pragma unroll
    for (int rr = 0; rr < 4; ++rr) { den[rr] = 0.f; m[rr] = -1e30f; }

    for (int t = 0; t < Tn; ++t) {
        // gh = bhh + h_{t-1} @ Whh (MFMA over 12 n-tiles)
        f4_t acc[12];
        #pragma unroll
        for (int nt = 0; nt < 12; ++nt)
            acc[nt] = (f4_t){bhh_l[nt], bhh_l[nt], bhh_l[nt], bhh_l[nt]};
        #pragma unroll
        for (int nt = 0; nt < 12; ++nt) {
            acc[nt] = __builtin_amdgcn_mfma_f32_16x16x32_bf16(a0f, bwhh[0][nt].v, acc[nt], 0, 0, 0);
            acc[nt] = __builtin_amdgcn_mfma_f32_16x16x32_bf16(a1f, bwhh[1][nt].v, acc[nt], 0, 0, 0);
        }
        // prefetch next step's gi (hidden under gates)
        {
            const int tn = (t < Tn - 1) ? t + 1 : t;
            const float* gb = gi2 + ((size_t)s * 40 + tn) * 3072 + l;
            #pragma unroll
            for (int j = 0; j < 48; ++j) valn[j] = gb[j * 64];
        }
        // gates
        #pragma unroll
        for (int nt = 0; nt < 4; ++nt)
            #pragma unroll
            for (int rr = 0; rr < 4; ++rr) {
                float r = sigmoidf_(val[nt * 4 + rr] + acc[nt][rr]);
                float z = sigmoidf_(val[(nt + 4) * 4 + rr] + acc[nt + 4][rr]);
                float n = tanhf_(val[(nt + 8) * 4 + rr] + r * acc[nt + 8][rr]);
                h[nt][rr] = (1.f - z) * n + z * h[nt][rr];
            }
        // store h_t, rebuild A-frags
        __builtin_amdgcn_wave_barrier();
        #pragma unroll
        for (int rr = 0; rr < 4; ++rr) {
            int day = lg * 4 + rr;
            if (day < Dn) {
                #pragma unroll
                for (int nt = 0; nt < 4; ++nt) hrow[day * 68 + nt * 16 + lr] = h[nt][rr];
            }
        }
        __builtin_amdgcn_wave_barrier();
        {
            const float* hp = hrow + lr * 68 + lg * 8;
            f4_t x0 = *(const f4_t*)hp,        x1 = *(const f4_t*)(hp + 4);
            f4_t y0 = *(const f4_t*)(hp + 32), y1 = *(const f4_t*)(hp + 36);
            bfu t0, t1;
            t0.u[0] = cvtpk(x0[0], x0[1]); t0.u[1] = cvtpk(x0[2], x0[3]);
            t0.u[2] = cvtpk(x1[0], x1[1]); t0.u[3] = cvtpk(x1[2], x1[3]);
            t1.u[0] = cvtpk(y0[0], y0[1]); t1.u[1] = cvtpk(y0[2], y0[3]);
            t1.u[2] = cvtpk(y1[0], y1[1]); t1.u[3] = cvtpk(y1[2], y1[3]);
            a0f = t0.v; a1f = t1.v;
        }
        // scores: u = h_t @ Wa (MFMA), term = sum_k tanh(u_k)*va_k
        f4_t sc[4];
        #pragma unroll
        for (int nt = 0; nt < 4; ++nt) sc[nt] = (f4_t){0.f, 0.f, 0.f, 0.f};
        #pragma unroll
        for (int ks = 0; ks < 2; ++ks) {
            bf8_t av = ks ? a1f : a0f;
            #pragma unroll
            for (int nt = 0; nt < 4; ++nt) {
                bf8_t bwv = *(const bf8_t*)(waT + (nt * 16 + lr) * 128
                                            + ((ks * 64 + lg * 16) ^ ((lr & 7) << 4)));
                sc[nt] = __builtin_amdgcn_mfma_f32_16x16x32_bf16(av, bwv, sc[nt], 0, 0, 0);
            }
        }
        float pr[4];
        #pragma unroll
        for (int rr = 0; rr < 4; ++rr) {
            pr[rr] = tanhf_(sc[0][rr]) * va_l[0] + tanhf_(sc[1][rr]) * va_l[1]
                   + tanhf_(sc[2][rr]) * va_l[2] + tanhf_(sc[3][rr]) * va_l[3];
            pr[rr] += __shfl_xor(pr[rr], 1);
            pr[rr] += __shfl_xor(pr[rr], 2);
            pr[rr] += __shfl_xor(pr[rr], 4);
            pr[rr] += __shfl_xor(pr[rr], 8);
        }
        #pragma unroll
        for (int rr = 0; rr < 4; ++rr) {
            float mn = fmaxf(m[rr], pr[rr]);
            float s0 = __expf(m[rr] - mn);
            float p = __expf(pr[rr] - mn);
            den[rr] = den[rr] * s0 + p;
            #pragma unroll
            for (int nt = 0; nt < 4; ++nt)
                accv[nt][rr] = accv[nt][rr] * s0 + p * h[nt][rr];
            m[rr] = mn;
        }
        #pragma unroll
        for (int j = 0; j < 48; ++j) val[j] = valn[j];
    }
    // pooled news -> LDS
    #pragma unroll
    for (int rr = 0; rr < 4; ++rr) {
        int day = lg * 4 + rr;
        if (day < Dn) {
            float inv = 1.f / den[rr];
            #pragma unroll
            for (int nt = 0; nt < 4; ++nt)
                newsL[day * 68 + nt * 16 + lr] = accv[nt][rr] * inv;
        }
    }
    __builtin_amdgcn_wave_barrier();

    // ---------------- phase 2: day-sequence GRU -> tvec ----------------
    {
        const float* W2 = Whh_s + (size_t)s * Hn * G3;
        const float* X2 = Wih_s + (size_t)s * Hn * G3;
        for (int r = 0; r < 192; ++r) {
            int e = l + r * 64, i = e / G3, j = e - i * G3;
            int off = j * 128 + ((2 * i) ^ ((j & 7) << 4));
            *(unsigned short*)(whh2 + off) = f2bf(W2[e]);
            *(unsigned short*)(wih2 + off) = f2bf(X2[e]);
        }
        const float* A2 = Wa_s + (size_t)s * Hn * Hn;
        for (int r = 0; r < 64; ++r) {
            int e = l + r * 64, i = e >> 6, k = e & 63;
            *(unsigned short*)(wa2 + k * 128 + ((2 * i) ^ ((k & 7) << 4))) = f2bf(A2[e]);
        }
        hbuf[l] = 0.f;
        if (l < 4) hbuf[64 + l] = 0.f;
    }
    __builtin_amdgcn_wave_barrier();
    {
        const float bi0 = bih_s[(size_t)s * G3 + l];
        const float bi1 = bih_s[(size_t)s * G3 + 64 + l];
        const float bi2 = bih_s[(size_t)s * G3 + 128 + l];
        const float bh0 = bhh_s[(size_t)s * G3 + l];
        const float bh1 = bhh_s[(size_t)s * G3 + 64 + l];
        const float bh2 = bhh_s[(size_t)s * G3 + 128 + l];
        const float vak = va_s[(size_t)s * Hn + l];
        const int swl = (l & 7) << 4;
        float h2 = 0.f, m2 = -1e30f, den2 = 0.f, av2 = 0.f;
        for (int t = 0; t < Dn; ++t) {
            float gh0 = bh0, gh1 = bh1, gh2 = bh2;
            float gg0 = bi0, gg1 = bi1, gg2 = bi2;
            #pragma unroll
            for (int ic = 0; ic < 8; ++ic) {
                const int off = (ic * 16) ^ swl;
                f4_t hA = *(const f4_t*)&hbuf[ic * 8];
                f4_t hB = *(const f4_t*)&hbuf[ic * 8 + 4];
                f4_t nA = *(const f4_t*)&newsL[t * 68 + ic * 8];
                f4_t nB = *(const f4_t*)&newsL[t * 68 + ic * 8 + 4];
                uint4 w0 = *(const uint4*)(whh2 + l * 128 + off);
                uint4 w1 = *(const uint4*)(whh2 + (l + 64) * 128 + off);
                uint4 w2 = *(const uint4*)(whh2 + (l + 128) * 128 + off);
                uint4 x0 = *(const uint4*)(wih2 + l * 128 + off);
                uint4 x1 = *(const uint4*)(wih2 + (l + 64) * 128 + off);
                uint4 x2 = *(const uint4*)(wih2 + (l + 128) * 128 + off);
                gh0 += dot8(w0, hA, hB); gh1 += dot8(w1, hA, hB); gh2 += dot8(w2, hA, hB);
                gg0 += dot8(x0, nA, nB); gg1 += dot8(x1, nA, nB); gg2 += dot8(x2, nA, nB);
            }
            float r = sigmoidf_(gg0 + gh0);
            float z = sigmoidf_(gg1 + gh1);
            float n = tanhf_(gg2 + r * gh2);
            h2 = (1.f - z) * n + z * h2;
            __builtin_amdgcn_wave_barrier();
            hbuf[l] = h2;
            __builtin_amdgcn_wave_barrier();
            float sk = 0.f;
            #pragma unroll
            for (int ic = 0; ic < 8; ++ic) {
                const int off = (ic * 16) ^ swl;
                uint4 wv = *(const uint4*)(wa2 + l * 128 + off);
                f4_t hA = *(const f4_t*)&hbuf[ic * 8];
                f4_t hB = *(const f4_t*)&hbuf[ic * 8 + 4];
                sk += dot8(wv, hA, hB);
            }
            float term = tanhf_(sk) * vak;
            #pragma unroll
            for (int off = 32; off; off >>= 1) term += __shfl_xor(term, off);
            float mn = fmaxf(m2, term);
            float s0 = __expf(m2 - mn);
            float p = __expf(term - mn);
            den2 = den2 * s0 + p;
            av2 = av2 * s0 + p * h2;
            m2 = mn;
        }
        tvec[(size_t)s * Hn + l] = av2 / den2;
    }
    __builtin_amdgcn_wave_barrier();

    // ---------------- phase 3: price GRU -> xprice ----------------
    {
        const float* W3 = Whh_p + (size_t)s * Hn * G3;
        for (int r = 0; r < 192; ++r) {
            int e = l + r * 64, i = e / G3, j = e - i * G3;
            *(unsigned short*)(whh2 + j * 128 + ((2 * i) ^ ((j & 7) << 4))) = f2bf(W3[e]);
        }
        const float* A3 = Wa_p + (size_t)s * Hn * Hn;
        for (int r = 0; r < 64; ++r) {
            int e = l + r * 64, i = e >> 6, k = e & 63;
            *(unsigned short*)(wa2 + k * 128 + ((2 * i) ^ ((k & 7) << 4))) = f2bf(A3[e]);
        }
        if (l < 30) priceL[l] = price[(size_t)s * 30 + l];
        hbuf[l] = 0.f;
        if (l < 4) hbuf[64 + l] = 0.f;
    }
    __builtin_amdgcn_wave_barrier();
    {
        float wp[3][3];
        #pragma unroll
        for (int i = 0; i < 3; ++i)
            #pragma unroll
            for (int g = 0; g < 3; ++g)
                wp[i][g] = Wih_p[(size_t)s * 3 * G3 + i * G3 + g * 64 + l];
        const float bi0 = bih_p[(size_t)s * G3 + l];
        const float bi1 = bih_p[(size_t)s * G3 + 64 + l];
        const float bi2 = bih_p[(size_t)s * G3 + 128 + l];
        const float bh0 = bhh_p[(size_t)s * G3 + l];
        const float bh1 = bhh_p[(size_t)s * G3 + 64 + l];
        const float bh2 = bhh_p[(size_t)s * G3 + 128 + l];
        const float vak = va_p[(size_t)s * Hn + l];
        const int swl = (l & 7) << 4;
        float h3 = 0.f, m3 = -1e30f, den3 = 0.f, av3 = 0.f;
        for (int t = 0; t < Dn; ++t) {
            float x0 = priceL[t * 3], x1 = priceL[t * 3 + 1], x2 = priceL[t * 3 + 2];
            float gg0 = bi0 + x0 * wp[0][0] + x1 * wp[1][0] + x2 * wp[2][0];
            float gg1 = bi1 + x0 * wp[0][1] + x1 * wp[1][1] + x2 * wp[2][1];
            float gg2 = bi2 + x0 * wp[0][2] + x1 * wp[1][2] + x2 * wp[2][2];
            float gh0 = bh0, gh1 = bh1, gh2 = bh2;
            #pragma unroll
            for (int ic = 0; ic < 8; ++ic) {
                const int off = (ic * 16) ^ swl;
                f4_t hA = *(const f4_t*)&hbuf[ic * 8];
                f4_t hB = *(const f4_t*)&hbuf[ic * 8 + 4];
                uint4 w0 = *(const uint4*)(whh2 + l * 128 + off);
                uint4 w1 = *(const uint4*)(whh2 + (l + 64) * 128 + off);
                uint4 w2 = *(const uint4*)(whh2 + (l + 128) * 128 + off);
                gh0 += dot8(w0, hA, hB); gh1 += dot8(w1, hA, hB); gh2 += dot8(w2, hA, hB);
            }
            float r = sigmoidf_(gg0 + gh0);
            float z = sigmoidf_(gg1 + gh1);
            float n = tanhf_(gg2 + r * gh2);
            h3 = (1.f - z) * n + z * h3;
            __builtin_amdgcn_wave_barrier();
            hbuf[l] = h3;
            __builtin_amdgcn_wave_barrier();
            float sk = 0.f;
            #pragma unroll
            for (int ic = 0; ic < 8; ++ic) {
                const int off = (ic * 16) ^ swl;
                uint4 wv = *(const uint4*)(wa2 + l * 128 + off);
                f4_t hA = *(const f4_t*)&hbuf[ic * 8];
                f4_t hB = *(const f4_t*)&hbuf[ic * 8 + 4];
                sk += dot8(wv, hA, hB);
            }
            float term = tanhf_(sk) * vak;
            #pragma unroll
            for (int off = 32; off; off >>= 1) term += __shfl_xor(term, off);
            float mn = fmaxf(m3, term);
            float s0 = __expf(m3 - mn);
            float p = __expf(term - mn);
            den3 = den3 * s0 + p;
            av3 = av3 * s0 + p * h3;
            m3 = mn;
        }
        xprice[(size_t)s * Hn + l] = av3 / den3;
    }
}

// ---------------------------------------------------------------------------
// FALLBACK (round-1) text encoder + small GRUs: used only if ws is too small.
// ---------------------------------------------------------------------------
__global__ __launch_bounds__(256) void text_enc(
    const float* __restrict__ text, const float* __restrict__ Wih,
    const float* __restrict__ Whh, const float* __restrict__ bih,
    const float* __restrict__ bhh, const float* __restrict__ Wa,
    const float* __restrict__ va, float* __restrict__ news)
{
    __shared__ __align__(16) float gi[Tn][G3];
    __shared__ __align__(16) unsigned char whhT[G3 * Hn * 2];
    __shared__ __align__(16) float hs[Tn][Hn];
    __shared__ __align__(16) float hcur[Hn];
    __shared__ float gh[G3];
    __shared__ float red[160];
    __shared__ float scb[Tn], alb[Tn];
    __shared__ float ssum;

    const int blk = blockIdx.x;
    const int s = blk / Dn;
    const int tid = threadIdx.x;
    const int lane = tid & 63, w = tid >> 6;

    const float* Wihs = Wih + (size_t)s * FTn * G3;
    const float* Whhs = Whh + (size_t)s * Hn * G3;
    const float* xblk = text + (size_t)blk * Tn * FTn;

    for (int e = tid; e < Hn * G3; e += 256) {
        int i = e / G3, j = e - i * G3;
        *(unsigned short*)(whhT + j * 128 + (((i * 2) ^ ((j & 7) << 4)))) = f2bf(Whhs[e]);
    }
    if (tid < Hn) hcur[tid] = 0.f;

    f4_t acc[3][3];
    #pragma unroll
    for (int a = 0; a < 3; a++)
        #pragma unroll
        for (int b = 0; b < 3; b++) acc[a][b] = (f4_t){0.f, 0.f, 0.f, 0.f};
    const int rt = lane & 15, kg = lane >> 4;
    for (int kk = 0; kk < FTn / 32; ++kk) {
        const int kbase = kk * 32 + kg * 8;
        bf8_t afr[3], bfr[3];
        #pragma unroll
        for (int mt = 0; mt < 3; ++mt) {
            int r = mt * 16 + rt;
            if (r < Tn) {
                const float* p = xblk + r * FTn + kbase;
                f4_t v0 = *(const f4_t*)p, v1 = *(const f4_t*)(p + 4);
                afr[mt][0] = (short)f2bf(v0[0]); afr[mt][1] = (short)f2bf(v0[1]);
                afr[mt][2] = (short)f2bf(v0[2]); afr[mt][3] = (short)f2bf(v0[3]);
                afr[mt][4] = (short)f2bf(v1[0]); afr[mt][5] = (short)f2bf(v1[1]);
                afr[mt][6] = (short)f2bf(v1[2]); afr[mt][7] = (short)f2bf(v1[3]);
            } else {
                #pragma unroll
                for (int b = 0; b < 8; b++) afr[mt][b] = 0;
            }
        }
        #pragma unroll
        for (int nc = 0; nc < 3; ++nc) {
            const int col = (w * 3 + nc) * 16 + rt;
            const float* bp = Wihs + (size_t)kbase * G3 + col;
            #pragma unroll
            for (int b = 0; b < 8; b++) bfr[nc][b] = (short)f2bf(bp[b * G3]);
        }
        #pragma unroll
        for (int mt = 0; mt < 3; ++mt)
            #pragma unroll
            for (int nc = 0; nc < 3; ++nc)
                acc[mt][nc] = __builtin_amdgcn_mfma_f32_16x16x32_bf16(afr[mt], bfr[nc], acc[mt][nc], 0, 0, 0);
    }
    const float* bihs = bih + (size_t)s * G3;
    #pragma unroll
    for (int nc = 0; nc < 3; ++nc) {
        const int col = (w * 3 + nc) * 16 + rt;
        const float bv = bihs[col];
        #pragma unroll
        for (int mt = 0; mt < 3; ++mt) {
            #pragma unroll
            for (int rg = 0; rg < 4; rg++) {
                int r = mt * 16 + kg * 4 + rg;
                if (r < Tn) gi[r][col] = acc[mt][nc][rg] + bv;
            }
        }
    }
    __syncthreads();

    const float* bhhs = bhh + (size_t)s * G3;
    for (int t = 0; t < Tn; t++) {
        if (tid < G3) {
            const int j = tid;
            const int sw = (j & 7) << 4;
            float a = bhhs[j];
            #pragma unroll
            for (int ic = 0; ic < 8; ++ic) {
                uint4 wv = *(const uint4*)(whhT + j * 128 + ((ic * 16) ^ sw));
                f4_t h0 = *(const f4_t*)&hcur[ic * 8];
                f4_t h1 = *(const f4_t*)&hcur[ic * 8 + 4];
                a += dot8(wv, h0, h1);
            }
            gh[j] = a;
        }
        __syncthreads();
        if (tid < Hn) {
            const int c = tid;
            float r = sigmoidf_(gi[t][c] + gh[c]);
            float z = sigmoidf_(gi[t][Hn + c] + gh[Hn + c]);
            float n = tanhf_(gi[t][2 * Hn + c] + r * gh[2 * Hn + c]);
            float hn = (1.f - z) * n + z * hcur[c];
            hcur[c] = hn;
            hs[t][c] = hn;
        }
        __syncthreads();
    }

    const float* Was = Wa + (size_t)s * Hn * Hn;
    const float* vas = va + (size_t)s * Hn;
    if (tid < 160) {
        const int t = tid % Tn, q = tid / Tn;
        float part = 0.f;
        for (int k = q * 16; k < q * 16 + 16; ++k) {
            float dot = 0.f;
            #pragma unroll 4
            for (int i = 0; i < Hn; i += 4) {
                f4_t hv = *(const f4_t*)&hs[t][i];
                dot += hv[0] * Was[i * Hn + k] + hv[1] * Was[(i + 1) * Hn + k]
                     + hv[2] * Was[(i + 2) * Hn + k] + hv[3] * Was[(i + 3) * Hn + k];
            }
            part += tanhf_(dot) * vas[k];
        }
        red[tid] = part;
    }
    __syncthreads();
    if (tid < Tn) scb[tid] = red[tid] + red[Tn + tid] + red[2 * Tn + tid] + red[3 * Tn + tid];
    __syncthreads();
    if (tid == 0) {
        float mx = -1e30f;
        for (int t = 0; t < Tn; t++) mx = fmaxf(mx, scb[t]);
        float ss = 0.f;
        for (int t = 0; t < Tn; t++) { float p = __expf(scb[t] - mx); alb[t] = p; ss += p; }
        ssum = ss;
    }
    __syncthreads();
    if (tid < Hn) {
        float o = 0.f;
        for (int t = 0; t < Tn; t++) o += alb[t] * hs[t][tid];
        news[(size_t)blk * Hn + tid] = o / ssum;
    }
}

template<int FIN>
__global__ __launch_bounds__(192) void small_gru(
    const float* __restrict__ xin, const float* __restrict__ Wih,
    const float* __restrict__ Whh, const float* __restrict__ bih,
    const float* __restrict__ bhh, const float* __restrict__ Wa,
    const float* __restrict__ va, float* __restrict__ outv)
{
    __shared__ __align__(16) float whhT[G3 * Hn];
    __shared__ float gi[Dn][G3];
    __shared__ float xs[Dn * FIN];
    __shared__ __align__(16) float hs[Dn][Hn];
    __shared__ __align__(16) float hcur[Hn];
    __shared__ float gh[G3];
    __shared__ float red[160];
    __shared__ float scb[Dn], alb[Dn];
    __shared__ float ssum;

    const int s = blockIdx.x, tid = threadIdx.x;
    char* wb = (char*)whhT;

    for (int e = tid; e < Dn * FIN; e += 192) xs[e] = xin[(size_t)s * Dn * FIN + e];
    const float* Whhs = Whh + (size_t)s * Hn * G3;
    for (int e = tid; e < Hn * G3; e += 192) {
        int i = e / G3, j = e - i * G3;
        *(float*)(wb + j * 256 + (((i * 4) ^ ((j & 15) << 4)))) = Whhs[e];
    }
    if (tid < Hn) hcur[tid] = 0.f;
    __syncthreads();

    {
        const int j = tid;
        const float* Wihs = Wih + (size_t)s * FIN * G3;
        const float bi = bih[(size_t)s * G3 + j];
        for (int t = 0; t < Dn; t++) {
            float a = bi;
            for (int i = 0; i < FIN; i++) a += xs[t * FIN + i] * Wihs[i * G3 + j];
            gi[t][j] = a;
        }
    }
    __syncthreads();

    const float* bhhs = bhh + (size_t)s * G3;
    for (int t = 0; t < Dn; t++) {
        {
            const int j = tid;
            const int sw = (j & 15) << 4;
            float a = bhhs[j];
            #pragma unroll
            for (int ic = 0; ic < 16; ++ic) {
                f4_t wv = *(const f4_t*)(wb + j * 256 + ((ic * 16) ^ sw));
                f4_t hv = *(const f4_t*)&hcur[ic * 4];
                a += wv[0] * hv[0] + wv[1] * hv[1] + wv[2] * hv[2] + wv[3] * hv[3];
            }
            gh[j] = a;
        }
        __syncthreads();
        if (tid < Hn) {
            const int c = tid;
            float r = sigmoidf_(gi[t][c] + gh[c]);
            float z = sigmoidf_(gi[t][Hn + c] + gh[Hn + c]);
            float n = tanhf_(gi[t][2 * Hn + c] + r * gh[2 * Hn + c]);
            float hn = (1.f - z) * n + z * hcur[c];
            hcur[c] = hn; hs[t][c] = hn;
        }
        __syncthreads();
    }

    const float* Was = Wa + (size_t)s * Hn * Hn;
    const float* vas = va + (size_t)s * Hn;
    if (tid < Dn * 16) {
        const int t = tid >> 4, kc = tid & 15;
        float part = 0.f;
        for (int k = kc * 4; k < kc * 4 + 4; ++k) {
            float dot = 0.f;
            for (int i = 0; i < Hn; i += 4) {
                f4_t hv = *(const f4_t*)&hs[t][i];
                dot += hv[0] * Was[i * Hn + k] + hv[1] * Was[(i + 1) * Hn + k]
                     + hv[2] * Was[(i + 2) * Hn + k] + hv[3] * Was[(i + 3) * Hn + k];
            }
            part += tanhf_(dot) * vas[k];
        }
        red[tid] = part;
    }
    __syncthreads();
    if (tid < Dn) {
        float sc = 0.f;
        for (int kc = 0; kc < 16; kc++) sc += red[tid * 16 + kc];
        scb[tid] = sc;
    }
    __syncthreads();
    if (tid == 0) {
        float mx = -1e30f;
        for (int t = 0; t < Dn; t++) mx = fmaxf(mx, scb[t]);
        float ss = 0.f;
        for (int t = 0; t < Dn; t++) { float p = __expf(scb[t] - mx); alb[t] = p; ss += p; }
        ssum = ss;
    }
    __syncthreads();
    if (tid < Hn) {
        float o = 0.f;
        for (int t = 0; t < Dn; t++) o += alb[t] * hs[t][tid];
        outv[(size_t)s * Hn + tid] = o / ssum;
    }
}

// ---------------------------------------------------------------------------
// Bilinear fusion + per-stock q/k projections + blend head. One block/stock.
// ---------------------------------------------------------------------------
__global__ __launch_bounds__(256) void bilinear_head(
    const float* __restrict__ Wb, const float* __restrict__ bb,
    const float* __restrict__ Wbl, const float* __restrict__ bbl,
    const float* __restrict__ Wq, const float* __restrict__ bq,
    const float* __restrict__ Wk, const float* __restrict__ bk,
    const float* __restrict__ xprice, const float* __restrict__ tvec,
    float* __restrict__ combined, float* __restrict__ qg,
    float* __restrict__ kg, float* __restrict__ out1)
{
    __shared__ __align__(16) float uT[Hn][Hn];
    __shared__ float cl[Hn];
    __shared__ float tv[Hn];

    const int s = blockIdx.x, tid = threadIdx.x;
    const int w = tid >> 6, l = tid & 63;
    if (tid < Hn) tv[tid] = tvec[s * Hn + tid];
    const int j4 = (l & 15) * 4;
    f4_t xq = *(const f4_t*)&xprice[s * Hn + j4];
    __syncthreads();

    const float* Wbs = Wb + (size_t)s * Hn * Hn * Hn;
    for (int g = 0; g < 256; ++g) {
        int P = w * 1024 + g * 4 + (l >> 4);
        f4_t wv = *(const f4_t*)&Wbs[(size_t)P * Hn + j4];
        float dp = wv[0] * xq[0] + wv[1] * xq[1] + wv[2] * xq[2] + wv[3] * xq[3];
        dp += __shfl_xor(dp, 8);
        dp += __shfl_xor(dp, 4);
        dp += __shfl_xor(dp, 2);
        dp += __shfl_xor(dp, 1);
        if ((l & 15) == 0) { int k = P >> 6, i = P & 63; uT[i][k] = dp; }
    }
    __syncthreads();
    if (tid < Hn) {
        const int k = tid;
        float a = bb[s * Hn + k];
        for (int i = 0; i < Hn; i++) a += tv[i] * uT[i][k];
        float c = tanhf_(a);
        cl[k] = c; combined[s * Hn + k] = c;
    }
    __syncthreads();
    if (tid < Hn) {
        const int j = tid;
        float aq = bq[j], ak = bk[j];
        for (int i = 0; i < Hn; i++) { float ci = cl[i]; aq += ci * Wq[i * Hn + j]; ak += ci * Wk[i * Hn + j]; }
        qg[s * Hn + j] = aq; kg[s * Hn + j] = ak;
    }
    if (tid >= Hn && tid < Hn + 2) {
        const int c = tid - Hn;
        float a = bbl[s * 2 + c];
        for (int i = 0; i < Hn; i++) a += cl[i] * Wbl[(size_t)s * Hn * 2 + i * 2 + c];
        out1[s * 2 + c] = tanhf_(a);
    }
}

// ---------------------------------------------------------------------------
// Cross-stock MHSA + elu head + blend + softmax.
// ---------------------------------------------------------------------------
__global__ __launch_bounds__(256) void mhsa(
    const float* __restrict__ qg, const float* __restrict__ kg,
    const float* __restrict__ combined, const float* __restrict__ Wf,
    const float* __restrict__ bfp, const float* __restrict__ out1,
    float* __restrict__ dout)
{
    __shared__ __align__(16) float ql[Hn];
    __shared__ float sl[NHn][Sn];
    __shared__ float hsum[NHn];
    __shared__ float ao[Hn];
    __shared__ float red2[8];
    __shared__ float red3[4][Hn];

    const int sq = blockIdx.x, tid = threadIdx.x;
    if (tid < Hn) ql[tid] = qg[sq * Hn + tid];
    __syncthreads();

    for (int id = tid; id < Sn * NHn; id += 256) {
        int t = id >> 2, h = id & 3;
        const float* kp = &kg[t * Hn + h * 16];
        float a = 0.f;
        #pragma unroll
        for (int x = 0; x < 16; x += 4) {
            f4_t kv = *(const f4_t*)&kp[x];
            f4_t qv = *(const f4_t*)&ql[h * 16 + x];
            a += kv[0] * qv[0] + kv[1] * qv[1] + kv[2] * qv[2] + kv[3] * qv[3];
        }
        sl[h][t] = a * 0.25f;
    }
    __syncthreads();
    for (int h = 0; h < NHn; ++h) {
        float m = -1e30f;
        for (int t = tid; t < Sn; t += 256) m = fmaxf(m, sl[h][t]);
        for (int o = 32; o; o >>= 1) m = fmaxf(m, __shfl_xor(m, o));
        if ((tid & 63) == 0) red2[tid >> 6] = m;
        __syncthreads();
        m = fmaxf(fmaxf(red2[0], red2[1]), fmaxf(red2[2], red2[3]));
        float ps = 0.f;
        for (int t = tid; t < Sn; t += 256) { float p = __expf(sl[h][t] - m); sl[h][t] = p; ps += p; }
        for (int o = 32; o; o >>= 1) ps += __shfl_xor(ps, o);
        if ((tid & 63) == 0) red2[4 + (tid >> 6)] = ps;
        __syncthreads();
        if (tid == 0) hsum[h] = red2[4] + red2[5] + red2[6] + red2[7];
        __syncthreads();
    }
    {
        const int q = tid >> 6, j = tid & 63, h = j >> 4;
        float a = 0.f;
        for (int t = q * 125; t < q * 125 + 125; ++t) a += sl[h][t] * combined[t * Hn + j];
        red3[q][j] = a;
    }
    __syncthreads();
    if (tid < Hn)
        ao[tid] = (red3[0][tid] + red3[1][tid] + red3[2][tid] + red3[3][tid]) / hsum[tid >> 4];
    __syncthreads();
    if (tid == 0) {
        float l0 = bfp[0], l1 = bfp[1];
        for (int j = 0; j < Hn; j++) { float v = ao[j]; l0 += v * Wf[j * 2]; l1 += v * Wf[j * 2 + 1]; }
        l0 = l0 > 0.f ? l0 : __expf(l0) - 1.f;
        l1 = l1 > 0.f ? l1 : __expf(l1) - 1.f;
        l0 += out1[sq * 2]; l1 += out1[sq * 2 + 1];
        float m = fmaxf(l0, l1);
        float e0 = __expf(l0 - m), e1 = __expf(l1 - m);
        float inv = 1.f / (e0 + e1);
        dout[1 + sq * 2] = e0 * inv;
        dout[2 + sq * 2] = e1 * inv;
    }
}

__global__ __launch_bounds__(512) void loss_k(float* __restrict__ dout,
                                              const int* __restrict__ label)
{
    __shared__ float red[512];
    const int tid = threadIdx.x;
    float a = 0.f;
    if (tid < Sn) {
        float p0 = dout[1 + 2 * tid], p1 = dout[2 + 2 * tid];
        float m = fmaxf(p0, p1);
        float lse = m + __logf(__expf(p0 - m) + __expf(p1 - m));
        float pl = label[tid] ? p1 : p0;
        a = -(pl - lse);
    }
    red[tid] = a;
    __syncthreads();
    for (int o = 256; o; o >>= 1) {
        if (tid < o) red[tid] += red[tid + o];
        __syncthreads();
    }
    if (tid == 0) dout[0] = red[0] / (float)Sn;
}

extern "C" void kernel_launch(void* const* d_in, const int* in_sizes, int n_in,
                              void* d_out, int out_size, void* d_ws, size_t ws_size,
                              hipStream_t stream)
{
    const float* text  = (const float*)d_in[0];
    const float* price = (const float*)d_in[1];
    const int*   label = (const int*)  d_in[2];
    const float* Wih_p = (const float*)d_in[5];
    const float* Whh_p = (const float*)d_in[6];
    const float* bih_p = (const float*)d_in[7];
    const float* bhh_p = (const float*)d_in[8];
    const float* Wa_p  = (const float*)d_in[9];
    const float* va_p  = (const float*)d_in[10];
    const float* Wih_t = (const float*)d_in[11];
    const float* Whh_t = (const float*)d_in[12];
    const float* bih_t = (const float*)d_in[13];
    const float* bhh_t = (const float*)d_in[14];
    const float* Wa_t  = (const float*)d_in[15];
    const float* va_t  = (const float*)d_in[16];
    const float* Wih_s = (const float*)d_in[17];
    const float* Whh_s = (const float*)d_in[18];
    const float* bih_s = (const float*)d_in[19];
    const float* bhh_s = (const float*)d_in[20];
    const float* Wa_s  = (const float*)d_in[21];
    const float* va_s  = (const float*)d_in[22];
    const float* Wb    = (const float*)d_in[23];
    const float* bb    = (const float*)d_in[24];
    const float* Wbl   = (const float*)d_in[25];
    const float* bbl   = (const float*)d_in[26];
    const float* Wq    = (const float*)d_in[27];
    const float* bq    = (const float*)d_in[28];
    const float* Wk    = (const float*)d_in[29];
    const float* bk    = (const float*)d_in[30];
    const float* Wf    = (const float*)d_in[31];
    const float* bf_   = (const float*)d_in[32];

    float* ws = (float*)d_ws;
    float* news     = ws;              // 320000 (fallback only)
    float* xprice   = ws + 320000;     // 32000
    float* tvec     = ws + 352000;     // 32000
    float* combined = ws + 384000;     // 32000
    float* qg       = ws + 416000;     // 32000
    float* kg       = ws + 448000;     // 32000
    float* out1     = ws + 480000;     // 1000
    float* gi2      = ws + 481000;     // 61,440,000 floats (245.8 MB)
    float* dout = (float*)d_out;

    const size_t need = (size_t)(481000 + 61440000) * 4;
    if (ws_size >= need) {
        gi_gemm2<<<Sn * 2, 256, 0, stream>>>(text, Wih_t, bih_t, gi2);
        gru_fused<<<Sn, 64, 0, stream>>>(gi2, Whh_t, bhh_t, Wa_t, va_t,
                                         Wih_s, Whh_s, bih_s, bhh_s, Wa_s, va_s,
                                         price, Wih_p, Whh_p, bih_p, bhh_p, Wa_p, va_p,
                                         tvec, xprice);
    } else {
        text_enc<<<Sn * Dn, 256, 0, stream>>>(text, Wih_t, Whh_t, bih_t, bhh_t, Wa_t, va_t, news);
        small_gru<FPn><<<Sn, 192, 0, stream>>>(price, Wih_p, Whh_p, bih_p, bhh_p, Wa_p, va_p, xprice);
        small_gru<Hn><<<Sn, 192, 0, stream>>>(news, Wih_s, Whh_s, bih_s, bhh_s, Wa_s, va_s, tvec);
    }
    bilinear_head<<<Sn, 256, 0, stream>>>(Wb, bb, Wbl, bbl, Wq, bq, Wk, bk,
                                          xprice, tvec, combined, qg, kg, out1);
    mhsa<<<Sn, 256, 0, stream>>>(qg, kg, combined, Wf, bf_, out1, dout);
    loss_k<<<1, 512, 0, stream>>>(dout, label);
}

// Round 4
// 675.192 us; speedup vs baseline: 1.2561x; 1.2561x over previous
//
#include <hip/hip_runtime.h>

#define Sn 500
#define Dn 10
#define Tn 40
#define FPn 3
#define FTn 512
#define Hn 64
#define G3 192
#define NHn 4

typedef __attribute__((ext_vector_type(8))) short bf8_t;   // 8 x bf16 bits
typedef __attribute__((ext_vector_type(4))) float f4_t;

__device__ __forceinline__ unsigned short f2bf(float f) {
    union { float f; unsigned int u; } v; v.f = f;
    unsigned int r = v.u + 0x7fffu + ((v.u >> 16) & 1u);   // round-to-nearest-even
    return (unsigned short)(r >> 16);
}
__device__ __forceinline__ float bflo(unsigned int u) {
    union { unsigned int u; float f; } v; v.u = u << 16; return v.f;
}
__device__ __forceinline__ float bfhi(unsigned int u) {
    union { unsigned int u; float f; } v; v.u = u & 0xffff0000u; return v.f;
}
__device__ __forceinline__ unsigned int cvtpk(float lo, float hi) {
    unsigned int r;
    asm("v_cvt_pk_bf16_f32 %0, %1, %2" : "=v"(r) : "v"(lo), "v"(hi));
    return r;
}
__device__ __forceinline__ float sigmoidf_(float x) { return 1.f / (1.f + __expf(-x)); }
__device__ __forceinline__ float tanhf_(float x) {
    x = fminf(15.f, fmaxf(-15.f, x));
    float e = __expf(2.f * x);
    return (e - 1.f) / (e + 1.f);
}
__device__ __forceinline__ float dot8(uint4 wv, f4_t hA, f4_t hB) {
    return bflo(wv.x) * hA[0] + bfhi(wv.x) * hA[1]
         + bflo(wv.y) * hA[2] + bfhi(wv.y) * hA[3]
         + bflo(wv.z) * hB[0] + bfhi(wv.z) * hB[1]
         + bflo(wv.w) * hB[2] + bfhi(wv.w) * hB[3];
}
union bfu { bf8_t v; unsigned int u[4]; };

// ---------------------------------------------------------------------------
// gi_gemm3: gi2 = permute(x @ Wih_t + bih_t). Block = (stock, quarter of 100
// rows), 4 waves; wave tile 112x48 -> acc[7][3] = 84 VGPR (NO SPILL).
// Bijective XCD swizzle co-locates a stock's 4 quarters on one XCD so Wih
// stays L2-hot. Output layout matches gru_text_f's MFMA C-layout:
//   gi2[((s*40+t)*48 + ntg*4 + (day&3))*64 + (day>>2)*16 + (col&15)]
// ---------------------------------------------------------------------------
__global__ __launch_bounds__(256, 3) void gi_gemm3(
    const float* __restrict__ text, const float* __restrict__ Wih,
    const float* __restrict__ bih, float* __restrict__ gi2)
{
    __shared__ __align__(16) unsigned char Asb[112 * 80];   // 112 rows x 32 k bf16 (stride 80B)

    const int bid = blockIdx.x;
    const int swz = (bid & 7) * 250 + (bid >> 3);    // 2000 % 8 == 0: bijective
    const int s = swz >> 2, q = swz & 3;
    const int tid = threadIdx.x, w = tid >> 6, l = tid & 63;
    const int lr = l & 15, lg = l >> 4;

    const float* Wihs = Wih + (size_t)s * FTn * G3;
    const float* xrow = text + ((size_t)s * 400 + q * 100) * FTn;

    if (tid < 240) ((unsigned int*)(Asb + 100 * 80))[tid] = 0u;   // zero pad rows 100..111

    f4_t acc[7][3];
    #pragma unroll
    for (int a = 0; a < 7; a++)
        #pragma unroll
        for (int b = 0; b < 3; b++) acc[a][b] = (f4_t){0.f, 0.f, 0.f, 0.f};

    // staging tasks: 400 = 100 rows x 4 chunks of 8 f32; 2 tasks/thread
    f4_t pa0[2], pa1[2];
    auto loadT = [&](int kk) {
        #pragma unroll
        for (int u = 0; u < 2; ++u) {
            int tsk = tid + u * 256;
            if (tsk < 400) {
                int rw = tsk >> 2, ch = tsk & 3;
                const float* p = xrow + (size_t)rw * FTn + kk * 32 + ch * 8;
                pa0[u] = *(const f4_t*)p; pa1[u] = *(const f4_t*)(p + 4);
            }
        }
    };
    auto storeT = [&]() {
        #pragma unroll
        for (int u = 0; u < 2; ++u) {
            int tsk = tid + u * 256;
            if (tsk < 400) {
                int rw = tsk >> 2, ch = tsk & 3;
                uint4 uu = { cvtpk(pa0[u][0], pa0[u][1]), cvtpk(pa0[u][2], pa0[u][3]),
                             cvtpk(pa1[u][0], pa1[u][1]), cvtpk(pa1[u][2], pa1[u][3]) };
                *(uint4*)(Asb + rw * 80 + ch * 16) = uu;
            }
        }
    };

    loadT(0);
    for (int kk = 0; kk < 16; ++kk) {
        __syncthreads();
        storeT();
        __syncthreads();
        if (kk < 15) loadT(kk + 1);

        bfu bfr[3];
        #pragma unroll
        for (int nc = 0; nc < 3; ++nc) {
            const int col = w * 48 + nc * 16 + lr;
            const float* bp = Wihs + (size_t)(kk * 32 + lg * 8) * G3 + col;
            float b0 = bp[0], b1 = bp[G3], b2 = bp[2 * G3], b3 = bp[3 * G3];
            float b4 = bp[4 * G3], b5 = bp[5 * G3], b6 = bp[6 * G3], b7 = bp[7 * G3];
            bfr[nc].u[0] = cvtpk(b0, b1); bfr[nc].u[1] = cvtpk(b2, b3);
            bfr[nc].u[2] = cvtpk(b4, b5); bfr[nc].u[3] = cvtpk(b6, b7);
        }
        #pragma unroll
        for (int mt = 0; mt < 7; ++mt) {
            bf8_t af = *(const bf8_t*)(Asb + (mt * 16 + lr) * 80 + lg * 16);
            #pragma unroll
            for (int nc = 0; nc < 3; ++nc)
                acc[mt][nc] = __builtin_amdgcn_mfma_f32_16x16x32_bf16(af, bfr[nc].v, acc[mt][nc], 0, 0, 0);
        }
    }

    #pragma unroll
    for (int nc = 0; nc < 3; ++nc) {
        const int col = w * 48 + nc * 16 + lr;
        const int ntg = col >> 4;
        const float bv = bih[(size_t)s * G3 + col];
        #pragma unroll
        for (int mt = 0; mt < 7; ++mt) {
            #pragma unroll
            for (int rg = 0; rg < 4; ++rg) {
                int rl = mt * 16 + lg * 4 + rg;
                if (rl < 100) {
                    int row = q * 100 + rl;
                    int day = row / 40, t = row - day * 40;
                    size_t idx = (((size_t)s * 40 + t) * 48 + ntg * 4 + (day & 3)) * 64
                               + ((day >> 2) << 4) + lr;
                    gi2[idx] = acc[mt][nc][rg] + bv;
                }
            }
        }
    }
}

// ---------------------------------------------------------------------------
// gru_text_f: text GRU recurrence, 10 days batched in the MFMA M-dim. One
// 64-thread block per stock; Whh lives in VGPRs as 24 B-frags; fused
// online-softmax attention pooling -> news (global). Zero block barriers.
// ---------------------------------------------------------------------------
__global__ __launch_bounds__(64, 1) void gru_text_f(
    const float* __restrict__ gi2, const float* __restrict__ Whh,
    const float* __restrict__ bhh, const float* __restrict__ Wa,
    const float* __restrict__ va, float* __restrict__ news)
{
    __shared__ __align__(16) float hrow[16 * 68];            // [16][68]
    __shared__ __align__(16) unsigned char waT[Hn * 128];    // Wa^T bf16 swizzled

    const int s = blockIdx.x, l = threadIdx.x;
    const int lr = l & 15, lg = l >> 4;

    const float* Whhs = Whh + (size_t)s * Hn * G3;
    bfu bwhh[2][12];
    #pragma unroll
    for (int ks = 0; ks < 2; ++ks)
        #pragma unroll
        for (int nt = 0; nt < 12; ++nt) {
            const float* p = Whhs + (size_t)(ks * 32 + lg * 8) * G3 + nt * 16 + lr;
            float b0 = p[0], b1 = p[G3], b2 = p[2 * G3], b3 = p[3 * G3];
            float b4 = p[4 * G3], b5 = p[5 * G3], b6 = p[6 * G3], b7 = p[7 * G3];
            bwhh[ks][nt].u[0] = cvtpk(b0, b1); bwhh[ks][nt].u[1] = cvtpk(b2, b3);
            bwhh[ks][nt].u[2] = cvtpk(b4, b5); bwhh[ks][nt].u[3] = cvtpk(b6, b7);
        }
    float bhh_l[12];
    #pragma unroll
    for (int nt = 0; nt < 12; ++nt) bhh_l[nt] = bhh[(size_t)s * G3 + nt * 16 + lr];
    float va_l[4];
    #pragma unroll
    for (int nt = 0; nt < 4; ++nt) va_l[nt] = va[(size_t)s * Hn + nt * 16 + lr];

    {
        const float* Was = Wa + (size_t)s * Hn * Hn;
        for (int r = 0; r < 64; ++r) {
            int e = l + r * 64, i = e >> 6, k = e & 63;
            *(unsigned short*)(waT + k * 128 + ((2 * i) ^ ((k & 7) << 4))) = f2bf(Was[e]);
        }
        #pragma unroll
        for (int r = 0; r < 17; ++r) hrow[l + r * 64] = 0.f;
    }
    __builtin_amdgcn_wave_barrier();

    float val[48], valn[48];
    {
        const float* gb = gi2 + (size_t)s * 40 * 3072 + l;
        #pragma unroll
        for (int j = 0; j < 48; ++j) val[j] = gb[j * 64];
    }
    bf8_t a0f, a1f;
    {   bfu z0; z0.u[0] = 0; z0.u[1] = 0; z0.u[2] = 0; z0.u[3] = 0; a0f = z0.v; a1f = z0.v; }

    float h[4][4], accv[4][4], den[4], m[4];
    #pragma unroll
    for (int nt = 0; nt < 4; ++nt)
        #pragma unroll
        for (int rr = 0; rr < 4; ++rr) { h[nt][rr] = 0.f; accv[nt][rr] = 0.f; }
    #pragma unroll
    for (int rr = 0; rr < 4; ++rr) { den[rr] = 0.f; m[rr] = -1e30f; }

    for (int t = 0; t < Tn; ++t) {
        f4_t acc[12];
        #pragma unroll
        for (int nt = 0; nt < 12; ++nt)
            acc[nt] = (f4_t){bhh_l[nt], bhh_l[nt], bhh_l[nt], bhh_l[nt]};
        #pragma unroll
        for (int nt = 0; nt < 12; ++nt) {
            acc[nt] = __builtin_amdgcn_mfma_f32_16x16x32_bf16(a0f, bwhh[0][nt].v, acc[nt], 0, 0, 0);
            acc[nt] = __builtin_amdgcn_mfma_f32_16x16x32_bf16(a1f, bwhh[1][nt].v, acc[nt], 0, 0, 0);
        }
        {
            const int tn = (t < Tn - 1) ? t + 1 : t;
            const float* gb = gi2 + ((size_t)s * 40 + tn) * 3072 + l;
            #pragma unroll
            for (int j = 0; j < 48; ++j) valn[j] = gb[j * 64];
        }
        #pragma unroll
        for (int nt = 0; nt < 4; ++nt)
            #pragma unroll
            for (int rr = 0; rr < 4; ++rr) {
                float r = sigmoidf_(val[nt * 4 + rr] + acc[nt][rr]);
                float z = sigmoidf_(val[(nt + 4) * 4 + rr] + acc[nt + 4][rr]);
                float n = tanhf_(val[(nt + 8) * 4 + rr] + r * acc[nt + 8][rr]);
                h[nt][rr] = (1.f - z) * n + z * h[nt][rr];
            }
        __builtin_amdgcn_wave_barrier();
        #pragma unroll
        for (int rr = 0; rr < 4; ++rr) {
            int day = lg * 4 + rr;
            if (day < Dn) {
                #pragma unroll
                for (int nt = 0; nt < 4; ++nt) hrow[day * 68 + nt * 16 + lr] = h[nt][rr];
            }
        }
        __builtin_amdgcn_wave_barrier();
        {
            const float* hp = hrow + lr * 68 + lg * 8;
            f4_t x0 = *(const f4_t*)hp,        x1 = *(const f4_t*)(hp + 4);
            f4_t y0 = *(const f4_t*)(hp + 32), y1 = *(const f4_t*)(hp + 36);
            bfu t0, t1;
            t0.u[0] = cvtpk(x0[0], x0[1]); t0.u[1] = cvtpk(x0[2], x0[3]);
            t0.u[2] = cvtpk(x1[0], x1[1]); t0.u[3] = cvtpk(x1[2], x1[3]);
            t1.u[0] = cvtpk(y0[0], y0[1]); t1.u[1] = cvtpk(y0[2], y0[3]);
            t1.u[2] = cvtpk(y1[0], y1[1]); t1.u[3] = cvtpk(y1[2], y1[3]);
            a0f = t0.v; a1f = t1.v;
        }
        f4_t sc[4];
        #pragma unroll
        for (int nt = 0; nt < 4; ++nt) sc[nt] = (f4_t){0.f, 0.f, 0.f, 0.f};
        #pragma unroll
        for (int ks = 0; ks < 2; ++ks) {
            bf8_t av = ks ? a1f : a0f;
            #pragma unroll
            for (int nt = 0; nt < 4; ++nt) {
                bf8_t bwv = *(const bf8_t*)(waT + (nt * 16 + lr) * 128
                                            + ((ks * 64 + lg * 16) ^ ((lr & 7) << 4)));
                sc[nt] = __builtin_amdgcn_mfma_f32_16x16x32_bf16(av, bwv, sc[nt], 0, 0, 0);
            }
        }
        float pr[4];
        #pragma unroll
        for (int rr = 0; rr < 4; ++rr) {
            pr[rr] = tanhf_(sc[0][rr]) * va_l[0] + tanhf_(sc[1][rr]) * va_l[1]
                   + tanhf_(sc[2][rr]) * va_l[2] + tanhf_(sc[3][rr]) * va_l[3];
            pr[rr] += __shfl_xor(pr[rr], 1);
            pr[rr] += __shfl_xor(pr[rr], 2);
            pr[rr] += __shfl_xor(pr[rr], 4);
            pr[rr] += __shfl_xor(pr[rr], 8);
        }
        #pragma unroll
        for (int rr = 0; rr < 4; ++rr) {
            float mn = fmaxf(m[rr], pr[rr]);
            float s0 = __expf(m[rr] - mn);
            float p = __expf(pr[rr] - mn);
            den[rr] = den[rr] * s0 + p;
            #pragma unroll
            for (int nt = 0; nt < 4; ++nt)
                accv[nt][rr] = accv[nt][rr] * s0 + p * h[nt][rr];
            m[rr] = mn;
        }
        #pragma unroll
        for (int j = 0; j < 48; ++j) val[j] = valn[j];
    }
    #pragma unroll
    for (int rr = 0; rr < 4; ++rr) {
        int day = lg * 4 + rr;
        if (day < Dn) {
            float inv = 1.f / den[rr];
            #pragma unroll
            for (int nt = 0; nt < 4; ++nt)
                news[((size_t)s * Dn + day) * Hn + nt * 16 + lr] = accv[nt][rr] * inv;
        }
    }
}

// ---------------------------------------------------------------------------
// gru_small_f: day-sequence GRU (over news) -> tvec, then price GRU -> xprice.
// One 64-thread block per stock, wave-synchronous (no block barriers).
// ---------------------------------------------------------------------------
__global__ __launch_bounds__(64, 1) void gru_small_f(
    const float* __restrict__ news,
    const float* __restrict__ Wih_s, const float* __restrict__ Whh_s,
    const float* __restrict__ bih_s, const float* __restrict__ bhh_s,
    const float* __restrict__ Wa_s, const float* __restrict__ va_s,
    const float* __restrict__ price, const float* __restrict__ Wih_p,
    const float* __restrict__ Whh_p, const float* __restrict__ bih_p,
    const float* __restrict__ bhh_p, const float* __restrict__ Wa_p,
    const float* __restrict__ va_p,
    float* __restrict__ tvec, float* __restrict__ xprice)
{
    __shared__ __align__(16) unsigned char sm[60928];
    unsigned char* whh2 = sm;                         // [192][128B]
    unsigned char* wih2 = sm + 24576;                 // [192][128B]
    unsigned char* wa2 = sm + 49152;                  // [64][128B]
    float* newsL = (float*)(sm + 57600);              // [10][68]
    float* hbuf  = (float*)(sm + 60320);              // [68]
    float* priceL = (float*)(sm + 60608);             // [30]

    const int s = blockIdx.x, l = threadIdx.x;

    // ---------------- phase 2: day-sequence GRU -> tvec ----------------
    {
        const float* W2 = Whh_s + (size_t)s * Hn * G3;
        const float* X2 = Wih_s + (size_t)s * Hn * G3;
        for (int r = 0; r < 192; ++r) {
            int e = l + r * 64, i = e / G3, j = e - i * G3;
            int off = j * 128 + ((2 * i) ^ ((j & 7) << 4));
            *(unsigned short*)(whh2 + off) = f2bf(W2[e]);
            *(unsigned short*)(wih2 + off) = f2bf(X2[e]);
        }
        const float* A2 = Wa_s + (size_t)s * Hn * Hn;
        for (int r = 0; r < 64; ++r) {
            int e = l + r * 64, i = e >> 6, k = e & 63;
            *(unsigned short*)(wa2 + k * 128 + ((2 * i) ^ ((k & 7) << 4))) = f2bf(A2[e]);
        }
        #pragma unroll
        for (int d = 0; d < Dn; ++d) newsL[d * 68 + l] = news[((size_t)s * Dn + d) * Hn + l];
        hbuf[l] = 0.f;
        if (l < 4) hbuf[64 + l] = 0.f;
    }
    __builtin_amdgcn_wave_barrier();
    {
        const float bi0 = bih_s[(size_t)s * G3 + l];
        const float bi1 = bih_s[(size_t)s * G3 + 64 + l];
        const float bi2 = bih_s[(size_t)s * G3 + 128 + l];
        const float bh0 = bhh_s[(size_t)s * G3 + l];
        const float bh1 = bhh_s[(size_t)s * G3 + 64 + l];
        const float bh2 = bhh_s[(size_t)s * G3 + 128 + l];
        const float vak = va_s[(size_t)s * Hn + l];
        const int swl = (l & 7) << 4;
        float h2 = 0.f, m2 = -1e30f, den2 = 0.f, av2 = 0.f;
        for (int t = 0; t < Dn; ++t) {
            float gh0 = bh0, gh1 = bh1, gh2 = bh2;
            float gg0 = bi0, gg1 = bi1, gg2 = bi2;
            #pragma unroll
            for (int ic = 0; ic < 8; ++ic) {
                const int off = (ic * 16) ^ swl;
                f4_t hA = *(const f4_t*)&hbuf[ic * 8];
                f4_t hB = *(const f4_t*)&hbuf[ic * 8 + 4];
                f4_t nA = *(const f4_t*)&newsL[t * 68 + ic * 8];
                f4_t nB = *(const f4_t*)&newsL[t * 68 + ic * 8 + 4];
                uint4 w0 = *(const uint4*)(whh2 + l * 128 + off);
                uint4 w1 = *(const uint4*)(whh2 + (l + 64) * 128 + off);
                uint4 w2 = *(const uint4*)(whh2 + (l + 128) * 128 + off);
                uint4 x0 = *(const uint4*)(wih2 + l * 128 + off);
                uint4 x1 = *(const uint4*)(wih2 + (l + 64) * 128 + off);
                uint4 x2 = *(const uint4*)(wih2 + (l + 128) * 128 + off);
                gh0 += dot8(w0, hA, hB); gh1 += dot8(w1, hA, hB); gh2 += dot8(w2, hA, hB);
                gg0 += dot8(x0, nA, nB); gg1 += dot8(x1, nA, nB); gg2 += dot8(x2, nA, nB);
            }
            float r = sigmoidf_(gg0 + gh0);
            float z = sigmoidf_(gg1 + gh1);
            float n = tanhf_(gg2 + r * gh2);
            h2 = (1.f - z) * n + z * h2;
            __builtin_amdgcn_wave_barrier();
            hbuf[l] = h2;
            __builtin_amdgcn_wave_barrier();
            float sk = 0.f;
            #pragma unroll
            for (int ic = 0; ic < 8; ++ic) {
                const int off = (ic * 16) ^ swl;
                uint4 wv = *(const uint4*)(wa2 + l * 128 + off);
                f4_t hA = *(const f4_t*)&hbuf[ic * 8];
                f4_t hB = *(const f4_t*)&hbuf[ic * 8 + 4];
                sk += dot8(wv, hA, hB);
            }
            float term = tanhf_(sk) * vak;
            #pragma unroll
            for (int off = 32; off; off >>= 1) term += __shfl_xor(term, off);
            float mn = fmaxf(m2, term);
            float s0 = __expf(m2 - mn);
            float p = __expf(term - mn);
            den2 = den2 * s0 + p;
            av2 = av2 * s0 + p * h2;
            m2 = mn;
        }
        tvec[(size_t)s * Hn + l] = av2 / den2;
    }
    __builtin_amdgcn_wave_barrier();

    // ---------------- phase 3: price GRU -> xprice ----------------
    {
        const float* W3 = Whh_p + (size_t)s * Hn * G3;
        for (int r = 0; r < 192; ++r) {
            int e = l + r * 64, i = e / G3, j = e - i * G3;
            *(unsigned short*)(whh2 + j * 128 + ((2 * i) ^ ((j & 7) << 4))) = f2bf(W3[e]);
        }
        const float* A3 = Wa_p + (size_t)s * Hn * Hn;
        for (int r = 0; r < 64; ++r) {
            int e = l + r * 64, i = e >> 6, k = e & 63;
            *(unsigned short*)(wa2 + k * 128 + ((2 * i) ^ ((k & 7) << 4))) = f2bf(A3[e]);
        }
        if (l < 30) priceL[l] = price[(size_t)s * 30 + l];
        hbuf[l] = 0.f;
        if (l < 4) hbuf[64 + l] = 0.f;
    }
    __builtin_amdgcn_wave_barrier();
    {
        float wp[3][3];
        #pragma unroll
        for (int i = 0; i < 3; ++i)
            #pragma unroll
            for (int g = 0; g < 3; ++g)
                wp[i][g] = Wih_p[(size_t)s * 3 * G3 + i * G3 + g * 64 + l];
        const float bi0 = bih_p[(size_t)s * G3 + l];
        const float bi1 = bih_p[(size_t)s * G3 + 64 + l];
        const float bi2 = bih_p[(size_t)s * G3 + 128 + l];
        const float bh0 = bhh_p[(size_t)s * G3 + l];
        const float bh1 = bhh_p[(size_t)s * G3 + 64 + l];
        const float bh2 = bhh_p[(size_t)s * G3 + 128 + l];
        const float vak = va_p[(size_t)s * Hn + l];
        const int swl = (l & 7) << 4;
        float h3 = 0.f, m3 = -1e30f, den3 = 0.f, av3 = 0.f;
        for (int t = 0; t < Dn; ++t) {
            float x0 = priceL[t * 3], x1 = priceL[t * 3 + 1], x2 = priceL[t * 3 + 2];
            float gg0 = bi0 + x0 * wp[0][0] + x1 * wp[1][0] + x2 * wp[2][0];
            float gg1 = bi1 + x0 * wp[0][1] + x1 * wp[1][1] + x2 * wp[2][1];
            float gg2 = bi2 + x0 * wp[0][2] + x1 * wp[1][2] + x2 * wp[2][2];
            float gh0 = bh0, gh1 = bh1, gh2 = bh2;
            #pragma unroll
            for (int ic = 0; ic < 8; ++ic) {
                const int off = (ic * 16) ^ swl;
                f4_t hA = *(const f4_t*)&hbuf[ic * 8];
                f4_t hB = *(const f4_t*)&hbuf[ic * 8 + 4];
                uint4 w0 = *(const uint4*)(whh2 + l * 128 + off);
                uint4 w1 = *(const uint4*)(whh2 + (l + 64) * 128 + off);
                uint4 w2 = *(const uint4*)(whh2 + (l + 128) * 128 + off);
                gh0 += dot8(w0, hA, hB); gh1 += dot8(w1, hA, hB); gh2 += dot8(w2, hA, hB);
            }
            float r = sigmoidf_(gg0 + gh0);
            float z = sigmoidf_(gg1 + gh1);
            float n = tanhf_(gg2 + r * gh2);
            h3 = (1.f - z) * n + z * h3;
            __builtin_amdgcn_wave_barrier();
            hbuf[l] = h3;
            __builtin_amdgcn_wave_barrier();
            float sk = 0.f;
            #pragma unroll
            for (int ic = 0; ic < 8; ++ic) {
                const int off = (ic * 16) ^ swl;
                uint4 wv = *(const uint4*)(wa2 + l * 128 + off);
                f4_t hA = *(const f4_t*)&hbuf[ic * 8];
                f4_t hB = *(const f4_t*)&hbuf[ic * 8 + 4];
                sk += dot8(wv, hA, hB);
            }
            float term = tanhf_(sk) * vak;
            #pragma unroll
            for (int off = 32; off; off >>= 1) term += __shfl_xor(term, off);
            float mn = fmaxf(m3, term);
            float s0 = __expf(m3 - mn);
            float p = __expf(term - mn);
            den3 = den3 * s0 + p;
            av3 = av3 * s0 + p * h3;
            m3 = mn;
        }
        xprice[(size_t)s * Hn + l] = av3 / den3;
    }
}

// ---------------------------------------------------------------------------
// bilinear2: combined = tanh(einsum(i,kij,j->k) + bb). Block = (stock, half of
// k-range): 1000 blocks for 2x the latency-hiding concurrency on the 524 MB
// Wb stream. Writes combined only (projections moved to qk_proj).
// ---------------------------------------------------------------------------
__global__ __launch_bounds__(256) void bilinear2(
    const float* __restrict__ Wb, const float* __restrict__ bb,
    const float* __restrict__ xprice, const float* __restrict__ tvec,
    float* __restrict__ combined)
{
    __shared__ __align__(16) float uT[Hn][32];   // [i][k_local], 8 KB
    __shared__ float tv[Hn];

    const int bid = blockIdx.x, s = bid >> 1, kh = bid & 1;
    const int tid = threadIdx.x;
    const int w = tid >> 6, l = tid & 63;
    if (tid < Hn) tv[tid] = tvec[s * Hn + tid];
    const int j4 = (l & 15) * 4;
    f4_t xq = *(const f4_t*)&xprice[s * Hn + j4];
    __syncthreads();

    const float* Wbs = Wb + (size_t)s * Hn * Hn * Hn;
    for (int g = 0; g < 128; ++g) {
        int P = kh * 2048 + w * 512 + g * 4 + (l >> 4);      // P = k*64 + i
        f4_t wv = *(const f4_t*)&Wbs[(size_t)P * Hn + j4];
        float dp = wv[0] * xq[0] + wv[1] * xq[1] + wv[2] * xq[2] + wv[3] * xq[3];
        dp += __shfl_xor(dp, 8);
        dp += __shfl_xor(dp, 4);
        dp += __shfl_xor(dp, 2);
        dp += __shfl_xor(dp, 1);
        if ((l & 15) == 0) { int k = P >> 6, i = P & 63; uT[i][k - kh * 32] = dp; }
    }
    __syncthreads();
    if (tid < 32) {
        const int k = kh * 32 + tid;
        float a = bb[s * Hn + k];
        for (int i = 0; i < Hn; i++) a += tv[i] * uT[i][tid];
        combined[s * Hn + k] = tanhf_(a);
    }
}

// ---------------------------------------------------------------------------
// qk_proj: q/k projections + per-stock blend head. One 64-thread block/stock.
// ---------------------------------------------------------------------------
__global__ __launch_bounds__(64) void qk_proj(
    const float* __restrict__ combined, const float* __restrict__ Wq,
    const float* __restrict__ bq, const float* __restrict__ Wk,
    const float* __restrict__ bk, const float* __restrict__ Wbl,
    const float* __restrict__ bbl,
    float* __restrict__ qg, float* __restrict__ kg, float* __restrict__ out1)
{
    __shared__ float cl[Hn];
    const int s = blockIdx.x, l = threadIdx.x;
    cl[l] = combined[s * Hn + l];
    __syncthreads();
    float aq = bq[l], ak = bk[l];
    for (int i = 0; i < Hn; i++) {
        float ci = cl[i];
        aq += ci * Wq[i * Hn + l];
        ak += ci * Wk[i * Hn + l];
    }
    qg[s * Hn + l] = aq; kg[s * Hn + l] = ak;
    if (l < 2) {
        float a = bbl[s * 2 + l];
        for (int i = 0; i < Hn; i++) a += cl[i] * Wbl[(size_t)s * Hn * 2 + i * 2 + l];
        out1[s * 2 + l] = tanhf_(a);
    }
}

// ---------------------------------------------------------------------------
// Cross-stock MHSA + elu head + blend + softmax.
// ---------------------------------------------------------------------------
__global__ __launch_bounds__(256) void mhsa(
    const float* __restrict__ qg, const float* __restrict__ kg,
    const float* __restrict__ combined, const float* __restrict__ Wf,
    const float* __restrict__ bfp, const float* __restrict__ out1,
    float* __restrict__ dout)
{
    __shared__ __align__(16) float ql[Hn];
    __shared__ float sl[NHn][Sn];
    __shared__ float hsum[NHn];
    __shared__ float ao[Hn];
    __shared__ float red2[8];
    __shared__ float red3[4][Hn];

    const int sq = blockIdx.x, tid = threadIdx.x;
    if (tid < Hn) ql[tid] = qg[sq * Hn + tid];
    __syncthreads();

    for (int id = tid; id < Sn * NHn; id += 256) {
        int t = id >> 2, h = id & 3;
        const float* kp = &kg[t * Hn + h * 16];
        float a = 0.f;
        #pragma unroll
        for (int x = 0; x < 16; x += 4) {
            f4_t kv = *(const f4_t*)&kp[x];
            f4_t qv = *(const f4_t*)&ql[h * 16 + x];
            a += kv[0] * qv[0] + kv[1] * qv[1] + kv[2] * qv[2] + kv[3] * qv[3];
        }
        sl[h][t] = a * 0.25f;
    }
    __syncthreads();
    for (int h = 0; h < NHn; ++h) {
        float m = -1e30f;
        for (int t = tid; t < Sn; t += 256) m = fmaxf(m, sl[h][t]);
        for (int o = 32; o; o >>= 1) m = fmaxf(m, __shfl_xor(m, o));
        if ((tid & 63) == 0) red2[tid >> 6] = m;
        __syncthreads();
        m = fmaxf(fmaxf(red2[0], red2[1]), fmaxf(red2[2], red2[3]));
        float ps = 0.f;
        for (int t = tid; t < Sn; t += 256) { float p = __expf(sl[h][t] - m); sl[h][t] = p; ps += p; }
        for (int o = 32; o; o >>= 1) ps += __shfl_xor(ps, o);
        if ((tid & 63) == 0) red2[4 + (tid >> 6)] = ps;
        __syncthreads();
        if (tid == 0) hsum[h] = red2[4] + red2[5] + red2[6] + red2[7];
        __syncthreads();
    }
    {
        const int q = tid >> 6, j = tid & 63, h = j >> 4;
        float a = 0.f;
        for (int t = q * 125; t < q * 125 + 125; ++t) a += sl[h][t] * combined[t * Hn + j];
        red3[q][j] = a;
    }
    __syncthreads();
    if (tid < Hn)
        ao[tid] = (red3[0][tid] + red3[1][tid] + red3[2][tid] + red3[3][tid]) / hsum[tid >> 4];
    __syncthreads();
    if (tid == 0) {
        float l0 = bfp[0], l1 = bfp[1];
        for (int j = 0; j < Hn; j++) { float v = ao[j]; l0 += v * Wf[j * 2]; l1 += v * Wf[j * 2 + 1]; }
        l0 = l0 > 0.f ? l0 : __expf(l0) - 1.f;
        l1 = l1 > 0.f ? l1 : __expf(l1) - 1.f;
        l0 += out1[sq * 2]; l1 += out1[sq * 2 + 1];
        float m = fmaxf(l0, l1);
        float e0 = __expf(l0 - m), e1 = __expf(l1 - m);
        float inv = 1.f / (e0 + e1);
        dout[1 + sq * 2] = e0 * inv;
        dout[2 + sq * 2] = e1 * inv;
    }
}

__global__ __launch_bounds__(512) void loss_k(float* __restrict__ dout,
                                              const int* __restrict__ label)
{
    __shared__ float red[512];
    const int tid = threadIdx.x;
    float a = 0.f;
    if (tid < Sn) {
        float p0 = dout[1 + 2 * tid], p1 = dout[2 + 2 * tid];
        float m = fmaxf(p0, p1);
        float lse = m + __logf(__expf(p0 - m) + __expf(p1 - m));
        float pl = label[tid] ? p1 : p0;
        a = -(pl - lse);
    }
    red[tid] = a;
    __syncthreads();
    for (int o = 256; o; o >>= 1) {
        if (tid < o) red[tid] += red[tid + o];
        __syncthreads();
    }
    if (tid == 0) dout[0] = red[0] / (float)Sn;
}

extern "C" void kernel_launch(void* const* d_in, const int* in_sizes, int n_in,
                              void* d_out, int out_size, void* d_ws, size_t ws_size,
                              hipStream_t stream)
{
    const float* text  = (const float*)d_in[0];
    const float* price = (const float*)d_in[1];
    const int*   label = (const int*)  d_in[2];
    const float* Wih_p = (const float*)d_in[5];
    const float* Whh_p = (const float*)d_in[6];
    const float* bih_p = (const float*)d_in[7];
    const float* bhh_p = (const float*)d_in[8];
    const float* Wa_p  = (const float*)d_in[9];
    const float* va_p  = (const float*)d_in[10];
    const float* Wih_t = (const float*)d_in[11];
    const float* Whh_t = (const float*)d_in[12];
    const float* bih_t = (const float*)d_in[13];
    const float* bhh_t = (const float*)d_in[14];
    const float* Wa_t  = (const float*)d_in[15];
    const float* va_t  = (const float*)d_in[16];
    const float* Wih_s = (const float*)d_in[17];
    const float* Whh_s = (const float*)d_in[18];
    const float* bih_s = (const float*)d_in[19];
    const float* bhh_s = (const float*)d_in[20];
    const float* Wa_s  = (const float*)d_in[21];
    const float* va_s  = (const float*)d_in[22];
    const float* Wb    = (const float*)d_in[23];
    const float* bb    = (const float*)d_in[24];
    const float* Wbl   = (const float*)d_in[25];
    const float* bbl   = (const float*)d_in[26];
    const float* Wq    = (const float*)d_in[27];
    const float* bq    = (const float*)d_in[28];
    const float* Wk    = (const float*)d_in[29];
    const float* bk    = (const float*)d_in[30];
    const float* Wf    = (const float*)d_in[31];
    const float* bf_   = (const float*)d_in[32];

    float* ws = (float*)d_ws;
    float* news     = ws;              // 320000
    float* xprice   = ws + 320000;     // 32000
    float* tvec     = ws + 352000;     // 32000
    float* combined = ws + 384000;     // 32000
    float* qg       = ws + 416000;     // 32000
    float* kg       = ws + 448000;     // 32000
    float* out1     = ws + 480000;     // 1000
    float* gi2      = ws + 481000;     // 61,440,000 floats (245.8 MB)
    float* dout = (float*)d_out;

    gi_gemm3<<<Sn * 4, 256, 0, stream>>>(text, Wih_t, bih_t, gi2);
    gru_text_f<<<Sn, 64, 0, stream>>>(gi2, Whh_t, bhh_t, Wa_t, va_t, news);
    gru_small_f<<<Sn, 64, 0, stream>>>(news,
                                       Wih_s, Whh_s, bih_s, bhh_s, Wa_s, va_s,
                                       price, Wih_p, Whh_p, bih_p, bhh_p, Wa_p, va_p,
                                       tvec, xprice);
    bilinear2<<<Sn * 2, 256, 0, stream>>>(Wb, bb, xprice, tvec, combined);
    qk_proj<<<Sn, 64, 0, stream>>>(combined, Wq, bq, Wk, bk, Wbl, bbl, qg, kg, out1);
    mhsa<<<Sn, 256, 0, stream>>>(qg, kg, combined, Wf, bf_, out1, dout);
    loss_k<<<1, 512, 0, stream>>>(dout, label);
}

// Round 5
// 663.114 us; speedup vs baseline: 1.2790x; 1.0182x over previous
//
#include <hip/hip_runtime.h>

#define Sn 500
#define Dn 10
#define Tn 40
#define FPn 3
#define FTn 512
#define Hn 64
#define G3 192
#define NHn 4

typedef __attribute__((ext_vector_type(8))) short bf8_t;   // 8 x bf16 bits
typedef __attribute__((ext_vector_type(4))) float f4_t;

__device__ __forceinline__ unsigned short f2bf(float f) {
    union { float f; unsigned int u; } v; v.f = f;
    unsigned int r = v.u + 0x7fffu + ((v.u >> 16) & 1u);   // round-to-nearest-even
    return (unsigned short)(r >> 16);
}
__device__ __forceinline__ float bflo(unsigned int u) {
    union { unsigned int u; float f; } v; v.u = u << 16; return v.f;
}
__device__ __forceinline__ float bfhi(unsigned int u) {
    union { unsigned int u; float f; } v; v.u = u & 0xffff0000u; return v.f;
}
__device__ __forceinline__ unsigned int cvtpk(float lo, float hi) {
    unsigned int r;
    asm("v_cvt_pk_bf16_f32 %0, %1, %2" : "=v"(r) : "v"(lo), "v"(hi));
    return r;
}
__device__ __forceinline__ float sigmoidf_(float x) { return 1.f / (1.f + __expf(-x)); }
__device__ __forceinline__ float tanhf_(float x) {
    x = fminf(15.f, fmaxf(-15.f, x));
    float e = __expf(2.f * x);
    return (e - 1.f) / (e + 1.f);
}
__device__ __forceinline__ float dot8(uint4 wv, f4_t hA, f4_t hB) {
    return bflo(wv.x) * hA[0] + bfhi(wv.x) * hA[1]
         + bflo(wv.y) * hA[2] + bfhi(wv.y) * hA[3]
         + bflo(wv.z) * hB[0] + bfhi(wv.z) * hB[1]
         + bflo(wv.w) * hB[2] + bfhi(wv.w) * hB[3];
}
union bfu { bf8_t v; unsigned int u[4]; };

// ---------------------------------------------------------------------------
// gi_gemm4: gi2[s][t][day][col] = x @ Wih_t + bih_t. Barrier-free, LDS-free
// streaming MFMA GEMM. Block = (stock, fifth of 80 rows = 2 whole days),
// 4 waves n-split 48 cols each; A-frags read per-lane from global (waves
// share lines via L1), 1-deep register prefetch of the A (HBM) stream.
// acc[5][3]=60 VGPR, total ~155 -> launch_bounds(256,2), no spill.
// Dense output: each (t,day) 768B row written by exactly one block.
// ---------------------------------------------------------------------------
__global__ __launch_bounds__(256, 2) void gi_gemm4(
    const float* __restrict__ text, const float* __restrict__ Wih,
    const float* __restrict__ bih, float* __restrict__ gi2)
{
    const int bid = blockIdx.x;
    const int xcd = bid & 7, ix = bid >> 3;
    // bijective XCD swizzle, nwg=2500: q=312, r=4 (m204 formula)
    const int swz = (xcd < 4 ? xcd * 313 : 4 * 313 + (xcd - 4) * 312) + ix;
    const int s = swz / 5, fi = swz % 5;
    const int tid = threadIdx.x, w = tid >> 6, l = tid & 63;
    const int lr = l & 15, kg = l >> 4;

    const float* Wihs = Wih + (size_t)s * FTn * G3 + w * 48 + lr;
    const float* xrow = text + ((size_t)s * 400 + fi * 80 + lr) * FTn + kg * 8;

    f4_t acc[5][3];
    #pragma unroll
    for (int a = 0; a < 5; a++)
        #pragma unroll
        for (int b = 0; b < 3; b++) acc[a][b] = (f4_t){0.f, 0.f, 0.f, 0.f};

    // prefetch A for kk=0
    f4_t an0[5], an1[5];
    #pragma unroll
    for (int mt = 0; mt < 5; ++mt) {
        const float* p = xrow + (size_t)mt * 16 * FTn;
        an0[mt] = *(const f4_t*)p; an1[mt] = *(const f4_t*)(p + 4);
    }

    for (int kk = 0; kk < 16; ++kk) {
        // convert current A to bf16 frags
        bfu af[5];
        #pragma unroll
        for (int mt = 0; mt < 5; ++mt) {
            af[mt].u[0] = cvtpk(an0[mt][0], an0[mt][1]);
            af[mt].u[1] = cvtpk(an0[mt][2], an0[mt][3]);
            af[mt].u[2] = cvtpk(an1[mt][0], an1[mt][1]);
            af[mt].u[3] = cvtpk(an1[mt][2], an1[mt][3]);
        }
        // issue next-kk A loads (HBM stream) before any compute
        if (kk < 15) {
            const float* px = xrow + (kk + 1) * 32;
            #pragma unroll
            for (int mt = 0; mt < 5; ++mt) {
                const float* p = px + (size_t)mt * 16 * FTn;
                an0[mt] = *(const f4_t*)p; an1[mt] = *(const f4_t*)(p + 4);
            }
        }
        // B frags from global (L2-resident; strided)
        bfu bfr[3];
        const float* bp0 = Wihs + (size_t)(kk * 32 + kg * 8) * G3;
        #pragma unroll
        for (int nc = 0; nc < 3; ++nc) {
            const float* bp = bp0 + nc * 16;
            float b0 = bp[0], b1 = bp[G3], b2 = bp[2 * G3], b3 = bp[3 * G3];
            float b4 = bp[4 * G3], b5 = bp[5 * G3], b6 = bp[6 * G3], b7 = bp[7 * G3];
            bfr[nc].u[0] = cvtpk(b0, b1); bfr[nc].u[1] = cvtpk(b2, b3);
            bfr[nc].u[2] = cvtpk(b4, b5); bfr[nc].u[3] = cvtpk(b6, b7);
        }
        #pragma unroll
        for (int mt = 0; mt < 5; ++mt)
            #pragma unroll
            for (int nc = 0; nc < 3; ++nc)
                acc[mt][nc] = __builtin_amdgcn_mfma_f32_16x16x32_bf16(af[mt].v, bfr[nc].v, acc[mt][nc], 0, 0, 0);
    }

    const float* bihs = bih + (size_t)s * G3 + w * 48 + lr;
    #pragma unroll
    for (int nc = 0; nc < 3; ++nc) {
        const int col = w * 48 + nc * 16 + lr;
        const float bv = bihs[nc * 16];
        #pragma unroll
        for (int mt = 0; mt < 5; ++mt)
            #pragma unroll
            for (int rg = 0; rg < 4; ++rg) {
                int r = mt * 16 + kg * 4 + rg;          // 0..79, all valid
                int hi = (r >= 40);
                int day = fi * 2 + hi;
                int t = r - hi * 40;
                gi2[((size_t)(s * 40 + t) * 10 + day) * 192 + col] = acc[mt][nc][rg] + bv;
            }
    }
}

// ---------------------------------------------------------------------------
// gru_text_f: text GRU recurrence, 10 days batched in the MFMA M-dim. One
// 64-thread block per stock; Whh lives in VGPRs as 24 B-frags; fused
// online-softmax attention pooling -> news (global). Zero block barriers.
// Reads dense gi2[s][t][day][col] with day-clamped per-lane offsets.
// ---------------------------------------------------------------------------
__global__ __launch_bounds__(64, 1) void gru_text_f(
    const float* __restrict__ gi2, const float* __restrict__ Whh,
    const float* __restrict__ bhh, const float* __restrict__ Wa,
    const float* __restrict__ va, float* __restrict__ news)
{
    __shared__ __align__(16) float hrow[16 * 68];            // [16][68]
    __shared__ __align__(16) unsigned char waT[Hn * 128];    // Wa^T bf16 swizzled

    const int s = blockIdx.x, l = threadIdx.x;
    const int lr = l & 15, lg = l >> 4;

    const float* Whhs = Whh + (size_t)s * Hn * G3;
    bfu bwhh[2][12];
    #pragma unroll
    for (int ks = 0; ks < 2; ++ks)
        #pragma unroll
        for (int nt = 0; nt < 12; ++nt) {
            const float* p = Whhs + (size_t)(ks * 32 + lg * 8) * G3 + nt * 16 + lr;
            float b0 = p[0], b1 = p[G3], b2 = p[2 * G3], b3 = p[3 * G3];
            float b4 = p[4 * G3], b5 = p[5 * G3], b6 = p[6 * G3], b7 = p[7 * G3];
            bwhh[ks][nt].u[0] = cvtpk(b0, b1); bwhh[ks][nt].u[1] = cvtpk(b2, b3);
            bwhh[ks][nt].u[2] = cvtpk(b4, b5); bwhh[ks][nt].u[3] = cvtpk(b6, b7);
        }
    float bhh_l[12];
    #pragma unroll
    for (int nt = 0; nt < 12; ++nt) bhh_l[nt] = bhh[(size_t)s * G3 + nt * 16 + lr];
    float va_l[4];
    #pragma unroll
    for (int nt = 0; nt < 4; ++nt) va_l[nt] = va[(size_t)s * Hn + nt * 16 + lr];

    {
        const float* Was = Wa + (size_t)s * Hn * Hn;
        for (int r = 0; r < 64; ++r) {
            int e = l + r * 64, i = e >> 6, k = e & 63;
            *(unsigned short*)(waT + k * 128 + ((2 * i) ^ ((k & 7) << 4))) = f2bf(Was[e]);
        }
        #pragma unroll
        for (int r = 0; r < 17; ++r) hrow[l + r * 64] = 0.f;
    }
    __builtin_amdgcn_wave_barrier();

    // per-lane gi2 offsets: val[j=nt*4+rr] = gi2[s][t][day=lg*4+rr][col=nt*16+lr]
    int dayoff[4];
    #pragma unroll
    for (int rr = 0; rr < 4; ++rr) {
        int d = lg * 4 + rr; if (d > 9) d = 9;   // clamp: invalid days read day 9 (discarded)
        dayoff[rr] = d * 192 + lr;
    }
    const float* gbase = gi2 + (size_t)s * 40 * 1920;

    float val[48], valn[48];
    #pragma unroll
    for (int j = 0; j < 48; ++j) val[j] = gbase[dayoff[j & 3] + (j >> 2) * 16];

    bf8_t a0f, a1f;
    {   bfu z0; z0.u[0] = 0; z0.u[1] = 0; z0.u[2] = 0; z0.u[3] = 0; a0f = z0.v; a1f = z0.v; }

    float h[4][4], accv[4][4], den[4], m[4];
    #pragma unroll
    for (int nt = 0; nt < 4; ++nt)
        #pragma unroll
        for (int rr = 0; rr < 4; ++rr) { h[nt][rr] = 0.f; accv[nt][rr] = 0.f; }
    #pragma unroll
    for (int rr = 0; rr < 4; ++rr) { den[rr] = 0.f; m[rr] = -1e30f; }

    for (int t = 0; t < Tn; ++t) {
        f4_t acc[12];
        #pragma unroll
        for (int nt = 0; nt < 12; ++nt)
            acc[nt] = (f4_t){bhh_l[nt], bhh_l[nt], bhh_l[nt], bhh_l[nt]};
        #pragma unroll
        for (int nt = 0; nt < 12; ++nt) {
            acc[nt] = __builtin_amdgcn_mfma_f32_16x16x32_bf16(a0f, bwhh[0][nt].v, acc[nt], 0, 0, 0);
            acc[nt] = __builtin_amdgcn_mfma_f32_16x16x32_bf16(a1f, bwhh[1][nt].v, acc[nt], 0, 0, 0);
        }
        {
            const int tn = (t < Tn - 1) ? t + 1 : t;
            const float* gb = gbase + (size_t)tn * 1920;
            #pragma unroll
            for (int j = 0; j < 48; ++j) valn[j] = gb[dayoff[j & 3] + (j >> 2) * 16];
        }
        #pragma unroll
        for (int nt = 0; nt < 4; ++nt)
            #pragma unroll
            for (int rr = 0; rr < 4; ++rr) {
                float r = sigmoidf_(val[nt * 4 + rr] + acc[nt][rr]);
                float z = sigmoidf_(val[(nt + 4) * 4 + rr] + acc[nt + 4][rr]);
                float n = tanhf_(val[(nt + 8) * 4 + rr] + r * acc[nt + 8][rr]);
                h[nt][rr] = (1.f - z) * n + z * h[nt][rr];
            }
        __builtin_amdgcn_wave_barrier();
        #pragma unroll
        for (int rr = 0; rr < 4; ++rr) {
            int day = lg * 4 + rr;
            if (day < Dn) {
                #pragma unroll
                for (int nt = 0; nt < 4; ++nt) hrow[day * 68 + nt * 16 + lr] = h[nt][rr];
            }
        }
        __builtin_amdgcn_wave_barrier();
        {
            const float* hp = hrow + lr * 68 + lg * 8;
            f4_t x0 = *(const f4_t*)hp,        x1 = *(const f4_t*)(hp + 4);
            f4_t y0 = *(const f4_t*)(hp + 32), y1 = *(const f4_t*)(hp + 36);
            bfu t0, t1;
            t0.u[0] = cvtpk(x0[0], x0[1]); t0.u[1] = cvtpk(x0[2], x0[3]);
            t0.u[2] = cvtpk(x1[0], x1[1]); t0.u[3] = cvtpk(x1[2], x1[3]);
            t1.u[0] = cvtpk(y0[0], y0[1]); t1.u[1] = cvtpk(y0[2], y0[3]);
            t1.u[2] = cvtpk(y1[0], y1[1]); t1.u[3] = cvtpk(y1[2], y1[3]);
            a0f = t0.v; a1f = t1.v;
        }
        f4_t sc[4];
        #pragma unroll
        for (int nt = 0; nt < 4; ++nt) sc[nt] = (f4_t){0.f, 0.f, 0.f, 0.f};
        #pragma unroll
        for (int ks = 0; ks < 2; ++ks) {
            bf8_t av = ks ? a1f : a0f;
            #pragma unroll
            for (int nt = 0; nt < 4; ++nt) {
                bf8_t bwv = *(const bf8_t*)(waT + (nt * 16 + lr) * 128
                                            + ((ks * 64 + lg * 16) ^ ((lr & 7) << 4)));
                sc[nt] = __builtin_amdgcn_mfma_f32_16x16x32_bf16(av, bwv, sc[nt], 0, 0, 0);
            }
        }
        float pr[4];
        #pragma unroll
        for (int rr = 0; rr < 4; ++rr) {
            pr[rr] = tanhf_(sc[0][rr]) * va_l[0] + tanhf_(sc[1][rr]) * va_l[1]
                   + tanhf_(sc[2][rr]) * va_l[2] + tanhf_(sc[3][rr]) * va_l[3];
            pr[rr] += __shfl_xor(pr[rr], 1);
            pr[rr] += __shfl_xor(pr[rr], 2);
            pr[rr] += __shfl_xor(pr[rr], 4);
            pr[rr] += __shfl_xor(pr[rr], 8);
        }
        #pragma unroll
        for (int rr = 0; rr < 4; ++rr) {
            float mn = fmaxf(m[rr], pr[rr]);
            float s0 = __expf(m[rr] - mn);
            float p = __expf(pr[rr] - mn);
            den[rr] = den[rr] * s0 + p;
            #pragma unroll
            for (int nt = 0; nt < 4; ++nt)
                accv[nt][rr] = accv[nt][rr] * s0 + p * h[nt][rr];
            m[rr] = mn;
        }
        #pragma unroll
        for (int j = 0; j < 48; ++j) val[j] = valn[j];
    }
    #pragma unroll
    for (int rr = 0; rr < 4; ++rr) {
        int day = lg * 4 + rr;
        if (day < Dn) {
            float inv = 1.f / den[rr];
            #pragma unroll
            for (int nt = 0; nt < 4; ++nt)
                news[((size_t)s * Dn + day) * Hn + nt * 16 + lr] = accv[nt][rr] * inv;
        }
    }
}

// ---------------------------------------------------------------------------
// gru_small_f: day-sequence GRU (over news) -> tvec, then price GRU -> xprice.
// One 64-thread block per stock, wave-synchronous (no block barriers).
// ---------------------------------------------------------------------------
__global__ __launch_bounds__(64, 1) void gru_small_f(
    const float* __restrict__ news,
    const float* __restrict__ Wih_s, const float* __restrict__ Whh_s,
    const float* __restrict__ bih_s, const float* __restrict__ bhh_s,
    const float* __restrict__ Wa_s, const float* __restrict__ va_s,
    const float* __restrict__ price, const float* __restrict__ Wih_p,
    const float* __restrict__ Whh_p, const float* __restrict__ bih_p,
    const float* __restrict__ bhh_p, const float* __restrict__ Wa_p,
    const float* __restrict__ va_p,
    float* __restrict__ tvec, float* __restrict__ xprice)
{
    __shared__ __align__(16) unsigned char sm[60928];
    unsigned char* whh2 = sm;                         // [192][128B]
    unsigned char* wih2 = sm + 24576;                 // [192][128B]
    unsigned char* wa2 = sm + 49152;                  // [64][128B]
    float* newsL = (float*)(sm + 57600);              // [10][68]
    float* hbuf  = (float*)(sm + 60320);              // [68]
    float* priceL = (float*)(sm + 60608);             // [30]

    const int s = blockIdx.x, l = threadIdx.x;

    // ---------------- phase 2: day-sequence GRU -> tvec ----------------
    {
        const float* W2 = Whh_s + (size_t)s * Hn * G3;
        const float* X2 = Wih_s + (size_t)s * Hn * G3;
        for (int r = 0; r < 192; ++r) {
            int e = l + r * 64, i = e / G3, j = e - i * G3;
            int off = j * 128 + ((2 * i) ^ ((j & 7) << 4));
            *(unsigned short*)(whh2 + off) = f2bf(W2[e]);
            *(unsigned short*)(wih2 + off) = f2bf(X2[e]);
        }
        const float* A2 = Wa_s + (size_t)s * Hn * Hn;
        for (int r = 0; r < 64; ++r) {
            int e = l + r * 64, i = e >> 6, k = e & 63;
            *(unsigned short*)(wa2 + k * 128 + ((2 * i) ^ ((k & 7) << 4))) = f2bf(A2[e]);
        }
        #pragma unroll
        for (int d = 0; d < Dn; ++d) newsL[d * 68 + l] = news[((size_t)s * Dn + d) * Hn + l];
        hbuf[l] = 0.f;
        if (l < 4) hbuf[64 + l] = 0.f;
    }
    __builtin_amdgcn_wave_barrier();
    {
        const float bi0 = bih_s[(size_t)s * G3 + l];
        const float bi1 = bih_s[(size_t)s * G3 + 64 + l];
        const float bi2 = bih_s[(size_t)s * G3 + 128 + l];
        const float bh0 = bhh_s[(size_t)s * G3 + l];
        const float bh1 = bhh_s[(size_t)s * G3 + 64 + l];
        const float bh2 = bhh_s[(size_t)s * G3 + 128 + l];
        const float vak = va_s[(size_t)s * Hn + l];
        const int swl = (l & 7) << 4;
        float h2 = 0.f, m2 = -1e30f, den2 = 0.f, av2 = 0.f;
        for (int t = 0; t < Dn; ++t) {
            float gh0 = bh0, gh1 = bh1, gh2 = bh2;
            float gg0 = bi0, gg1 = bi1, gg2 = bi2;
            #pragma unroll
            for (int ic = 0; ic < 8; ++ic) {
                const int off = (ic * 16) ^ swl;
                f4_t hA = *(const f4_t*)&hbuf[ic * 8];
                f4_t hB = *(const f4_t*)&hbuf[ic * 8 + 4];
                f4_t nA = *(const f4_t*)&newsL[t * 68 + ic * 8];
                f4_t nB = *(const f4_t*)&newsL[t * 68 + ic * 8 + 4];
                uint4 w0 = *(const uint4*)(whh2 + l * 128 + off);
                uint4 w1 = *(const uint4*)(whh2 + (l + 64) * 128 + off);
                uint4 w2 = *(const uint4*)(whh2 + (l + 128) * 128 + off);
                uint4 x0 = *(const uint4*)(wih2 + l * 128 + off);
                uint4 x1 = *(const uint4*)(wih2 + (l + 64) * 128 + off);
                uint4 x2 = *(const uint4*)(wih2 + (l + 128) * 128 + off);
                gh0 += dot8(w0, hA, hB); gh1 += dot8(w1, hA, hB); gh2 += dot8(w2, hA, hB);
                gg0 += dot8(x0, nA, nB); gg1 += dot8(x1, nA, nB); gg2 += dot8(x2, nA, nB);
            }
            float r = sigmoidf_(gg0 + gh0);
            float z = sigmoidf_(gg1 + gh1);
            float n = tanhf_(gg2 + r * gh2);
            h2 = (1.f - z) * n + z * h2;
            __builtin_amdgcn_wave_barrier();
            hbuf[l] = h2;
            __builtin_amdgcn_wave_barrier();
            float sk = 0.f;
            #pragma unroll
            for (int ic = 0; ic < 8; ++ic) {
                const int off = (ic * 16) ^ swl;
                uint4 wv = *(const uint4*)(wa2 + l * 128 + off);
                f4_t hA = *(const f4_t*)&hbuf[ic * 8];
                f4_t hB = *(const f4_t*)&hbuf[ic * 8 + 4];
                sk += dot8(wv, hA, hB);
            }
            float term = tanhf_(sk) * vak;
            #pragma unroll
            for (int off = 32; off; off >>= 1) term += __shfl_xor(term, off);
            float mn = fmaxf(m2, term);
            float s0 = __expf(m2 - mn);
            float p = __expf(term - mn);
            den2 = den2 * s0 + p;
            av2 = av2 * s0 + p * h2;
            m2 = mn;
        }
        tvec[(size_t)s * Hn + l] = av2 / den2;
    }
    __builtin_amdgcn_wave_barrier();

    // ---------------- phase 3: price GRU -> xprice ----------------
    {
        const float* W3 = Whh_p + (size_t)s * Hn * G3;
        for (int r = 0; r < 192; ++r) {
            int e = l + r * 64, i = e / G3, j = e - i * G3;
            *(unsigned short*)(whh2 + j * 128 + ((2 * i) ^ ((j & 7) << 4))) = f2bf(W3[e]);
        }
        const float* A3 = Wa_p + (size_t)s * Hn * Hn;
        for (int r = 0; r < 64; ++r) {
            int e = l + r * 64, i = e >> 6, k = e & 63;
            *(unsigned short*)(wa2 + k * 128 + ((2 * i) ^ ((k & 7) << 4))) = f2bf(A3[e]);
        }
        if (l < 30) priceL[l] = price[(size_t)s * 30 + l];
        hbuf[l] = 0.f;
        if (l < 4) hbuf[64 + l] = 0.f;
    }
    __builtin_amdgcn_wave_barrier();
    {
        float wp[3][3];
        #pragma unroll
        for (int i = 0; i < 3; ++i)
            #pragma unroll
            for (int g = 0; g < 3; ++g)
                wp[i][g] = Wih_p[(size_t)s * 3 * G3 + i * G3 + g * 64 + l];
        const float bi0 = bih_p[(size_t)s * G3 + l];
        const float bi1 = bih_p[(size_t)s * G3 + 64 + l];
        const float bi2 = bih_p[(size_t)s * G3 + 128 + l];
        const float bh0 = bhh_p[(size_t)s * G3 + l];
        const float bh1 = bhh_p[(size_t)s * G3 + 64 + l];
        const float bh2 = bhh_p[(size_t)s * G3 + 128 + l];
        const float vak = va_p[(size_t)s * Hn + l];
        const int swl = (l & 7) << 4;
        float h3 = 0.f, m3 = -1e30f, den3 = 0.f, av3 = 0.f;
        for (int t = 0; t < Dn; ++t) {
            float x0 = priceL[t * 3], x1 = priceL[t * 3 + 1], x2 = priceL[t * 3 + 2];
            float gg0 = bi0 + x0 * wp[0][0] + x1 * wp[1][0] + x2 * wp[2][0];
            float gg1 = bi1 + x0 * wp[0][1] + x1 * wp[1][1] + x2 * wp[2][1];
            float gg2 = bi2 + x0 * wp[0][2] + x1 * wp[1][2] + x2 * wp[2][2];
            float gh0 = bh0, gh1 = bh1, gh2 = bh2;
            #pragma unroll
            for (int ic = 0; ic < 8; ++ic) {
                const int off = (ic * 16) ^ swl;
                f4_t hA = *(const f4_t*)&hbuf[ic * 8];
                f4_t hB = *(const f4_t*)&hbuf[ic * 8 + 4];
                uint4 w0 = *(const uint4*)(whh2 + l * 128 + off);
                uint4 w1 = *(const uint4*)(whh2 + (l + 64) * 128 + off);
                uint4 w2 = *(const uint4*)(whh2 + (l + 128) * 128 + off);
                gh0 += dot8(w0, hA, hB); gh1 += dot8(w1, hA, hB); gh2 += dot8(w2, hA, hB);
            }
            float r = sigmoidf_(gg0 + gh0);
            float z = sigmoidf_(gg1 + gh1);
            float n = tanhf_(gg2 + r * gh2);
            h3 = (1.f - z) * n + z * h3;
            __builtin_amdgcn_wave_barrier();
            hbuf[l] = h3;
            __builtin_amdgcn_wave_barrier();
            float sk = 0.f;
            #pragma unroll
            for (int ic = 0; ic < 8; ++ic) {
                const int off = (ic * 16) ^ swl;
                uint4 wv = *(const uint4*)(wa2 + l * 128 + off);
                f4_t hA = *(const f4_t*)&hbuf[ic * 8];
                f4_t hB = *(const f4_t*)&hbuf[ic * 8 + 4];
                sk += dot8(wv, hA, hB);
            }
            float term = tanhf_(sk) * vak;
            #pragma unroll
            for (int off = 32; off; off >>= 1) term += __shfl_xor(term, off);
            float mn = fmaxf(m3, term);
            float s0 = __expf(m3 - mn);
            float p = __expf(term - mn);
            den3 = den3 * s0 + p;
            av3 = av3 * s0 + p * h3;
            m3 = mn;
        }
        xprice[(size_t)s * Hn + l] = av3 / den3;
    }
}

// ---------------------------------------------------------------------------
// bilinear2: combined = tanh(einsum(i,kij,j->k) + bb). Block = (stock, half of
// k-range): 1000 blocks streaming the 524 MB Wb.
// ---------------------------------------------------------------------------
__global__ __launch_bounds__(256) void bilinear2(
    const float* __restrict__ Wb, const float* __restrict__ bb,
    const float* __restrict__ xprice, const float* __restrict__ tvec,
    float* __restrict__ combined)
{
    __shared__ __align__(16) float uT[Hn][32];   // [i][k_local], 8 KB
    __shared__ float tv[Hn];

    const int bid = blockIdx.x, s = bid >> 1, kh = bid & 1;
    const int tid = threadIdx.x;
    const int w = tid >> 6, l = tid & 63;
    if (tid < Hn) tv[tid] = tvec[s * Hn + tid];
    const int j4 = (l & 15) * 4;
    f4_t xq = *(const f4_t*)&xprice[s * Hn + j4];
    __syncthreads();

    const float* Wbs = Wb + (size_t)s * Hn * Hn * Hn;
    for (int g = 0; g < 128; ++g) {
        int P = kh * 2048 + w * 512 + g * 4 + (l >> 4);      // P = k*64 + i
        f4_t wv = *(const f4_t*)&Wbs[(size_t)P * Hn + j4];
        float dp = wv[0] * xq[0] + wv[1] * xq[1] + wv[2] * xq[2] + wv[3] * xq[3];
        dp += __shfl_xor(dp, 8);
        dp += __shfl_xor(dp, 4);
        dp += __shfl_xor(dp, 2);
        dp += __shfl_xor(dp, 1);
        if ((l & 15) == 0) { int k = P >> 6, i = P & 63; uT[i][k - kh * 32] = dp; }
    }
    __syncthreads();
    if (tid < 32) {
        const int k = kh * 32 + tid;
        float a = bb[s * Hn + k];
        for (int i = 0; i < Hn; i++) a += tv[i] * uT[i][tid];
        combined[s * Hn + k] = tanhf_(a);
    }
}

// ---------------------------------------------------------------------------
// qk_proj: q/k projections + per-stock blend head. One 64-thread block/stock.
// ---------------------------------------------------------------------------
__global__ __launch_bounds__(64) void qk_proj(
    const float* __restrict__ combined, const float* __restrict__ Wq,
    const float* __restrict__ bq, const float* __restrict__ Wk,
    const float* __restrict__ bk, const float* __restrict__ Wbl,
    const float* __restrict__ bbl,
    float* __restrict__ qg, float* __restrict__ kg, float* __restrict__ out1)
{
    __shared__ float cl[Hn];
    const int s = blockIdx.x, l = threadIdx.x;
    cl[l] = combined[s * Hn + l];
    __syncthreads();
    float aq = bq[l], ak = bk[l];
    for (int i = 0; i < Hn; i++) {
        float ci = cl[i];
        aq += ci * Wq[i * Hn + l];
        ak += ci * Wk[i * Hn + l];
    }
    qg[s * Hn + l] = aq; kg[s * Hn + l] = ak;
    if (l < 2) {
        float a = bbl[s * 2 + l];
        for (int i = 0; i < Hn; i++) a += cl[i] * Wbl[(size_t)s * Hn * 2 + i * 2 + l];
        out1[s * 2 + l] = tanhf_(a);
    }
}

// ---------------------------------------------------------------------------
// Cross-stock MHSA + elu head + blend + softmax.
// ---------------------------------------------------------------------------
__global__ __launch_bounds__(256) void mhsa(
    const float* __restrict__ qg, const float* __restrict__ kg,
    const float* __restrict__ combined, const float* __restrict__ Wf,
    const float* __restrict__ bfp, const float* __restrict__ out1,
    float* __restrict__ dout)
{
    __shared__ __align__(16) float ql[Hn];
    __shared__ float sl[NHn][Sn];
    __shared__ float hsum[NHn];
    __shared__ float ao[Hn];
    __shared__ float red2[8];
    __shared__ float red3[4][Hn];

    const int sq = blockIdx.x, tid = threadIdx.x;
    if (tid < Hn) ql[tid] = qg[sq * Hn + tid];
    __syncthreads();

    for (int id = tid; id < Sn * NHn; id += 256) {
        int t = id >> 2, h = id & 3;
        const float* kp = &kg[t * Hn + h * 16];
        float a = 0.f;
        #pragma unroll
        for (int x = 0; x < 16; x += 4) {
            f4_t kv = *(const f4_t*)&kp[x];
            f4_t qv = *(const f4_t*)&ql[h * 16 + x];
            a += kv[0] * qv[0] + kv[1] * qv[1] + kv[2] * qv[2] + kv[3] * qv[3];
        }
        sl[h][t] = a * 0.25f;
    }
    __syncthreads();
    for (int h = 0; h < NHn; ++h) {
        float m = -1e30f;
        for (int t = tid; t < Sn; t += 256) m = fmaxf(m, sl[h][t]);
        for (int o = 32; o; o >>= 1) m = fmaxf(m, __shfl_xor(m, o));
        if ((tid & 63) == 0) red2[tid >> 6] = m;
        __syncthreads();
        m = fmaxf(fmaxf(red2[0], red2[1]), fmaxf(red2[2], red2[3]));
        float ps = 0.f;
        for (int t = tid; t < Sn; t += 256) { float p = __expf(sl[h][t] - m); sl[h][t] = p; ps += p; }
        for (int o = 32; o; o >>= 1) ps += __shfl_xor(ps, o);
        if ((tid & 63) == 0) red2[4 + (tid >> 6)] = ps;
        __syncthreads();
        if (tid == 0) hsum[h] = red2[4] + red2[5] + red2[6] + red2[7];
        __syncthreads();
    }
    {
        const int q = tid >> 6, j = tid & 63, h = j >> 4;
        float a = 0.f;
        for (int t = q * 125; t < q * 125 + 125; ++t) a += sl[h][t] * combined[t * Hn + j];
        red3[q][j] = a;
    }
    __syncthreads();
    if (tid < Hn)
        ao[tid] = (red3[0][tid] + red3[1][tid] + red3[2][tid] + red3[3][tid]) / hsum[tid >> 4];
    __syncthreads();
    if (tid == 0) {
        float l0 = bfp[0], l1 = bfp[1];
        for (int j = 0; j < Hn; j++) { float v = ao[j]; l0 += v * Wf[j * 2]; l1 += v * Wf[j * 2 + 1]; }
        l0 = l0 > 0.f ? l0 : __expf(l0) - 1.f;
        l1 = l1 > 0.f ? l1 : __expf(l1) - 1.f;
        l0 += out1[sq * 2]; l1 += out1[sq * 2 + 1];
        float m = fmaxf(l0, l1);
        float e0 = __expf(l0 - m), e1 = __expf(l1 - m);
        float inv = 1.f / (e0 + e1);
        dout[1 + sq * 2] = e0 * inv;
        dout[2 + sq * 2] = e1 * inv;
    }
}

__global__ __launch_bounds__(512) void loss_k(float* __restrict__ dout,
                                              const int* __restrict__ label)
{
    __shared__ float red[512];
    const int tid = threadIdx.x;
    float a = 0.f;
    if (tid < Sn) {
        float p0 = dout[1 + 2 * tid], p1 = dout[2 + 2 * tid];
        float m = fmaxf(p0, p1);
        float lse = m + __logf(__expf(p0 - m) + __expf(p1 - m));
        float pl = label[tid] ? p1 : p0;
        a = -(pl - lse);
    }
    red[tid] = a;
    __syncthreads();
    for (int o = 256; o; o >>= 1) {
        if (tid < o) red[tid] += red[tid + o];
        __syncthreads();
    }
    if (tid == 0) dout[0] = red[0] / (float)Sn;
}

extern "C" void kernel_launch(void* const* d_in, const int* in_sizes, int n_in,
                              void* d_out, int out_size, void* d_ws, size_t ws_size,
                              hipStream_t stream)
{
    const float* text  = (const float*)d_in[0];
    const float* price = (const float*)d_in[1];
    const int*   label = (const int*)  d_in[2];
    const float* Wih_p = (const float*)d_in[5];
    const float* Whh_p = (const float*)d_in[6];
    const float* bih_p = (const float*)d_in[7];
    const float* bhh_p = (const float*)d_in[8];
    const float* Wa_p  = (const float*)d_in[9];
    const float* va_p  = (const float*)d_in[10];
    const float* Wih_t = (const float*)d_in[11];
    const float* Whh_t = (const float*)d_in[12];
    const float* bih_t = (const float*)d_in[13];
    const float* bhh_t = (const float*)d_in[14];
    const float* Wa_t  = (const float*)d_in[15];
    const float* va_t  = (const float*)d_in[16];
    const float* Wih_s = (const float*)d_in[17];
    const float* Whh_s = (const float*)d_in[18];
    const float* bih_s = (const float*)d_in[19];
    const float* bhh_s = (const float*)d_in[20];
    const float* Wa_s  = (const float*)d_in[21];
    const float* va_s  = (const float*)d_in[22];
    const float* Wb    = (const float*)d_in[23];
    const float* bb    = (const float*)d_in[24];
    const float* Wbl   = (const float*)d_in[25];
    const float* bbl   = (const float*)d_in[26];
    const float* Wq    = (const float*)d_in[27];
    const float* bq    = (const float*)d_in[28];
    const float* Wk    = (const float*)d_in[29];
    const float* bk    = (const float*)d_in[30];
    const float* Wf    = (const float*)d_in[31];
    const float* bf_   = (const float*)d_in[32];

    float* ws = (float*)d_ws;
    float* news     = ws;              // 320000
    float* xprice   = ws + 320000;     // 32000
    float* tvec     = ws + 352000;     // 32000
    float* combined = ws + 384000;     // 32000
    float* qg       = ws + 416000;     // 32000
    float* kg       = ws + 448000;     // 32000
    float* out1     = ws + 480000;     // 1000
    float* gi2      = ws + 481000;     // 38,400,000 floats (153.6 MB), dense
    float* dout = (float*)d_out;

    gi_gemm4<<<Sn * 5, 256, 0, stream>>>(text, Wih_t, bih_t, gi2);
    gru_text_f<<<Sn, 64, 0, stream>>>(gi2, Whh_t, bhh_t, Wa_t, va_t, news);
    gru_small_f<<<Sn, 64, 0, stream>>>(news,
                                       Wih_s, Whh_s, bih_s, bhh_s, Wa_s, va_s,
                                       price, Wih_p, Whh_p, bih_p, bhh_p, Wa_p, va_p,
                                       tvec, xprice);
    bilinear2<<<Sn * 2, 256, 0, stream>>>(Wb, bb, xprice, tvec, combined);
    qk_proj<<<Sn, 64, 0, stream>>>(combined, Wq, bq, Wk, bk, Wbl, bbl, qg, kg, out1);
    mhsa<<<Sn, 256, 0, stream>>>(qg, kg, combined, Wf, bf_, out1, dout);
    loss_k<<<1, 512, 0, stream>>>(dout, label);
}

// Round 6
// 644.572 us; speedup vs baseline: 1.3158x; 1.0288x over previous
//
#include <hip/hip_runtime.h>

#define Sn 500
#define Dn 10
#define Tn 40
#define FPn 3
#define FTn 512
#define Hn 64
#define G3 192
#define NHn 4

typedef __attribute__((ext_vector_type(8))) short bf8_t;   // 8 x bf16 bits
typedef __attribute__((ext_vector_type(4))) float f4_t;

__device__ __forceinline__ unsigned short f2bf(float f) {
    union { float f; unsigned int u; } v; v.f = f;
    unsigned int r = v.u + 0x7fffu + ((v.u >> 16) & 1u);   // round-to-nearest-even
    return (unsigned short)(r >> 16);
}
__device__ __forceinline__ float bflo(unsigned int u) {
    union { unsigned int u; float f; } v; v.u = u << 16; return v.f;
}
__device__ __forceinline__ float bfhi(unsigned int u) {
    union { unsigned int u; float f; } v; v.u = u & 0xffff0000u; return v.f;
}
__device__ __forceinline__ unsigned int cvtpk(float lo, float hi) {
    unsigned int r;
    asm("v_cvt_pk_bf16_f32 %0, %1, %2" : "=v"(r) : "v"(lo), "v"(hi));
    return r;
}
__device__ __forceinline__ float sigmoidf_(float x) { return 1.f / (1.f + __expf(-x)); }
__device__ __forceinline__ float tanhf_(float x) {
    x = fminf(15.f, fmaxf(-15.f, x));
    float e = __expf(2.f * x);
    return (e - 1.f) / (e + 1.f);
}
__device__ __forceinline__ float dot8(uint4 wv, f4_t hA, f4_t hB) {
    return bflo(wv.x) * hA[0] + bfhi(wv.x) * hA[1]
         + bflo(wv.y) * hA[2] + bfhi(wv.y) * hA[3]
         + bflo(wv.z) * hB[0] + bfhi(wv.z) * hB[1]
         + bflo(wv.w) * hB[2] + bfhi(wv.w) * hB[3];
}
union bfu { bf8_t v; unsigned int u[4]; };

// ---------------------------------------------------------------------------
// wih_prep: WT[s][col 192][k 512] bf16 = transpose+convert of Wih_t[s][k][col].
// Block = (stock, 64x64 tile). Coalesced read, LDS transpose (+1 pad),
// coalesced packed u32 write. Makes gi_gemm6's B-frag a single 16B load.
// ---------------------------------------------------------------------------
__global__ __launch_bounds__(256) void wih_prep(
    const float* __restrict__ Wih, unsigned short* __restrict__ wt)
{
    __shared__ float tile[64][65];
    const int bid = blockIdx.x;
    const int s = bid / 24, tlo = bid % 24;
    const int kt = tlo / 3, ct = tlo % 3;
    const int k0 = kt * 64, c0 = ct * 64;
    const int tid = threadIdx.x;

    const int c = tid & 63, r0 = tid >> 6;
    const float* src = Wih + ((size_t)s * FTn + k0) * G3 + c0 + c;
    #pragma unroll
    for (int i = 0; i < 16; ++i) {
        int r = i * 4 + r0;
        tile[c][r] = src[(size_t)r * G3];
    }
    __syncthreads();

    const int cl = tid >> 5, k2 = (tid & 31) * 2;
    unsigned int* wout = (unsigned int*)(wt + ((size_t)s * G3 + c0) * FTn + k0);
    #pragma unroll
    for (int p = 0; p < 8; ++p) {
        int col = cl + p * 8;
        wout[col * 256 + (k2 >> 1)] = cvtpk(tile[col][k2], tile[col][k2 + 1]);
    }
}

// ---------------------------------------------------------------------------
// gi_gemm6: gi2[s][t][day][col] = x @ Wih_t + bih_t.
// Block = (stock, fifth = 80 rows = 2 days), 4 waves n-split 48 cols.
// A: reg-staged into double-buffered XOR-swizzled LDS (80x32 f32/buf),
//    issue-early/write-late (T14); fully coalesced 16B loads.
// B: direct 16B bf16 fragment loads from pre-transposed WT, 1-step prefetch.
// acc[5][3]=60 VGPR, total ~111 -> no spill, no occupancy cap.
// ---------------------------------------------------------------------------
__global__ __launch_bounds__(256) void gi_gemm6(
    const float* __restrict__ text, const unsigned short* __restrict__ wt,
    const float* __restrict__ bih, float* __restrict__ gi2)
{
    __shared__ __align__(16) float Ab[2][2560];   // [80 rows][32 f32], swizzled

    const int bid = blockIdx.x;
    const int xcd = bid & 7, ix = bid >> 3;
    const int swz = (xcd < 4 ? xcd * 313 : 1252 + (xcd - 4) * 312) + ix;  // bijective, nwg=2500
    const int s = swz / 5, fi = swz % 5;
    const int tid = threadIdx.x, w = tid >> 6, l = tid & 63;
    const int lr = l & 15, kg = l >> 4;

    const float* xbase = text + ((size_t)s * 400 + fi * 80) * FTn;
    const unsigned short* wtb = wt + ((size_t)s * G3 + w * 48) * FTn;

    // A staging tasks: 640 f4-chunks (80 rows x 8 slots); thread owns c0,c1(,c2)
    const int c0 = tid, c1 = tid + 256, c2 = tid + 512;   // c2 only if tid<128

    auto aload = [&](int kk, int c) -> f4_t {
        int row = c >> 3, slot = c & 7;
        return *(const f4_t*)(xbase + (size_t)row * FTn + kk * 32 + slot * 4);
    };
    auto awrite = [&](int c, f4_t v, float* buf) {
        int row = c >> 3, slot = c & 7;
        *(f4_t*)(buf + row * 32 + ((slot ^ (row & 7)) * 4)) = v;
    };
    auto afrag = [&](const float* buf, int mt) -> bf8_t {
        int row = mt * 16 + lr;
        int sw = row & 7;
        f4_t x0 = *(const f4_t*)(buf + row * 32 + ((((kg << 1)) ^ sw) << 2));
        f4_t x1 = *(const f4_t*)(buf + row * 32 + ((((kg << 1) | 1) ^ sw) << 2));
        bfu t;
        t.u[0] = cvtpk(x0[0], x0[1]); t.u[1] = cvtpk(x0[2], x0[3]);
        t.u[2] = cvtpk(x1[0], x1[1]); t.u[3] = cvtpk(x1[2], x1[3]);
        return t.v;
    };
    auto bload = [&](int kk, int nc) -> bf8_t {
        return *(const bf8_t*)(wtb + (size_t)(nc * 16 + lr) * FTn + kk * 32 + kg * 8);
    };

    f4_t acc[5][3];
    #pragma unroll
    for (int a = 0; a < 5; a++)
        #pragma unroll
        for (int b = 0; b < 3; b++) acc[a][b] = (f4_t){0.f, 0.f, 0.f, 0.f};

    // prologue: stage kk=0, preload B(kk=0)
    f4_t a0 = aload(0, c0), a1 = aload(0, c1), a2;
    if (tid < 128) a2 = aload(0, c2);
    bf8_t bc0 = bload(0, 0), bc1 = bload(0, 1), bc2 = bload(0, 2);
    awrite(c0, a0, Ab[0]); awrite(c1, a1, Ab[0]);
    if (tid < 128) awrite(c2, a2, Ab[0]);
    __syncthreads();

    bf8_t bn0 = bc0, bn1 = bc1, bn2 = bc2;
    for (int kk = 0; kk < 16; ++kk) {
        float* cur = Ab[kk & 1];
        float* nxt = Ab[(kk & 1) ^ 1];
        if (kk < 15) {
            a0 = aload(kk + 1, c0); a1 = aload(kk + 1, c1);
            if (tid < 128) a2 = aload(kk + 1, c2);
            bn0 = bload(kk + 1, 0); bn1 = bload(kk + 1, 1); bn2 = bload(kk + 1, 2);
        }
        #pragma unroll
        for (int mt = 0; mt < 5; ++mt) {
            bf8_t af = afrag(cur, mt);
            acc[mt][0] = __builtin_amdgcn_mfma_f32_16x16x32_bf16(af, bc0, acc[mt][0], 0, 0, 0);
            acc[mt][1] = __builtin_amdgcn_mfma_f32_16x16x32_bf16(af, bc1, acc[mt][1], 0, 0, 0);
            acc[mt][2] = __builtin_amdgcn_mfma_f32_16x16x32_bf16(af, bc2, acc[mt][2], 0, 0, 0);
        }
        if (kk < 15) {
            awrite(c0, a0, nxt); awrite(c1, a1, nxt);
            if (tid < 128) awrite(c2, a2, nxt);
        }
        __syncthreads();
        bc0 = bn0; bc1 = bn1; bc2 = bn2;
    }

    const float* bihs = bih + (size_t)s * G3 + w * 48 + lr;
    #pragma unroll
    for (int nc = 0; nc < 3; ++nc) {
        const int col = w * 48 + nc * 16 + lr;
        const float bv = bihs[nc * 16];
        #pragma unroll
        for (int mt = 0; mt < 5; ++mt)
            #pragma unroll
            for (int rg = 0; rg < 4; ++rg) {
                int r = mt * 16 + kg * 4 + rg;          // 0..79
                int hi = (r >= 40);
                int day = fi * 2 + hi;
                int t = r - hi * 40;
                gi2[((size_t)(s * 40 + t) * 10 + day) * 192 + col] = acc[mt][nc][rg] + bv;
            }
    }
}

// ---------------------------------------------------------------------------
// gru_text_f: text GRU recurrence, 10 days batched in the MFMA M-dim. One
// 64-thread block per stock; Whh in VGPRs as 24 B-frags; fused online-softmax
// attention pooling -> news (global). Zero block barriers.
// ---------------------------------------------------------------------------
__global__ __launch_bounds__(64, 1) void gru_text_f(
    const float* __restrict__ gi2, const float* __restrict__ Whh,
    const float* __restrict__ bhh, const float* __restrict__ Wa,
    const float* __restrict__ va, float* __restrict__ news)
{
    __shared__ __align__(16) float hrow[16 * 68];            // [16][68]
    __shared__ __align__(16) unsigned char waT[Hn * 128];    // Wa^T bf16 swizzled

    const int s = blockIdx.x, l = threadIdx.x;
    const int lr = l & 15, lg = l >> 4;

    const float* Whhs = Whh + (size_t)s * Hn * G3;
    bfu bwhh[2][12];
    #pragma unroll
    for (int ks = 0; ks < 2; ++ks)
        #pragma unroll
        for (int nt = 0; nt < 12; ++nt) {
            const float* p = Whhs + (size_t)(ks * 32 + lg * 8) * G3 + nt * 16 + lr;
            float b0 = p[0], b1 = p[G3], b2 = p[2 * G3], b3 = p[3 * G3];
            float b4 = p[4 * G3], b5 = p[5 * G3], b6 = p[6 * G3], b7 = p[7 * G3];
            bwhh[ks][nt].u[0] = cvtpk(b0, b1); bwhh[ks][nt].u[1] = cvtpk(b2, b3);
            bwhh[ks][nt].u[2] = cvtpk(b4, b5); bwhh[ks][nt].u[3] = cvtpk(b6, b7);
        }
    float bhh_l[12];
    #pragma unroll
    for (int nt = 0; nt < 12; ++nt) bhh_l[nt] = bhh[(size_t)s * G3 + nt * 16 + lr];
    float va_l[4];
    #pragma unroll
    for (int nt = 0; nt < 4; ++nt) va_l[nt] = va[(size_t)s * Hn + nt * 16 + lr];

    {
        const float* Was = Wa + (size_t)s * Hn * Hn;
        for (int r = 0; r < 64; ++r) {
            int e = l + r * 64, i = e >> 6, k = e & 63;
            *(unsigned short*)(waT + k * 128 + ((2 * i) ^ ((k & 7) << 4))) = f2bf(Was[e]);
        }
        #pragma unroll
        for (int r = 0; r < 17; ++r) hrow[l + r * 64] = 0.f;
    }
    __builtin_amdgcn_wave_barrier();

    int dayoff[4];
    #pragma unroll
    for (int rr = 0; rr < 4; ++rr) {
        int d = lg * 4 + rr; if (d > 9) d = 9;
        dayoff[rr] = d * 192 + lr;
    }
    const float* gbase = gi2 + (size_t)s * 40 * 1920;

    float val[48], valn[48];
    #pragma unroll
    for (int j = 0; j < 48; ++j) val[j] = gbase[dayoff[j & 3] + (j >> 2) * 16];

    bf8_t a0f, a1f;
    {   bfu z0; z0.u[0] = 0; z0.u[1] = 0; z0.u[2] = 0; z0.u[3] = 0; a0f = z0.v; a1f = z0.v; }

    float h[4][4], accv[4][4], den[4], m[4];
    #pragma unroll
    for (int nt = 0; nt < 4; ++nt)
        #pragma unroll
        for (int rr = 0; rr < 4; ++rr) { h[nt][rr] = 0.f; accv[nt][rr] = 0.f; }
    #pragma unroll
    for (int rr = 0; rr < 4; ++rr) { den[rr] = 0.f; m[rr] = -1e30f; }

    for (int t = 0; t < Tn; ++t) {
        f4_t acc[12];
        #pragma unroll
        for (int nt = 0; nt < 12; ++nt)
            acc[nt] = (f4_t){bhh_l[nt], bhh_l[nt], bhh_l[nt], bhh_l[nt]};
        #pragma unroll
        for (int nt = 0; nt < 12; ++nt) {
            acc[nt] = __builtin_amdgcn_mfma_f32_16x16x32_bf16(a0f, bwhh[0][nt].v, acc[nt], 0, 0, 0);
            acc[nt] = __builtin_amdgcn_mfma_f32_16x16x32_bf16(a1f, bwhh[1][nt].v, acc[nt], 0, 0, 0);
        }
        {
            const int tn = (t < Tn - 1) ? t + 1 : t;
            const float* gb = gbase + (size_t)tn * 1920;
            #pragma unroll
            for (int j = 0; j < 48; ++j) valn[j] = gb[dayoff[j & 3] + (j >> 2) * 16];
        }
        #pragma unroll
        for (int nt = 0; nt < 4; ++nt)
            #pragma unroll
            for (int rr = 0; rr < 4; ++rr) {
                float r = sigmoidf_(val[nt * 4 + rr] + acc[nt][rr]);
                float z = sigmoidf_(val[(nt + 4) * 4 + rr] + acc[nt + 4][rr]);
                float n = tanhf_(val[(nt + 8) * 4 + rr] + r * acc[nt + 8][rr]);
                h[nt][rr] = (1.f - z) * n + z * h[nt][rr];
            }
        __builtin_amdgcn_wave_barrier();
        #pragma unroll
        for (int rr = 0; rr < 4; ++rr) {
            int day = lg * 4 + rr;
            if (day < Dn) {
                #pragma unroll
                for (int nt = 0; nt < 4; ++nt) hrow[day * 68 + nt * 16 + lr] = h[nt][rr];
            }
        }
        __builtin_amdgcn_wave_barrier();
        {
            const float* hp = hrow + lr * 68 + lg * 8;
            f4_t x0 = *(const f4_t*)hp,        x1 = *(const f4_t*)(hp + 4);
            f4_t y0 = *(const f4_t*)(hp + 32), y1 = *(const f4_t*)(hp + 36);
            bfu t0, t1;
            t0.u[0] = cvtpk(x0[0], x0[1]); t0.u[1] = cvtpk(x0[2], x0[3]);
            t0.u[2] = cvtpk(x1[0], x1[1]); t0.u[3] = cvtpk(x1[2], x1[3]);
            t1.u[0] = cvtpk(y0[0], y0[1]); t1.u[1] = cvtpk(y0[2], y0[3]);
            t1.u[2] = cvtpk(y1[0], y1[1]); t1.u[3] = cvtpk(y1[2], y1[3]);
            a0f = t0.v; a1f = t1.v;
        }
        f4_t sc[4];
        #pragma unroll
        for (int nt = 0; nt < 4; ++nt) sc[nt] = (f4_t){0.f, 0.f, 0.f, 0.f};
        #pragma unroll
        for (int ks = 0; ks < 2; ++ks) {
            bf8_t av = ks ? a1f : a0f;
            #pragma unroll
            for (int nt = 0; nt < 4; ++nt) {
                bf8_t bwv = *(const bf8_t*)(waT + (nt * 16 + lr) * 128
                                            + ((ks * 64 + lg * 16) ^ ((lr & 7) << 4)));
                sc[nt] = __builtin_amdgcn_mfma_f32_16x16x32_bf16(av, bwv, sc[nt], 0, 0, 0);
            }
        }
        float pr[4];
        #pragma unroll
        for (int rr = 0; rr < 4; ++rr) {
            pr[rr] = tanhf_(sc[0][rr]) * va_l[0] + tanhf_(sc[1][rr]) * va_l[1]
                   + tanhf_(sc[2][rr]) * va_l[2] + tanhf_(sc[3][rr]) * va_l[3];
            pr[rr] += __shfl_xor(pr[rr], 1);
            pr[rr] += __shfl_xor(pr[rr], 2);
            pr[rr] += __shfl_xor(pr[rr], 4);
            pr[rr] += __shfl_xor(pr[rr], 8);
        }
        #pragma unroll
        for (int rr = 0; rr < 4; ++rr) {
            float mn = fmaxf(m[rr], pr[rr]);
            float s0 = __expf(m[rr] - mn);
            float p = __expf(pr[rr] - mn);
            den[rr] = den[rr] * s0 + p;
            #pragma unroll
            for (int nt = 0; nt < 4; ++nt)
                accv[nt][rr] = accv[nt][rr] * s0 + p * h[nt][rr];
            m[rr] = mn;
        }
        #pragma unroll
        for (int j = 0; j < 48; ++j) val[j] = valn[j];
    }
    #pragma unroll
    for (int rr = 0; rr < 4; ++rr) {
        int day = lg * 4 + rr;
        if (day < Dn) {
            float inv = 1.f / den[rr];
            #pragma unroll
            for (int nt = 0; nt < 4; ++nt)
                news[((size_t)s * Dn + day) * Hn + nt * 16 + lr] = accv[nt][rr] * inv;
        }
    }
}

// ---------------------------------------------------------------------------
// gru_small_f: day-sequence GRU (over news) -> tvec, then price GRU -> xprice.
// ---------------------------------------------------------------------------
__global__ __launch_bounds__(64, 1) void gru_small_f(
    const float* __restrict__ news,
    const float* __restrict__ Wih_s, const float* __restrict__ Whh_s,
    const float* __restrict__ bih_s, const float* __restrict__ bhh_s,
    const float* __restrict__ Wa_s, const float* __restrict__ va_s,
    const float* __restrict__ price, const float* __restrict__ Wih_p,
    const float* __restrict__ Whh_p, const float* __restrict__ bih_p,
    const float* __restrict__ bhh_p, const float* __restrict__ Wa_p,
    const float* __restrict__ va_p,
    float* __restrict__ tvec, float* __restrict__ xprice)
{
    __shared__ __align__(16) unsigned char sm[60928];
    unsigned char* whh2 = sm;                         // [192][128B]
    unsigned char* wih2 = sm + 24576;                 // [192][128B]
    unsigned char* wa2 = sm + 49152;                  // [64][128B]
    float* newsL = (float*)(sm + 57600);              // [10][68]
    float* hbuf  = (float*)(sm + 60320);              // [68]
    float* priceL = (float*)(sm + 60608);             // [30]

    const int s = blockIdx.x, l = threadIdx.x;

    {
        const float* W2 = Whh_s + (size_t)s * Hn * G3;
        const float* X2 = Wih_s + (size_t)s * Hn * G3;
        for (int r = 0; r < 192; ++r) {
            int e = l + r * 64, i = e / G3, j = e - i * G3;
            int off = j * 128 + ((2 * i) ^ ((j & 7) << 4));
            *(unsigned short*)(whh2 + off) = f2bf(W2[e]);
            *(unsigned short*)(wih2 + off) = f2bf(X2[e]);
        }
        const float* A2 = Wa_s + (size_t)s * Hn * Hn;
        for (int r = 0; r < 64; ++r) {
            int e = l + r * 64, i = e >> 6, k = e & 63;
            *(unsigned short*)(wa2 + k * 128 + ((2 * i) ^ ((k & 7) << 4))) = f2bf(A2[e]);
        }
        #pragma unroll
        for (int d = 0; d < Dn; ++d) newsL[d * 68 + l] = news[((size_t)s * Dn + d) * Hn + l];
        hbuf[l] = 0.f;
        if (l < 4) hbuf[64 + l] = 0.f;
    }
    __builtin_amdgcn_wave_barrier();
    {
        const float bi0 = bih_s[(size_t)s * G3 + l];
        const float bi1 = bih_s[(size_t)s * G3 + 64 + l];
        const float bi2 = bih_s[(size_t)s * G3 + 128 + l];
        const float bh0 = bhh_s[(size_t)s * G3 + l];
        const float bh1 = bhh_s[(size_t)s * G3 + 64 + l];
        const float bh2 = bhh_s[(size_t)s * G3 + 128 + l];
        const float vak = va_s[(size_t)s * Hn + l];
        const int swl = (l & 7) << 4;
        float h2 = 0.f, m2 = -1e30f, den2 = 0.f, av2 = 0.f;
        for (int t = 0; t < Dn; ++t) {
            float gh0 = bh0, gh1 = bh1, gh2 = bh2;
            float gg0 = bi0, gg1 = bi1, gg2 = bi2;
            #pragma unroll
            for (int ic = 0; ic < 8; ++ic) {
                const int off = (ic * 16) ^ swl;
                f4_t hA = *(const f4_t*)&hbuf[ic * 8];
                f4_t hB = *(const f4_t*)&hbuf[ic * 8 + 4];
                f4_t nA = *(const f4_t*)&newsL[t * 68 + ic * 8];
                f4_t nB = *(const f4_t*)&newsL[t * 68 + ic * 8 + 4];
                uint4 w0 = *(const uint4*)(whh2 + l * 128 + off);
                uint4 w1 = *(const uint4*)(whh2 + (l + 64) * 128 + off);
                uint4 w2 = *(const uint4*)(whh2 + (l + 128) * 128 + off);
                uint4 x0 = *(const uint4*)(wih2 + l * 128 + off);
                uint4 x1 = *(const uint4*)(wih2 + (l + 64) * 128 + off);
                uint4 x2 = *(const uint4*)(wih2 + (l + 128) * 128 + off);
                gh0 += dot8(w0, hA, hB); gh1 += dot8(w1, hA, hB); gh2 += dot8(w2, hA, hB);
                gg0 += dot8(x0, nA, nB); gg1 += dot8(x1, nA, nB); gg2 += dot8(x2, nA, nB);
            }
            float r = sigmoidf_(gg0 + gh0);
            float z = sigmoidf_(gg1 + gh1);
            float n = tanhf_(gg2 + r * gh2);
            h2 = (1.f - z) * n + z * h2;
            __builtin_amdgcn_wave_barrier();
            hbuf[l] = h2;
            __builtin_amdgcn_wave_barrier();
            float sk = 0.f;
            #pragma unroll
            for (int ic = 0; ic < 8; ++ic) {
                const int off = (ic * 16) ^ swl;
                uint4 wv = *(const uint4*)(wa2 + l * 128 + off);
                f4_t hA = *(const f4_t*)&hbuf[ic * 8];
                f4_t hB = *(const f4_t*)&hbuf[ic * 8 + 4];
                sk += dot8(wv, hA, hB);
            }
            float term = tanhf_(sk) * vak;
            #pragma unroll
            for (int off = 32; off; off >>= 1) term += __shfl_xor(term, off);
            float mn = fmaxf(m2, term);
            float s0 = __expf(m2 - mn);
            float p = __expf(term - mn);
            den2 = den2 * s0 + p;
            av2 = av2 * s0 + p * h2;
            m2 = mn;
        }
        tvec[(size_t)s * Hn + l] = av2 / den2;
    }
    __builtin_amdgcn_wave_barrier();

    {
        const float* W3 = Whh_p + (size_t)s * Hn * G3;
        for (int r = 0; r < 192; ++r) {
            int e = l + r * 64, i = e / G3, j = e - i * G3;
            *(unsigned short*)(whh2 + j * 128 + ((2 * i) ^ ((j & 7) << 4))) = f2bf(W3[e]);
        }
        const float* A3 = Wa_p + (size_t)s * Hn * Hn;
        for (int r = 0; r < 64; ++r) {
            int e = l + r * 64, i = e >> 6, k = e & 63;
            *(unsigned short*)(wa2 + k * 128 + ((2 * i) ^ ((k & 7) << 4))) = f2bf(A3[e]);
        }
        if (l < 30) priceL[l] = price[(size_t)s * 30 + l];
        hbuf[l] = 0.f;
        if (l < 4) hbuf[64 + l] = 0.f;
    }
    __builtin_amdgcn_wave_barrier();
    {
        float wp[3][3];
        #pragma unroll
        for (int i = 0; i < 3; ++i)
            #pragma unroll
            for (int g = 0; g < 3; ++g)
                wp[i][g] = Wih_p[(size_t)s * 3 * G3 + i * G3 + g * 64 + l];
        const float bi0 = bih_p[(size_t)s * G3 + l];
        const float bi1 = bih_p[(size_t)s * G3 + 64 + l];
        const float bi2 = bih_p[(size_t)s * G3 + 128 + l];
        const float bh0 = bhh_p[(size_t)s * G3 + l];
        const float bh1 = bhh_p[(size_t)s * G3 + 64 + l];
        const float bh2 = bhh_p[(size_t)s * G3 + 128 + l];
        const float vak = va_p[(size_t)s * Hn + l];
        const int swl = (l & 7) << 4;
        float h3 = 0.f, m3 = -1e30f, den3 = 0.f, av3 = 0.f;
        for (int t = 0; t < Dn; ++t) {
            float x0 = priceL[t * 3], x1 = priceL[t * 3 + 1], x2 = priceL[t * 3 + 2];
            float gg0 = bi0 + x0 * wp[0][0] + x1 * wp[1][0] + x2 * wp[2][0];
            float gg1 = bi1 + x0 * wp[0][1] + x1 * wp[1][1] + x2 * wp[2][1];
            float gg2 = bi2 + x0 * wp[0][2] + x1 * wp[1][2] + x2 * wp[2][2];
            float gh0 = bh0, gh1 = bh1, gh2 = bh2;
            #pragma unroll
            for (int ic = 0; ic < 8; ++ic) {
                const int off = (ic * 16) ^ swl;
                f4_t hA = *(const f4_t*)&hbuf[ic * 8];
                f4_t hB = *(const f4_t*)&hbuf[ic * 8 + 4];
                uint4 w0 = *(const uint4*)(whh2 + l * 128 + off);
                uint4 w1 = *(const uint4*)(whh2 + (l + 64) * 128 + off);
                uint4 w2 = *(const uint4*)(whh2 + (l + 128) * 128 + off);
                gh0 += dot8(w0, hA, hB); gh1 += dot8(w1, hA, hB); gh2 += dot8(w2, hA, hB);
            }
            float r = sigmoidf_(gg0 + gh0);
            float z = sigmoidf_(gg1 + gh1);
            float n = tanhf_(gg2 + r * gh2);
            h3 = (1.f - z) * n + z * h3;
            __builtin_amdgcn_wave_barrier();
            hbuf[l] = h3;
            __builtin_amdgcn_wave_barrier();
            float sk = 0.f;
            #pragma unroll
            for (int ic = 0; ic < 8; ++ic) {
                const int off = (ic * 16) ^ swl;
                uint4 wv = *(const uint4*)(wa2 + l * 128 + off);
                f4_t hA = *(const f4_t*)&hbuf[ic * 8];
                f4_t hB = *(const f4_t*)&hbuf[ic * 8 + 4];
                sk += dot8(wv, hA, hB);
            }
            float term = tanhf_(sk) * vak;
            #pragma unroll
            for (int off = 32; off; off >>= 1) term += __shfl_xor(term, off);
            float mn = fmaxf(m3, term);
            float s0 = __expf(m3 - mn);
            float p = __expf(term - mn);
            den3 = den3 * s0 + p;
            av3 = av3 * s0 + p * h3;
            m3 = mn;
        }
        xprice[(size_t)s * Hn + l] = av3 / den3;
    }
}

// ---------------------------------------------------------------------------
// bilinear4: combined = tanh(einsum(i,kij,j->k) + bb). Block = (stock,
// quarter of k-range): 2000 blocks for deeper latency hiding on the 524 MB
// Wb stream.
// ---------------------------------------------------------------------------
__global__ __launch_bounds__(256) void bilinear4(
    const float* __restrict__ Wb, const float* __restrict__ bb,
    const float* __restrict__ xprice, const float* __restrict__ tvec,
    float* __restrict__ combined)
{
    __shared__ __align__(16) float uT[Hn][16];
    __shared__ float tv[Hn];

    const int bid = blockIdx.x, s = bid >> 2, kq = bid & 3;
    const int tid = threadIdx.x;
    const int w = tid >> 6, l = tid & 63;
    if (tid < Hn) tv[tid] = tvec[s * Hn + tid];
    const int j4 = (l & 15) * 4;
    f4_t xq = *(const f4_t*)&xprice[s * Hn + j4];
    __syncthreads();

    const float* Wbs = Wb + (size_t)s * Hn * Hn * Hn;
    for (int g = 0; g < 64; ++g) {
        int P = kq * 1024 + w * 256 + g * 4 + (l >> 4);      // P = k*64 + i
        f4_t wv = *(const f4_t*)&Wbs[(size_t)P * Hn + j4];
        float dp = wv[0] * xq[0] + wv[1] * xq[1] + wv[2] * xq[2] + wv[3] * xq[3];
        dp += __shfl_xor(dp, 8);
        dp += __shfl_xor(dp, 4);
        dp += __shfl_xor(dp, 2);
        dp += __shfl_xor(dp, 1);
        if ((l & 15) == 0) { int k = P >> 6, i = P & 63; uT[i][k - kq * 16] = dp; }
    }
    __syncthreads();
    if (tid < 16) {
        const int k = kq * 16 + tid;
        float a = bb[s * Hn + k];
        for (int i = 0; i < Hn; i++) a += tv[i] * uT[i][tid];
        combined[s * Hn + k] = tanhf_(a);
    }
}

// ---------------------------------------------------------------------------
// qk_proj: q/k projections + per-stock blend head. One 64-thread block/stock.
// ---------------------------------------------------------------------------
__global__ __launch_bounds__(64) void qk_proj(
    const float* __restrict__ combined, const float* __restrict__ Wq,
    const float* __restrict__ bq, const float* __restrict__ Wk,
    const float* __restrict__ bk, const float* __restrict__ Wbl,
    const float* __restrict__ bbl,
    float* __restrict__ qg, float* __restrict__ kg, float* __restrict__ out1)
{
    __shared__ float cl[Hn];
    const int s = blockIdx.x, l = threadIdx.x;
    cl[l] = combined[s * Hn + l];
    __syncthreads();
    float aq = bq[l], ak = bk[l];
    for (int i = 0; i < Hn; i++) {
        float ci = cl[i];
        aq += ci * Wq[i * Hn + l];
        ak += ci * Wk[i * Hn + l];
    }
    qg[s * Hn + l] = aq; kg[s * Hn + l] = ak;
    if (l < 2) {
        float a = bbl[s * 2 + l];
        for (int i = 0; i < Hn; i++) a += cl[i] * Wbl[(size_t)s * Hn * 2 + i * 2 + l];
        out1[s * 2 + l] = tanhf_(a);
    }
}

// ---------------------------------------------------------------------------
// Cross-stock MHSA + elu head + blend + softmax.
// ---------------------------------------------------------------------------
__global__ __launch_bounds__(256) void mhsa(
    const float* __restrict__ qg, const float* __restrict__ kg,
    const float* __restrict__ combined, const float* __restrict__ Wf,
    const float* __restrict__ bfp, const float* __restrict__ out1,
    float* __restrict__ dout)
{
    __shared__ __align__(16) float ql[Hn];
    __shared__ float sl[NHn][Sn];
    __shared__ float hsum[NHn];
    __shared__ float ao[Hn];
    __shared__ float red2[8];
    __shared__ float red3[4][Hn];

    const int sq = blockIdx.x, tid = threadIdx.x;
    if (tid < Hn) ql[tid] = qg[sq * Hn + tid];
    __syncthreads();

    for (int id = tid; id < Sn * NHn; id += 256) {
        int t = id >> 2, h = id & 3;
        const float* kp = &kg[t * Hn + h * 16];
        float a = 0.f;
        #pragma unroll
        for (int x = 0; x < 16; x += 4) {
            f4_t kv = *(const f4_t*)&kp[x];
            f4_t qv = *(const f4_t*)&ql[h * 16 + x];
            a += kv[0] * qv[0] + kv[1] * qv[1] + kv[2] * qv[2] + kv[3] * qv[3];
        }
        sl[h][t] = a * 0.25f;
    }
    __syncthreads();
    for (int h = 0; h < NHn; ++h) {
        float m = -1e30f;
        for (int t = tid; t < Sn; t += 256) m = fmaxf(m, sl[h][t]);
        for (int o = 32; o; o >>= 1) m = fmaxf(m, __shfl_xor(m, o));
        if ((tid & 63) == 0) red2[tid >> 6] = m;
        __syncthreads();
        m = fmaxf(fmaxf(red2[0], red2[1]), fmaxf(red2[2], red2[3]));
        float ps = 0.f;
        for (int t = tid; t < Sn; t += 256) { float p = __expf(sl[h][t] - m); sl[h][t] = p; ps += p; }
        for (int o = 32; o; o >>= 1) ps += __shfl_xor(ps, o);
        if ((tid & 63) == 0) red2[4 + (tid >> 6)] = ps;
        __syncthreads();
        if (tid == 0) hsum[h] = red2[4] + red2[5] + red2[6] + red2[7];
        __syncthreads();
    }
    {
        const int q = tid >> 6, j = tid & 63, h = j >> 4;
        float a = 0.f;
        for (int t = q * 125; t < q * 125 + 125; ++t) a += sl[h][t] * combined[t * Hn + j];
        red3[q][j] = a;
    }
    __syncthreads();
    if (tid < Hn)
        ao[tid] = (red3[0][tid] + red3[1][tid] + red3[2][tid] + red3[3][tid]) / hsum[tid >> 4];
    __syncthreads();
    if (tid == 0) {
        float l0 = bfp[0], l1 = bfp[1];
        for (int j = 0; j < Hn; j++) { float v = ao[j]; l0 += v * Wf[j * 2]; l1 += v * Wf[j * 2 + 1]; }
        l0 = l0 > 0.f ? l0 : __expf(l0) - 1.f;
        l1 = l1 > 0.f ? l1 : __expf(l1) - 1.f;
        l0 += out1[sq * 2]; l1 += out1[sq * 2 + 1];
        float m = fmaxf(l0, l1);
        float e0 = __expf(l0 - m), e1 = __expf(l1 - m);
        float inv = 1.f / (e0 + e1);
        dout[1 + sq * 2] = e0 * inv;
        dout[2 + sq * 2] = e1 * inv;
    }
}

__global__ __launch_bounds__(512) void loss_k(float* __restrict__ dout,
                                              const int* __restrict__ label)
{
    __shared__ float red[512];
    const int tid = threadIdx.x;
    float a = 0.f;
    if (tid < Sn) {
        float p0 = dout[1 + 2 * tid], p1 = dout[2 + 2 * tid];
        float m = fmaxf(p0, p1);
        float lse = m + __logf(__expf(p0 - m) + __expf(p1 - m));
        float pl = label[tid] ? p1 : p0;
        a = -(pl - lse);
    }
    red[tid] = a;
    __syncthreads();
    for (int o = 256; o; o >>= 1) {
        if (tid < o) red[tid] += red[tid + o];
        __syncthreads();
    }
    if (tid == 0) dout[0] = red[0] / (float)Sn;
}

extern "C" void kernel_launch(void* const* d_in, const int* in_sizes, int n_in,
                              void* d_out, int out_size, void* d_ws, size_t ws_size,
                              hipStream_t stream)
{
    const float* text  = (const float*)d_in[0];
    const float* price = (const float*)d_in[1];
    const int*   label = (const int*)  d_in[2];
    const float* Wih_p = (const float*)d_in[5];
    const float* Whh_p = (const float*)d_in[6];
    const float* bih_p = (const float*)d_in[7];
    const float* bhh_p = (const float*)d_in[8];
    const float* Wa_p  = (const float*)d_in[9];
    const float* va_p  = (const float*)d_in[10];
    const float* Wih_t = (const float*)d_in[11];
    const float* Whh_t = (const float*)d_in[12];
    const float* bih_t = (const float*)d_in[13];
    const float* bhh_t = (const float*)d_in[14];
    const float* Wa_t  = (const float*)d_in[15];
    const float* va_t  = (const float*)d_in[16];
    const float* Wih_s = (const float*)d_in[17];
    const float* Whh_s = (const float*)d_in[18];
    const float* bih_s = (const float*)d_in[19];
    const float* bhh_s = (const float*)d_in[20];
    const float* Wa_s  = (const float*)d_in[21];
    const float* va_s  = (const float*)d_in[22];
    const float* Wb    = (const float*)d_in[23];
    const float* bb    = (const float*)d_in[24];
    const float* Wbl   = (const float*)d_in[25];
    const float* bbl   = (const float*)d_in[26];
    const float* Wq    = (const float*)d_in[27];
    const float* bq    = (const float*)d_in[28];
    const float* Wk    = (const float*)d_in[29];
    const float* bk    = (const float*)d_in[30];
    const float* Wf    = (const float*)d_in[31];
    const float* bf_   = (const float*)d_in[32];

    float* ws = (float*)d_ws;
    float* news     = ws;              // 320000
    float* xprice   = ws + 320000;     // 32000
    float* tvec     = ws + 352000;     // 32000
    float* combined = ws + 384000;     // 32000
    float* qg       = ws + 416000;     // 32000
    float* kg       = ws + 448000;     // 32000
    float* out1     = ws + 480000;     // 1000
    float* gi2      = ws + 481000;     // 38,400,000 floats (153.6 MB), dense
    unsigned short* wt = (unsigned short*)(ws + 481000 + 38400000);  // 49,152,000 bf16 (98.3 MB)
    float* dout = (float*)d_out;

    wih_prep<<<Sn * 24, 256, 0, stream>>>(Wih_t, wt);
    gi_gemm6<<<Sn * 5, 256, 0, stream>>>(text, wt, bih_t, gi2);
    gru_text_f<<<Sn, 64, 0, stream>>>(gi2, Whh_t, bhh_t, Wa_t, va_t, news);
    gru_small_f<<<Sn, 64, 0, stream>>>(news,
                                       Wih_s, Whh_s, bih_s, bhh_s, Wa_s, va_s,
                                       price, Wih_p, Whh_p, bih_p, bhh_p, Wa_p, va_p,
                                       tvec, xprice);
    bilinear4<<<Sn * 4, 256, 0, stream>>>(Wb, bb, xprice, tvec, combined);
    qk_proj<<<Sn, 64, 0, stream>>>(combined, Wq, bq, Wk, bk, Wbl, bbl, qg, kg, out1);
    mhsa<<<Sn, 256, 0, stream>>>(qg, kg, combined, Wf, bf_, out1, dout);
    loss_k<<<1, 512, 0, stream>>>(dout, label);
}

// Round 7
// 638.216 us; speedup vs baseline: 1.3289x; 1.0100x over previous
//
#include <hip/hip_runtime.h>

#define Sn 500
#define Dn 10
#define Tn 40
#define FPn 3
#define FTn 512
#define Hn 64
#define G3 192
#define NHn 4

typedef __attribute__((ext_vector_type(8))) short bf8_t;   // 8 x bf16 bits
typedef __attribute__((ext_vector_type(4))) float f4_t;

__device__ __forceinline__ unsigned short f2bf(float f) {
    union { float f; unsigned int u; } v; v.f = f;
    unsigned int r = v.u + 0x7fffu + ((v.u >> 16) & 1u);
    return (unsigned short)(r >> 16);
}
__device__ __forceinline__ float bflo(unsigned int u) {
    union { unsigned int u; float f; } v; v.u = u << 16; return v.f;
}
__device__ __forceinline__ float bfhi(unsigned int u) {
    union { unsigned int u; float f; } v; v.u = u & 0xffff0000u; return v.f;
}
__device__ __forceinline__ unsigned int cvtpk(float lo, float hi) {
    unsigned int r;
    asm("v_cvt_pk_bf16_f32 %0, %1, %2" : "=v"(r) : "v"(lo), "v"(hi));
    return r;
}
__device__ __forceinline__ float sigmoidf_(float x) { return 1.f / (1.f + __expf(-x)); }
__device__ __forceinline__ float tanhf_(float x) {
    x = fminf(15.f, fmaxf(-15.f, x));
    float e = __expf(2.f * x);
    return (e - 1.f) / (e + 1.f);
}
__device__ __forceinline__ float dot8(uint4 wv, f4_t hA, f4_t hB) {
    return bflo(wv.x) * hA[0] + bfhi(wv.x) * hA[1]
         + bflo(wv.y) * hA[2] + bfhi(wv.y) * hA[3]
         + bflo(wv.z) * hB[0] + bfhi(wv.z) * hB[1]
         + bflo(wv.w) * hB[2] + bfhi(wv.w) * hB[3];
}
union bfu { bf8_t v; unsigned int u[4]; };

// ---------------------------------------------------------------------------
// prep_fused: blocks [0,12000): transpose+convert Wih_t into
//   wt2[s][kc=k/8][col][k&7] bf16  (B-frag = one fully-coalesced 16B load).
// blocks [12000,12500): price GRU -> xprice (64 active threads).
// ---------------------------------------------------------------------------
__global__ __launch_bounds__(256) void prep_fused(
    const float* __restrict__ Wih, unsigned short* __restrict__ wt,
    const float* __restrict__ price, const float* __restrict__ Wih_p,
    const float* __restrict__ Whh_p, const float* __restrict__ bih_p,
    const float* __restrict__ bhh_p, const float* __restrict__ Wa_p,
    const float* __restrict__ va_p, float* __restrict__ xprice)
{
    __shared__ float tile[64][65];                     // wih path
    __shared__ __align__(16) unsigned char smp[33160]; // price path

    const int bid = blockIdx.x, tid = threadIdx.x;

    if (bid < 12000) {
        const int s = bid / 24, tlo = bid % 24;
        const int kt = tlo / 3, ct = tlo % 3;
        const int k0 = kt * 64, c0 = ct * 64;

        const int c = tid & 63, r0 = tid >> 6;
        const float* src = Wih + ((size_t)s * FTn + k0) * G3 + c0 + c;
        #pragma unroll
        for (int i = 0; i < 16; ++i) {
            int r = i * 4 + r0;
            tile[c][r] = src[(size_t)r * G3];
        }
        __syncthreads();

        const int cl = tid >> 5, k2 = (tid & 31) * 2;
        unsigned int* wo = (unsigned int*)wt;
        const int kc = (k0 >> 3) + (k2 >> 3), e2 = (k2 & 7) >> 1;
        #pragma unroll
        for (int p = 0; p < 8; ++p) {
            int col = cl + p * 8;
            wo[(size_t)s * 49152 + ((size_t)kc * G3 + c0 + col) * 4 + e2] =
                cvtpk(tile[col][k2], tile[col][k2 + 1]);
        }
        return;
    }

    // ---- price GRU ----
    const int s = bid - 12000;
    if (tid >= 64) return;
    const int l = tid;
    unsigned char* whh2 = smp;                    // [192][128B]
    unsigned char* wa2 = smp + 24576;             // [64][128B]
    float* hbuf = (float*)(smp + 32768);          // [68]
    float* priceL = (float*)(smp + 33040);        // [30]

    {
        const float* W3 = Whh_p + (size_t)s * Hn * G3;
        for (int r = 0; r < 192; ++r) {
            int e = l + r * 64, i = e / G3, j = e - i * G3;
            *(unsigned short*)(whh2 + j * 128 + ((2 * i) ^ ((j & 7) << 4))) = f2bf(W3[e]);
        }
        const float* A3 = Wa_p + (size_t)s * Hn * Hn;
        for (int r = 0; r < 64; ++r) {
            int e = l + r * 64, i = e >> 6, k = e & 63;
            *(unsigned short*)(wa2 + k * 128 + ((2 * i) ^ ((k & 7) << 4))) = f2bf(A3[e]);
        }
        if (l < 30) priceL[l] = price[(size_t)s * 30 + l];
        hbuf[l] = 0.f;
        if (l < 4) hbuf[64 + l] = 0.f;
    }
    __builtin_amdgcn_wave_barrier();
    {
        float wp[3][3];
        #pragma unroll
        for (int i = 0; i < 3; ++i)
            #pragma unroll
            for (int g = 0; g < 3; ++g)
                wp[i][g] = Wih_p[(size_t)s * 3 * G3 + i * G3 + g * 64 + l];
        const float bi0 = bih_p[(size_t)s * G3 + l];
        const float bi1 = bih_p[(size_t)s * G3 + 64 + l];
        const float bi2 = bih_p[(size_t)s * G3 + 128 + l];
        const float bh0 = bhh_p[(size_t)s * G3 + l];
        const float bh1 = bhh_p[(size_t)s * G3 + 64 + l];
        const float bh2 = bhh_p[(size_t)s * G3 + 128 + l];
        const float vak = va_p[(size_t)s * Hn + l];
        const int swl = (l & 7) << 4;
        float h3 = 0.f, m3 = -1e30f, den3 = 0.f, av3 = 0.f;
        for (int t = 0; t < Dn; ++t) {
            float x0 = priceL[t * 3], x1 = priceL[t * 3 + 1], x2 = priceL[t * 3 + 2];
            float gg0 = bi0 + x0 * wp[0][0] + x1 * wp[1][0] + x2 * wp[2][0];
            float gg1 = bi1 + x0 * wp[0][1] + x1 * wp[1][1] + x2 * wp[2][1];
            float gg2 = bi2 + x0 * wp[0][2] + x1 * wp[1][2] + x2 * wp[2][2];
            float gh0 = bh0, gh1 = bh1, gh2 = bh2;
            #pragma unroll
            for (int ic = 0; ic < 8; ++ic) {
                const int off = (ic * 16) ^ swl;
                f4_t hA = *(const f4_t*)&hbuf[ic * 8];
                f4_t hB = *(const f4_t*)&hbuf[ic * 8 + 4];
                uint4 w0 = *(const uint4*)(whh2 + l * 128 + off);
                uint4 w1 = *(const uint4*)(whh2 + (l + 64) * 128 + off);
                uint4 w2 = *(const uint4*)(whh2 + (l + 128) * 128 + off);
                gh0 += dot8(w0, hA, hB); gh1 += dot8(w1, hA, hB); gh2 += dot8(w2, hA, hB);
            }
            float r = sigmoidf_(gg0 + gh0);
            float z = sigmoidf_(gg1 + gh1);
            float n = tanhf_(gg2 + r * gh2);
            h3 = (1.f - z) * n + z * h3;
            __builtin_amdgcn_wave_barrier();
            hbuf[l] = h3;
            __builtin_amdgcn_wave_barrier();
            float sk = 0.f;
            #pragma unroll
            for (int ic = 0; ic < 8; ++ic) {
                const int off = (ic * 16) ^ swl;
                uint4 wv = *(const uint4*)(wa2 + l * 128 + off);
                f4_t hA = *(const f4_t*)&hbuf[ic * 8];
                f4_t hB = *(const f4_t*)&hbuf[ic * 8 + 4];
                sk += dot8(wv, hA, hB);
            }
            float term = tanhf_(sk) * vak;
            #pragma unroll
            for (int off = 32; off; off >>= 1) term += __shfl_xor(term, off);
            float mn = fmaxf(m3, term);
            float s0 = __expf(m3 - mn);
            float p = __expf(term - mn);
            den3 = den3 * s0 + p;
            av3 = av3 * s0 + p * h3;
            m3 = mn;
        }
        xprice[(size_t)s * Hn + l] = av3 / den3;
    }
}

// ---------------------------------------------------------------------------
// main_fused: 4500 blocks in 500 groups of 9 (one group per stock):
//   sub 0..4  -> gi GEMM fifth (80 rows), BK=64, bf16 dbuf swizzled LDS
//   sub 5..8  -> bilinearA quarter: u[s][k][i] = sum_j Wb[s,k,i,j]*xprice[j]
// Two independent HBM streams co-resident -> combined BW utilization.
// ---------------------------------------------------------------------------
__global__ __launch_bounds__(256) void main_fused(
    const float* __restrict__ text, const unsigned short* __restrict__ wt,
    const float* __restrict__ bih, float* __restrict__ gi2,
    const float* __restrict__ Wb, const float* __restrict__ xprice,
    float* __restrict__ u)
{
    __shared__ __align__(16) unsigned char sm[20480];

    const int id = blockIdx.x;
    const int grp = id / 9, sub = id - grp * 9;
    const int tid = threadIdx.x, w = tid >> 6, l = tid & 63;

    if (sub < 5) {
        // ================= gi GEMM =================
        const int s = grp, fi = sub;
        const int lr = l & 15, kg = l >> 4;
        unsigned short* Ab0 = (unsigned short*)sm;          // [80][64] bf16 swz
        unsigned short* Ab1 = Ab0 + 5120;

        const float* xbase = text + ((size_t)s * 400 + fi * 80) * FTn;
        const unsigned short* wtb = wt + (size_t)s * 98304 + (size_t)(w * 48 + lr) * 8;

        const int c0 = tid, c1 = tid + 256, c2 = tid + 512;  // tasks of 640

        f4_t acc[5][3];
        #pragma unroll
        for (int a = 0; a < 5; a++)
            #pragma unroll
            for (int b = 0; b < 3; b++) acc[a][b] = (f4_t){0.f, 0.f, 0.f, 0.f};

        f4_t pa[3], pb[3];
        auto aload = [&](int kk) {
            #pragma unroll
            for (int q = 0; q < 3; ++q) {
                int c = tid + q * 256;
                if (q < 2 || tid < 128) {
                    int row = c >> 3, slot = c & 7;
                    const float* p = xbase + (size_t)row * FTn + kk * 64 + slot * 8;
                    pa[q] = *(const f4_t*)p; pb[q] = *(const f4_t*)(p + 4);
                }
            }
        };
        auto awrite = [&](unsigned short* buf) {
            #pragma unroll
            for (int q = 0; q < 3; ++q) {
                int c = tid + q * 256;
                if (q < 2 || tid < 128) {
                    int row = c >> 3, slot = c & 7;
                    uint4 uu = { cvtpk(pa[q][0], pa[q][1]), cvtpk(pa[q][2], pa[q][3]),
                                 cvtpk(pb[q][0], pb[q][1]), cvtpk(pb[q][2], pb[q][3]) };
                    *(uint4*)(buf + row * 64 + ((slot ^ (row & 7)) * 8)) = uu;
                }
            }
        };
        auto bload = [&](int kk, int ks, int nc) -> bf8_t {
            return *(const bf8_t*)(wtb + (size_t)((kk * 8 + ks * 4 + kg) * G3 + nc * 16) * 8);
        };
        auto afrag = [&](const unsigned short* buf, int mt, int ks) -> bf8_t {
            int row = mt * 16 + lr;
            int slot = (ks * 4 + kg) ^ (row & 7);
            return *(const bf8_t*)(buf + row * 64 + slot * 8);
        };

        bf8_t bc[2][3], bn[2][3];
        aload(0);
        #pragma unroll
        for (int ks = 0; ks < 2; ++ks)
            #pragma unroll
            for (int nc = 0; nc < 3; ++nc) bc[ks][nc] = bload(0, ks, nc);
        awrite(Ab0);
        __syncthreads();

        for (int kk = 0; kk < 8; ++kk) {
            unsigned short* cur = (kk & 1) ? Ab1 : Ab0;
            unsigned short* nxt = (kk & 1) ? Ab0 : Ab1;
            if (kk < 7) {
                aload(kk + 1);
                #pragma unroll
                for (int ks = 0; ks < 2; ++ks)
                    #pragma unroll
                    for (int nc = 0; nc < 3; ++nc) bn[ks][nc] = bload(kk + 1, ks, nc);
            }
            #pragma unroll
            for (int ks = 0; ks < 2; ++ks)
                #pragma unroll
                for (int mt = 0; mt < 5; ++mt) {
                    bf8_t af = afrag(cur, mt, ks);
                    acc[mt][0] = __builtin_amdgcn_mfma_f32_16x16x32_bf16(af, bc[ks][0], acc[mt][0], 0, 0, 0);
                    acc[mt][1] = __builtin_amdgcn_mfma_f32_16x16x32_bf16(af, bc[ks][1], acc[mt][1], 0, 0, 0);
                    acc[mt][2] = __builtin_amdgcn_mfma_f32_16x16x32_bf16(af, bc[ks][2], acc[mt][2], 0, 0, 0);
                }
            if (kk < 7) awrite(nxt);
            __syncthreads();
            #pragma unroll
            for (int ks = 0; ks < 2; ++ks)
                #pragma unroll
                for (int nc = 0; nc < 3; ++nc) bc[ks][nc] = bn[ks][nc];
        }

        const float* bihs = bih + (size_t)s * G3 + w * 48 + lr;
        #pragma unroll
        for (int nc = 0; nc < 3; ++nc) {
            const int col = w * 48 + nc * 16 + lr;
            const float bv = bihs[nc * 16];
            #pragma unroll
            for (int mt = 0; mt < 5; ++mt)
                #pragma unroll
                for (int rg = 0; rg < 4; ++rg) {
                    int r = mt * 16 + kg * 4 + rg;      // 0..79
                    int hi = (r >= 40);
                    int day = fi * 2 + hi;
                    int t = r - hi * 40;
                    gi2[((size_t)(s * 40 + t) * 10 + day) * 192 + col] = acc[mt][nc][rg] + bv;
                }
        }
    } else {
        // ================= bilinearA =================
        const int s = grp, kq = sub - 5;
        float* uT = (float*)sm;                       // [64][17] pad
        const int j4 = (l & 15) * 4;
        f4_t xq = *(const f4_t*)&xprice[s * Hn + j4];

        const float* Wbs = Wb + (size_t)s * Hn * Hn * Hn;
        for (int g = 0; g < 64; ++g) {
            int P = kq * 1024 + w * 256 + g * 4 + (l >> 4);   // P = k*64 + i
            f4_t wv = *(const f4_t*)&Wbs[(size_t)P * Hn + j4];
            float dp = wv[0] * xq[0] + wv[1] * xq[1] + wv[2] * xq[2] + wv[3] * xq[3];
            dp += __shfl_xor(dp, 8);
            dp += __shfl_xor(dp, 4);
            dp += __shfl_xor(dp, 2);
            dp += __shfl_xor(dp, 1);
            if ((l & 15) == 0) { int k = P >> 6, i = P & 63; uT[i * 17 + (k - kq * 16)] = dp; }
        }
        __syncthreads();
        #pragma unroll
        for (int r = 0; r < 4; ++r) {
            int flat = tid + r * 256;
            int kr = flat >> 6, i = flat & 63;
            u[((size_t)s * 64 + kq * 16 + kr) * 64 + i] = uT[i * 17 + kr];
        }
    }
}

// ---------------------------------------------------------------------------
// gru_text_f: text GRU recurrence, 10 days batched in MFMA M-dim; Whh in
// VGPRs; fused online-softmax pooling -> news. Zero block barriers. T5 setprio.
// ---------------------------------------------------------------------------
__global__ __launch_bounds__(64, 1) void gru_text_f(
    const float* __restrict__ gi2, const float* __restrict__ Whh,
    const float* __restrict__ bhh, const float* __restrict__ Wa,
    const float* __restrict__ va, float* __restrict__ news)
{
    __shared__ __align__(16) float hrow[16 * 68];
    __shared__ __align__(16) unsigned char waT[Hn * 128];

    const int s = blockIdx.x, l = threadIdx.x;
    const int lr = l & 15, lg = l >> 4;

    const float* Whhs = Whh + (size_t)s * Hn * G3;
    bfu bwhh[2][12];
    #pragma unroll
    for (int ks = 0; ks < 2; ++ks)
        #pragma unroll
        for (int nt = 0; nt < 12; ++nt) {
            const float* p = Whhs + (size_t)(ks * 32 + lg * 8) * G3 + nt * 16 + lr;
            float b0 = p[0], b1 = p[G3], b2 = p[2 * G3], b3 = p[3 * G3];
            float b4 = p[4 * G3], b5 = p[5 * G3], b6 = p[6 * G3], b7 = p[7 * G3];
            bwhh[ks][nt].u[0] = cvtpk(b0, b1); bwhh[ks][nt].u[1] = cvtpk(b2, b3);
            bwhh[ks][nt].u[2] = cvtpk(b4, b5); bwhh[ks][nt].u[3] = cvtpk(b6, b7);
        }
    float bhh_l[12];
    #pragma unroll
    for (int nt = 0; nt < 12; ++nt) bhh_l[nt] = bhh[(size_t)s * G3 + nt * 16 + lr];
    float va_l[4];
    #pragma unroll
    for (int nt = 0; nt < 4; ++nt) va_l[nt] = va[(size_t)s * Hn + nt * 16 + lr];

    {
        const float* Was = Wa + (size_t)s * Hn * Hn;
        for (int r = 0; r < 64; ++r) {
            int e = l + r * 64, i = e >> 6, k = e & 63;
            *(unsigned short*)(waT + k * 128 + ((2 * i) ^ ((k & 7) << 4))) = f2bf(Was[e]);
        }
        #pragma unroll
        for (int r = 0; r < 17; ++r) hrow[l + r * 64] = 0.f;
    }
    __builtin_amdgcn_wave_barrier();

    int dayoff[4];
    #pragma unroll
    for (int rr = 0; rr < 4; ++rr) {
        int d = lg * 4 + rr; if (d > 9) d = 9;
        dayoff[rr] = d * 192 + lr;
    }
    const float* gbase = gi2 + (size_t)s * 40 * 1920;

    float val[48], valn[48];
    #pragma unroll
    for (int j = 0; j < 48; ++j) val[j] = gbase[dayoff[j & 3] + (j >> 2) * 16];

    bf8_t a0f, a1f;
    {   bfu z0; z0.u[0] = 0; z0.u[1] = 0; z0.u[2] = 0; z0.u[3] = 0; a0f = z0.v; a1f = z0.v; }

    float h[4][4], accv[4][4], den[4], m[4];
    #pragma unroll
    for (int nt = 0; nt < 4; ++nt)
        #pragma unroll
        for (int rr = 0; rr < 4; ++rr) { h[nt][rr] = 0.f; accv[nt][rr] = 0.f; }
    #pragma unroll
    for (int rr = 0; rr < 4; ++rr) { den[rr] = 0.f; m[rr] = -1e30f; }

    for (int t = 0; t < Tn; ++t) {
        f4_t acc[12];
        #pragma unroll
        for (int nt = 0; nt < 12; ++nt)
            acc[nt] = (f4_t){bhh_l[nt], bhh_l[nt], bhh_l[nt], bhh_l[nt]};
        __builtin_amdgcn_s_setprio(1);
        #pragma unroll
        for (int nt = 0; nt < 12; ++nt) {
            acc[nt] = __builtin_amdgcn_mfma_f32_16x16x32_bf16(a0f, bwhh[0][nt].v, acc[nt], 0, 0, 0);
            acc[nt] = __builtin_amdgcn_mfma_f32_16x16x32_bf16(a1f, bwhh[1][nt].v, acc[nt], 0, 0, 0);
        }
        __builtin_amdgcn_s_setprio(0);
        {
            const int tn = (t < Tn - 1) ? t + 1 : t;
            const float* gb = gbase + (size_t)tn * 1920;
            #pragma unroll
            for (int j = 0; j < 48; ++j) valn[j] = gb[dayoff[j & 3] + (j >> 2) * 16];
        }
        #pragma unroll
        for (int nt = 0; nt < 4; ++nt)
            #pragma unroll
            for (int rr = 0; rr < 4; ++rr) {
                float r = sigmoidf_(val[nt * 4 + rr] + acc[nt][rr]);
                float z = sigmoidf_(val[(nt + 4) * 4 + rr] + acc[nt + 4][rr]);
                float n = tanhf_(val[(nt + 8) * 4 + rr] + r * acc[nt + 8][rr]);
                h[nt][rr] = (1.f - z) * n + z * h[nt][rr];
            }
        __builtin_amdgcn_wave_barrier();
        #pragma unroll
        for (int rr = 0; rr < 4; ++rr) {
            int day = lg * 4 + rr;
            if (day < Dn) {
                #pragma unroll
                for (int nt = 0; nt < 4; ++nt) hrow[day * 68 + nt * 16 + lr] = h[nt][rr];
            }
        }
        __builtin_amdgcn_wave_barrier();
        {
            const float* hp = hrow + lr * 68 + lg * 8;
            f4_t x0 = *(const f4_t*)hp,        x1 = *(const f4_t*)(hp + 4);
            f4_t y0 = *(const f4_t*)(hp + 32), y1 = *(const f4_t*)(hp + 36);
            bfu t0, t1;
            t0.u[0] = cvtpk(x0[0], x0[1]); t0.u[1] = cvtpk(x0[2], x0[3]);
            t0.u[2] = cvtpk(x1[0], x1[1]); t0.u[3] = cvtpk(x1[2], x1[3]);
            t1.u[0] = cvtpk(y0[0], y0[1]); t1.u[1] = cvtpk(y0[2], y0[3]);
            t1.u[2] = cvtpk(y1[0], y1[1]); t1.u[3] = cvtpk(y1[2], y1[3]);
            a0f = t0.v; a1f = t1.v;
        }
        f4_t sc[4];
        #pragma unroll
        for (int nt = 0; nt < 4; ++nt) sc[nt] = (f4_t){0.f, 0.f, 0.f, 0.f};
        __builtin_amdgcn_s_setprio(1);
        #pragma unroll
        for (int ks = 0; ks < 2; ++ks) {
            bf8_t av = ks ? a1f : a0f;
            #pragma unroll
            for (int nt = 0; nt < 4; ++nt) {
                bf8_t bwv = *(const bf8_t*)(waT + (nt * 16 + lr) * 128
                                            + ((ks * 64 + lg * 16) ^ ((lr & 7) << 4)));
                sc[nt] = __builtin_amdgcn_mfma_f32_16x16x32_bf16(av, bwv, sc[nt], 0, 0, 0);
            }
        }
        __builtin_amdgcn_s_setprio(0);
        float pr[4];
        #pragma unroll
        for (int rr = 0; rr < 4; ++rr) {
            pr[rr] = tanhf_(sc[0][rr]) * va_l[0] + tanhf_(sc[1][rr]) * va_l[1]
                   + tanhf_(sc[2][rr]) * va_l[2] + tanhf_(sc[3][rr]) * va_l[3];
            pr[rr] += __shfl_xor(pr[rr], 1);
            pr[rr] += __shfl_xor(pr[rr], 2);
            pr[rr] += __shfl_xor(pr[rr], 4);
            pr[rr] += __shfl_xor(pr[rr], 8);
        }
        #pragma unroll
        for (int rr = 0; rr < 4; ++rr) {
            float mn = fmaxf(m[rr], pr[rr]);
            float s0 = __expf(m[rr] - mn);
            float p = __expf(pr[rr] - mn);
            den[rr] = den[rr] * s0 + p;
            #pragma unroll
            for (int nt = 0; nt < 4; ++nt)
                accv[nt][rr] = accv[nt][rr] * s0 + p * h[nt][rr];
            m[rr] = mn;
        }
        #pragma unroll
        for (int j = 0; j < 48; ++j) val[j] = valn[j];
    }
    #pragma unroll
    for (int rr = 0; rr < 4; ++rr) {
        int day = lg * 4 + rr;
        if (day < Dn) {
            float inv = 1.f / den[rr];
            #pragma unroll
            for (int nt = 0; nt < 4; ++nt)
                news[((size_t)s * Dn + day) * Hn + nt * 16 + lr] = accv[nt][rr] * inv;
        }
    }
}

// ---------------------------------------------------------------------------
// day_finish: day-sequence GRU over news -> tvec (reg), then
// combined = tanh(tvec . u + bb), then q/k/out1. One 64-thr block per stock.
// ---------------------------------------------------------------------------
__global__ __launch_bounds__(64, 1) void day_finish(
    const float* __restrict__ news,
    const float* __restrict__ Wih_s, const float* __restrict__ Whh_s,
    const float* __restrict__ bih_s, const float* __restrict__ bhh_s,
    const float* __restrict__ Wa_s, const float* __restrict__ va_s,
    const float* __restrict__ u, const float* __restrict__ bb,
    const float* __restrict__ Wq, const float* __restrict__ bq,
    const float* __restrict__ Wk, const float* __restrict__ bk,
    const float* __restrict__ Wbl, const float* __restrict__ bbl,
    float* __restrict__ combined, float* __restrict__ qg,
    float* __restrict__ kg, float* __restrict__ out1)
{
    __shared__ __align__(16) unsigned char sm[60928];
    unsigned char* whh2 = sm;                         // [192][128B]
    unsigned char* wih2 = sm + 24576;                 // [192][128B]
    unsigned char* wa2 = sm + 49152;                  // [64][128B]
    float* newsL = (float*)(sm + 57600);              // [10][68]
    float* hbuf  = (float*)(sm + 60320);              // [68]

    const int s = blockIdx.x, l = threadIdx.x;
    float tvv;

    {
        const float* W2 = Whh_s + (size_t)s * Hn * G3;
        const float* X2 = Wih_s + (size_t)s * Hn * G3;
        for (int r = 0; r < 192; ++r) {
            int e = l + r * 64, i = e / G3, j = e - i * G3;
            int off = j * 128 + ((2 * i) ^ ((j & 7) << 4));
            *(unsigned short*)(whh2 + off) = f2bf(W2[e]);
            *(unsigned short*)(wih2 + off) = f2bf(X2[e]);
        }
        const float* A2 = Wa_s + (size_t)s * Hn * Hn;
        for (int r = 0; r < 64; ++r) {
            int e = l + r * 64, i = e >> 6, k = e & 63;
            *(unsigned short*)(wa2 + k * 128 + ((2 * i) ^ ((k & 7) << 4))) = f2bf(A2[e]);
        }
        #pragma unroll
        for (int d = 0; d < Dn; ++d) newsL[d * 68 + l] = news[((size_t)s * Dn + d) * Hn + l];
        hbuf[l] = 0.f;
        if (l < 4) hbuf[64 + l] = 0.f;
    }
    __builtin_amdgcn_wave_barrier();
    {
        const float bi0 = bih_s[(size_t)s * G3 + l];
        const float bi1 = bih_s[(size_t)s * G3 + 64 + l];
        const float bi2 = bih_s[(size_t)s * G3 + 128 + l];
        const float bh0 = bhh_s[(size_t)s * G3 + l];
        const float bh1 = bhh_s[(size_t)s * G3 + 64 + l];
        const float bh2 = bhh_s[(size_t)s * G3 + 128 + l];
        const float vak = va_s[(size_t)s * Hn + l];
        const int swl = (l & 7) << 4;
        float h2 = 0.f, m2 = -1e30f, den2 = 0.f, av2 = 0.f;
        for (int t = 0; t < Dn; ++t) {
            float gh0 = bh0, gh1 = bh1, gh2 = bh2;
            float gg0 = bi0, gg1 = bi1, gg2 = bi2;
            #pragma unroll
            for (int ic = 0; ic < 8; ++ic) {
                const int off = (ic * 16) ^ swl;
                f4_t hA = *(const f4_t*)&hbuf[ic * 8];
                f4_t hB = *(const f4_t*)&hbuf[ic * 8 + 4];
                f4_t nA = *(const f4_t*)&newsL[t * 68 + ic * 8];
                f4_t nB = *(const f4_t*)&newsL[t * 68 + ic * 8 + 4];
                uint4 w0 = *(const uint4*)(whh2 + l * 128 + off);
                uint4 w1 = *(const uint4*)(whh2 + (l + 64) * 128 + off);
                uint4 w2 = *(const uint4*)(whh2 + (l + 128) * 128 + off);
                uint4 x0 = *(const uint4*)(wih2 + l * 128 + off);
                uint4 x1 = *(const uint4*)(wih2 + (l + 64) * 128 + off);
                uint4 x2 = *(const uint4*)(wih2 + (l + 128) * 128 + off);
                gh0 += dot8(w0, hA, hB); gh1 += dot8(w1, hA, hB); gh2 += dot8(w2, hA, hB);
                gg0 += dot8(x0, nA, nB); gg1 += dot8(x1, nA, nB); gg2 += dot8(x2, nA, nB);
            }
            float r = sigmoidf_(gg0 + gh0);
            float z = sigmoidf_(gg1 + gh1);
            float n = tanhf_(gg2 + r * gh2);
            h2 = (1.f - z) * n + z * h2;
            __builtin_amdgcn_wave_barrier();
            hbuf[l] = h2;
            __builtin_amdgcn_wave_barrier();
            float sk = 0.f;
            #pragma unroll
            for (int ic = 0; ic < 8; ++ic) {
                const int off = (ic * 16) ^ swl;
                uint4 wv = *(const uint4*)(wa2 + l * 128 + off);
                f4_t hA = *(const f4_t*)&hbuf[ic * 8];
                f4_t hB = *(const f4_t*)&hbuf[ic * 8 + 4];
                sk += dot8(wv, hA, hB);
            }
            float term = tanhf_(sk) * vak;
            #pragma unroll
            for (int off = 32; off; off >>= 1) term += __shfl_xor(term, off);
            float mn = fmaxf(m2, term);
            float s0 = __expf(m2 - mn);
            float p = __expf(term - mn);
            den2 = den2 * s0 + p;
            av2 = av2 * s0 + p * h2;
            m2 = mn;
        }
        tvv = av2 / den2;
    }
    __builtin_amdgcn_wave_barrier();

    // ---- combined = tanh(tvec . u + bb); weights region now dead -> reuse
    float* uL = (float*)sm;              // [64][65]
    float* tvL = (float*)(sm + 16640);   // [64]
    float* cl  = (float*)(sm + 16960);   // [64]
    tvL[l] = tvv;
    const float* ub = u + (size_t)s * 4096;
    #pragma unroll 8
    for (int i = 0; i < 64; ++i) uL[i * 65 + l] = ub[i * 64 + l];
    __builtin_amdgcn_wave_barrier();
    {
        float a = bb[s * Hn + l];
        #pragma unroll 8
        for (int i = 0; i < 64; ++i) a += tvL[i] * uL[l * 65 + i];
        float c = tanhf_(a);
        cl[l] = c;
        combined[s * Hn + l] = c;
    }
    __builtin_amdgcn_wave_barrier();
    {
        float aq = bq[l], ak = bk[l];
        for (int i = 0; i < Hn; i++) {
            float ci = cl[i];
            aq += ci * Wq[i * Hn + l];
            ak += ci * Wk[i * Hn + l];
        }
        qg[s * Hn + l] = aq; kg[s * Hn + l] = ak;
        if (l < 2) {
            float a = bbl[s * 2 + l];
            for (int i = 0; i < Hn; i++) a += cl[i] * Wbl[(size_t)s * Hn * 2 + i * 2 + l];
            out1[s * 2 + l] = tanhf_(a);
        }
    }
}

// ---------------------------------------------------------------------------
// Cross-stock MHSA + elu head + blend + softmax.
// ---------------------------------------------------------------------------
__global__ __launch_bounds__(256) void mhsa(
    const float* __restrict__ qg, const float* __restrict__ kg,
    const float* __restrict__ combined, const float* __restrict__ Wf,
    const float* __restrict__ bfp, const float* __restrict__ out1,
    float* __restrict__ dout)
{
    __shared__ __align__(16) float ql[Hn];
    __shared__ float sl[NHn][Sn];
    __shared__ float hsum[NHn];
    __shared__ float ao[Hn];
    __shared__ float red2[8];
    __shared__ float red3[4][Hn];

    const int sq = blockIdx.x, tid = threadIdx.x;
    if (tid < Hn) ql[tid] = qg[sq * Hn + tid];
    __syncthreads();

    for (int id = tid; id < Sn * NHn; id += 256) {
        int t = id >> 2, h = id & 3;
        const float* kp = &kg[t * Hn + h * 16];
        float a = 0.f;
        #pragma unroll
        for (int x = 0; x < 16; x += 4) {
            f4_t kv = *(const f4_t*)&kp[x];
            f4_t qv = *(const f4_t*)&ql[h * 16 + x];
            a += kv[0] * qv[0] + kv[1] * qv[1] + kv[2] * qv[2] + kv[3] * qv[3];
        }
        sl[h][t] = a * 0.25f;
    }
    __syncthreads();
    for (int h = 0; h < NHn; ++h) {
        float m = -1e30f;
        for (int t = tid; t < Sn; t += 256) m = fmaxf(m, sl[h][t]);
        for (int o = 32; o; o >>= 1) m = fmaxf(m, __shfl_xor(m, o));
        if ((tid & 63) == 0) red2[tid >> 6] = m;
        __syncthreads();
        m = fmaxf(fmaxf(red2[0], red2[1]), fmaxf(red2[2], red2[3]));
        float ps = 0.f;
        for (int t = tid; t < Sn; t += 256) { float p = __expf(sl[h][t] - m); sl[h][t] = p; ps += p; }
        for (int o = 32; o; o >>= 1) ps += __shfl_xor(ps, o);
        if ((tid & 63) == 0) red2[4 + (tid >> 6)] = ps;
        __syncthreads();
        if (tid == 0) hsum[h] = red2[4] + red2[5] + red2[6] + red2[7];
        __syncthreads();
    }
    {
        const int q = tid >> 6, j = tid & 63, h = j >> 4;
        float a = 0.f;
        for (int t = q * 125; t < q * 125 + 125; ++t) a += sl[h][t] * combined[t * Hn + j];
        red3[q][j] = a;
    }
    __syncthreads();
    if (tid < Hn)
        ao[tid] = (red3[0][tid] + red3[1][tid] + red3[2][tid] + red3[3][tid]) / hsum[tid >> 4];
    __syncthreads();
    if (tid == 0) {
        float l0 = bfp[0], l1 = bfp[1];
        for (int j = 0; j < Hn; j++) { float v = ao[j]; l0 += v * Wf[j * 2]; l1 += v * Wf[j * 2 + 1]; }
        l0 = l0 > 0.f ? l0 : __expf(l0) - 1.f;
        l1 = l1 > 0.f ? l1 : __expf(l1) - 1.f;
        l0 += out1[sq * 2]; l1 += out1[sq * 2 + 1];
        float m = fmaxf(l0, l1);
        float e0 = __expf(l0 - m), e1 = __expf(l1 - m);
        float inv = 1.f / (e0 + e1);
        dout[1 + sq * 2] = e0 * inv;
        dout[2 + sq * 2] = e1 * inv;
    }
}

__global__ __launch_bounds__(512) void loss_k(float* __restrict__ dout,
                                              const int* __restrict__ label)
{
    __shared__ float red[512];
    const int tid = threadIdx.x;
    float a = 0.f;
    if (tid < Sn) {
        float p0 = dout[1 + 2 * tid], p1 = dout[2 + 2 * tid];
        float m = fmaxf(p0, p1);
        float lse = m + __logf(__expf(p0 - m) + __expf(p1 - m));
        float pl = label[tid] ? p1 : p0;
        a = -(pl - lse);
    }
    red[tid] = a;
    __syncthreads();
    for (int o = 256; o; o >>= 1) {
        if (tid < o) red[tid] += red[tid + o];
        __syncthreads();
    }
    if (tid == 0) dout[0] = red[0] / (float)Sn;
}

extern "C" void kernel_launch(void* const* d_in, const int* in_sizes, int n_in,
                              void* d_out, int out_size, void* d_ws, size_t ws_size,
                              hipStream_t stream)
{
    const float* text  = (const float*)d_in[0];
    const float* price = (const float*)d_in[1];
    const int*   label = (const int*)  d_in[2];
    const float* Wih_p = (const float*)d_in[5];
    const float* Whh_p = (const float*)d_in[6];
    const float* bih_p = (const float*)d_in[7];
    const float* bhh_p = (const float*)d_in[8];
    const float* Wa_p  = (const float*)d_in[9];
    const float* va_p  = (const float*)d_in[10];
    const float* Wih_t = (const float*)d_in[11];
    const float* Whh_t = (const float*)d_in[12];
    const float* bih_t = (const float*)d_in[13];
    const float* bhh_t = (const float*)d_in[14];
    const float* Wa_t  = (const float*)d_in[15];
    const float* va_t  = (const float*)d_in[16];
    const float* Wih_s = (const float*)d_in[17];
    const float* Whh_s = (const float*)d_in[18];
    const float* bih_s = (const float*)d_in[19];
    const float* bhh_s = (const float*)d_in[20];
    const float* Wa_s  = (const float*)d_in[21];
    const float* va_s  = (const float*)d_in[22];
    const float* Wb    = (const float*)d_in[23];
    const float* bb    = (const float*)d_in[24];
    const float* Wbl   = (const float*)d_in[25];
    const float* bbl   = (const float*)d_in[26];
    const float* Wq    = (const float*)d_in[27];
    const float* bq    = (const float*)d_in[28];
    const float* Wk    = (const float*)d_in[29];
    const float* bk    = (const float*)d_in[30];
    const float* Wf    = (const float*)d_in[31];
    const float* bf_   = (const float*)d_in[32];

    float* ws = (float*)d_ws;
    float* news     = ws;              // 320000
    float* xprice   = ws + 320000;     // 32000
    float* combined = ws + 384000;     // 32000
    float* qg       = ws + 416000;     // 32000
    float* kg       = ws + 448000;     // 32000
    float* out1     = ws + 480000;     // 1000
    float* u        = ws + 481000;     // 2,048,000 (8.2 MB)
    float* gi2      = ws + 2529000;    // 38,400,000 (153.6 MB)
    unsigned short* wt = (unsigned short*)(ws + 40929000);  // 49,152,000 bf16 (98.3 MB)
    float* dout = (float*)d_out;

    prep_fused<<<12500, 256, 0, stream>>>(Wih_t, wt,
                                          price, Wih_p, Whh_p, bih_p, bhh_p, Wa_p, va_p,
                                          xprice);
    main_fused<<<4500, 256, 0, stream>>>(text, wt, bih_t, gi2, Wb, xprice, u);
    gru_text_f<<<Sn, 64, 0, stream>>>(gi2, Whh_t, bhh_t, Wa_t, va_t, news);
    day_finish<<<Sn, 64, 0, stream>>>(news,
                                      Wih_s, Whh_s, bih_s, bhh_s, Wa_s, va_s,
                                      u, bb, Wq, bq, Wk, bk, Wbl, bbl,
                                      combined, qg, kg, out1);
    mhsa<<<Sn, 256, 0, stream>>>(qg, kg, combined, Wf, bf_, out1, dout);
    loss_k<<<1, 512, 0, stream>>>(dout, label);
}

// Round 8
// 622.871 us; speedup vs baseline: 1.3616x; 1.0246x over previous
//
#include <hip/hip_runtime.h>

#define Sn 500
#define Dn 10
#define Tn 40
#define FPn 3
#define FTn 512
#define Hn 64
#define G3 192
#define NHn 4

typedef __attribute__((ext_vector_type(8))) short bf8_t;   // 8 x bf16 bits
typedef __attribute__((ext_vector_type(4))) float f4_t;

__device__ __forceinline__ unsigned short f2bf(float f) {
    union { float f; unsigned int u; } v; v.f = f;
    unsigned int r = v.u + 0x7fffu + ((v.u >> 16) & 1u);
    return (unsigned short)(r >> 16);
}
__device__ __forceinline__ float bflo(unsigned int u) {
    union { unsigned int u; float f; } v; v.u = u << 16; return v.f;
}
__device__ __forceinline__ float bfhi(unsigned int u) {
    union { unsigned int u; float f; } v; v.u = u & 0xffff0000u; return v.f;
}
__device__ __forceinline__ unsigned int cvtpk(float lo, float hi) {
    unsigned int r;
    asm("v_cvt_pk_bf16_f32 %0, %1, %2" : "=v"(r) : "v"(lo), "v"(hi));
    return r;
}
__device__ __forceinline__ float sigmoidf_(float x) { return 1.f / (1.f + __expf(-x)); }
__device__ __forceinline__ float tanhf_(float x) {
    x = fminf(15.f, fmaxf(-15.f, x));
    float e = __expf(2.f * x);
    return (e - 1.f) / (e + 1.f);
}
__device__ __forceinline__ float dot8(uint4 wv, f4_t hA, f4_t hB) {
    return bflo(wv.x) * hA[0] + bfhi(wv.x) * hA[1]
         + bflo(wv.y) * hA[2] + bfhi(wv.y) * hA[3]
         + bflo(wv.z) * hB[0] + bfhi(wv.z) * hB[1]
         + bflo(wv.w) * hB[2] + bfhi(wv.w) * hB[3];
}
union bfu { bf8_t v; unsigned int u[4]; };

// ---------------------------------------------------------------------------
// price_gru: price GRU + attention pooling -> xprice. 500 blocks x 64 thr.
// ---------------------------------------------------------------------------
__global__ __launch_bounds__(64, 1) void price_gru(
    const float* __restrict__ price, const float* __restrict__ Wih_p,
    const float* __restrict__ Whh_p, const float* __restrict__ bih_p,
    const float* __restrict__ bhh_p, const float* __restrict__ Wa_p,
    const float* __restrict__ va_p, float* __restrict__ xprice)
{
    __shared__ __align__(16) unsigned char smp[33160];
    unsigned char* whh2 = smp;                    // [192][128B]
    unsigned char* wa2 = smp + 24576;             // [64][128B]
    float* hbuf = (float*)(smp + 32768);          // [68]
    float* priceL = (float*)(smp + 33040);        // [30]

    const int s = blockIdx.x, l = threadIdx.x;
    {
        const float* W3 = Whh_p + (size_t)s * Hn * G3;
        for (int r = 0; r < 192; ++r) {
            int e = l + r * 64, i = e / G3, j = e - i * G3;
            *(unsigned short*)(whh2 + j * 128 + ((2 * i) ^ ((j & 7) << 4))) = f2bf(W3[e]);
        }
        const float* A3 = Wa_p + (size_t)s * Hn * Hn;
        for (int r = 0; r < 64; ++r) {
            int e = l + r * 64, i = e >> 6, k = e & 63;
            *(unsigned short*)(wa2 + k * 128 + ((2 * i) ^ ((k & 7) << 4))) = f2bf(A3[e]);
        }
        if (l < 30) priceL[l] = price[(size_t)s * 30 + l];
        hbuf[l] = 0.f;
        if (l < 4) hbuf[64 + l] = 0.f;
    }
    __builtin_amdgcn_wave_barrier();
    {
        float wp[3][3];
        #pragma unroll
        for (int i = 0; i < 3; ++i)
            #pragma unroll
            for (int g = 0; g < 3; ++g)
                wp[i][g] = Wih_p[(size_t)s * 3 * G3 + i * G3 + g * 64 + l];
        const float bi0 = bih_p[(size_t)s * G3 + l];
        const float bi1 = bih_p[(size_t)s * G3 + 64 + l];
        const float bi2 = bih_p[(size_t)s * G3 + 128 + l];
        const float bh0 = bhh_p[(size_t)s * G3 + l];
        const float bh1 = bhh_p[(size_t)s * G3 + 64 + l];
        const float bh2 = bhh_p[(size_t)s * G3 + 128 + l];
        const float vak = va_p[(size_t)s * Hn + l];
        const int swl = (l & 7) << 4;
        float h3 = 0.f, m3 = -1e30f, den3 = 0.f, av3 = 0.f;
        for (int t = 0; t < Dn; ++t) {
            float x0 = priceL[t * 3], x1 = priceL[t * 3 + 1], x2 = priceL[t * 3 + 2];
            float gg0 = bi0 + x0 * wp[0][0] + x1 * wp[1][0] + x2 * wp[2][0];
            float gg1 = bi1 + x0 * wp[0][1] + x1 * wp[1][1] + x2 * wp[2][1];
            float gg2 = bi2 + x0 * wp[0][2] + x1 * wp[1][2] + x2 * wp[2][2];
            float gh0 = bh0, gh1 = bh1, gh2 = bh2;
            #pragma unroll
            for (int ic = 0; ic < 8; ++ic) {
                const int off = (ic * 16) ^ swl;
                f4_t hA = *(const f4_t*)&hbuf[ic * 8];
                f4_t hB = *(const f4_t*)&hbuf[ic * 8 + 4];
                uint4 w0 = *(const uint4*)(whh2 + l * 128 + off);
                uint4 w1 = *(const uint4*)(whh2 + (l + 64) * 128 + off);
                uint4 w2 = *(const uint4*)(whh2 + (l + 128) * 128 + off);
                gh0 += dot8(w0, hA, hB); gh1 += dot8(w1, hA, hB); gh2 += dot8(w2, hA, hB);
            }
            float r = sigmoidf_(gg0 + gh0);
            float z = sigmoidf_(gg1 + gh1);
            float n = tanhf_(gg2 + r * gh2);
            h3 = (1.f - z) * n + z * h3;
            __builtin_amdgcn_wave_barrier();
            hbuf[l] = h3;
            __builtin_amdgcn_wave_barrier();
            float sk = 0.f;
            #pragma unroll
            for (int ic = 0; ic < 8; ++ic) {
                const int off = (ic * 16) ^ swl;
                uint4 wv = *(const uint4*)(wa2 + l * 128 + off);
                f4_t hA = *(const f4_t*)&hbuf[ic * 8];
                f4_t hB = *(const f4_t*)&hbuf[ic * 8 + 4];
                sk += dot8(wv, hA, hB);
            }
            float term = tanhf_(sk) * vak;
            #pragma unroll
            for (int off = 32; off; off >>= 1) term += __shfl_xor(term, off);
            float mn = fmaxf(m3, term);
            float s0 = __expf(m3 - mn);
            float p = __expf(term - mn);
            den3 = den3 * s0 + p;
            av3 = av3 * s0 + p * h3;
            m3 = mn;
        }
        xprice[(size_t)s * Hn + l] = av3 / den3;
    }
}

// ---------------------------------------------------------------------------
// mega_fused: 6500 blocks in 500 groups of 13 (one group per stock):
//   sub 0..4  -> gi GEMM fifth (80 rows), BK=64, bf16 dbuf swizzled LDS,
//                B direct from Wih (8 strided f32 -> cvtpk, prefetched)
//   sub 5..12 -> bilinear eighth: u[s][k][i] = sum_j Wb[s,k,i,j]*xprice[j]
// XCD-bijective swizzle groups a stock's 13 blocks on one XCD (Wih L2-hot).
// ---------------------------------------------------------------------------
__global__ __launch_bounds__(256) void mega_fused(
    const float* __restrict__ text, const float* __restrict__ Wih,
    const float* __restrict__ bih, float* __restrict__ gi2,
    const float* __restrict__ Wb, const float* __restrict__ xprice,
    float* __restrict__ u)
{
    __shared__ __align__(16) unsigned char sm[20480];

    const int bid = blockIdx.x;
    const int xcd = bid & 7, ix = bid >> 3;
    // bijective XCD swizzle, nwg=6500: q=812, r=4
    const int swz = (xcd < 4 ? xcd * 813 : 3252 + (xcd - 4) * 812) + ix;
    const int grp = swz / 13, sub = swz - grp * 13;
    const int tid = threadIdx.x, w = tid >> 6, l = tid & 63;

    if (sub < 5) {
        // ================= gi GEMM =================
        const int s = grp, fi = sub;
        const int lr = l & 15, kg = l >> 4;
        unsigned short* Ab0 = (unsigned short*)sm;          // [80][64] bf16 swz
        unsigned short* Ab1 = Ab0 + 5120;

        const float* xbase = text + ((size_t)s * 400 + fi * 80) * FTn;
        const float* Wihs = Wih + (size_t)s * FTn * G3 + w * 48 + lr;

        f4_t acc[5][3];
        #pragma unroll
        for (int a = 0; a < 5; a++)
            #pragma unroll
            for (int b = 0; b < 3; b++) acc[a][b] = (f4_t){0.f, 0.f, 0.f, 0.f};

        f4_t pa[3], pb[3];
        auto aload = [&](int kk) {
            #pragma unroll
            for (int q = 0; q < 3; ++q) {
                int c = tid + q * 256;
                if (q < 2 || tid < 128) {
                    int row = c >> 3, slot = c & 7;
                    const float* p = xbase + (size_t)row * FTn + kk * 64 + slot * 8;
                    pa[q] = *(const f4_t*)p; pb[q] = *(const f4_t*)(p + 4);
                }
            }
        };
        auto awrite = [&](unsigned short* buf) {
            #pragma unroll
            for (int q = 0; q < 3; ++q) {
                int c = tid + q * 256;
                if (q < 2 || tid < 128) {
                    int row = c >> 3, slot = c & 7;
                    uint4 uu = { cvtpk(pa[q][0], pa[q][1]), cvtpk(pa[q][2], pa[q][3]),
                                 cvtpk(pb[q][0], pb[q][1]), cvtpk(pb[q][2], pb[q][3]) };
                    *(uint4*)(buf + row * 64 + ((slot ^ (row & 7)) * 8)) = uu;
                }
            }
        };
        auto bload = [&](int kk, int ks, int nc) -> bf8_t {
            const float* bp = Wihs + (size_t)(kk * 64 + ks * 32 + kg * 8) * G3 + nc * 16;
            float b0 = bp[0], b1 = bp[G3], b2 = bp[2 * G3], b3 = bp[3 * G3];
            float b4 = bp[4 * G3], b5 = bp[5 * G3], b6 = bp[6 * G3], b7 = bp[7 * G3];
            bfu t;
            t.u[0] = cvtpk(b0, b1); t.u[1] = cvtpk(b2, b3);
            t.u[2] = cvtpk(b4, b5); t.u[3] = cvtpk(b6, b7);
            return t.v;
        };
        auto afrag = [&](const unsigned short* buf, int mt, int ks) -> bf8_t {
            int row = mt * 16 + lr;
            int slot = (ks * 4 + kg) ^ (row & 7);
            return *(const bf8_t*)(buf + row * 64 + slot * 8);
        };

        bf8_t bc[2][3], bn[2][3];
        aload(0);
        #pragma unroll
        for (int ks = 0; ks < 2; ++ks)
            #pragma unroll
            for (int nc = 0; nc < 3; ++nc) bc[ks][nc] = bload(0, ks, nc);
        awrite(Ab0);
        __syncthreads();

        for (int kk = 0; kk < 8; ++kk) {
            unsigned short* cur = (kk & 1) ? Ab1 : Ab0;
            unsigned short* nxt = (kk & 1) ? Ab0 : Ab1;
            if (kk < 7) {
                aload(kk + 1);
                #pragma unroll
                for (int ks = 0; ks < 2; ++ks)
                    #pragma unroll
                    for (int nc = 0; nc < 3; ++nc) bn[ks][nc] = bload(kk + 1, ks, nc);
            }
            #pragma unroll
            for (int ks = 0; ks < 2; ++ks)
                #pragma unroll
                for (int mt = 0; mt < 5; ++mt) {
                    bf8_t af = afrag(cur, mt, ks);
                    acc[mt][0] = __builtin_amdgcn_mfma_f32_16x16x32_bf16(af, bc[ks][0], acc[mt][0], 0, 0, 0);
                    acc[mt][1] = __builtin_amdgcn_mfma_f32_16x16x32_bf16(af, bc[ks][1], acc[mt][1], 0, 0, 0);
                    acc[mt][2] = __builtin_amdgcn_mfma_f32_16x16x32_bf16(af, bc[ks][2], acc[mt][2], 0, 0, 0);
                }
            if (kk < 7) awrite(nxt);
            __syncthreads();
            #pragma unroll
            for (int ks = 0; ks < 2; ++ks)
                #pragma unroll
                for (int nc = 0; nc < 3; ++nc) bc[ks][nc] = bn[ks][nc];
        }

        const float* bihs = bih + (size_t)s * G3 + w * 48 + lr;
        #pragma unroll
        for (int nc = 0; nc < 3; ++nc) {
            const int col = w * 48 + nc * 16 + lr;
            const float bv = bihs[nc * 16];
            #pragma unroll
            for (int mt = 0; mt < 5; ++mt)
                #pragma unroll
                for (int rg = 0; rg < 4; ++rg) {
                    int r = mt * 16 + kg * 4 + rg;      // 0..79
                    int hi = (r >= 40);
                    int day = fi * 2 + hi;
                    int t = r - hi * 40;
                    gi2[((size_t)(s * 40 + t) * 10 + day) * 192 + col] = acc[mt][nc][rg] + bv;
                }
        }
    } else {
        // ================= bilinear eighth =================
        const int s = grp, kq = sub - 5;                  // kq in [0,8)
        float* uT = (float*)sm;                           // [64][9] pad
        const int j4 = (l & 15) * 4;
        f4_t xq = *(const f4_t*)&xprice[s * Hn + j4];

        const float* Wbs = Wb + (size_t)s * Hn * Hn * Hn;
        for (int g = 0; g < 32; ++g) {
            int P = kq * 512 + g * 16 + w * 4 + (l >> 4);  // P = k*64 + i
            f4_t wv = *(const f4_t*)&Wbs[(size_t)P * Hn + j4];
            float dp = wv[0] * xq[0] + wv[1] * xq[1] + wv[2] * xq[2] + wv[3] * xq[3];
            dp += __shfl_xor(dp, 8);
            dp += __shfl_xor(dp, 4);
            dp += __shfl_xor(dp, 2);
            dp += __shfl_xor(dp, 1);
            if ((l & 15) == 0) { int k = P >> 6, i = P & 63; uT[i * 9 + (k - kq * 8)] = dp; }
        }
        __syncthreads();
        #pragma unroll
        for (int r = 0; r < 2; ++r) {
            int flat = tid + r * 256;                      // [0,512)
            int kL = flat >> 6, i = flat & 63;
            u[((size_t)s * 64 + kq * 8 + kL) * 64 + i] = uT[i * 9 + kL];
        }
    }
}

// ---------------------------------------------------------------------------
// gru_text_f: text GRU recurrence, 10 days batched in MFMA M-dim; Whh in
// VGPRs; fused online-softmax pooling -> news. Zero block barriers.
// ---------------------------------------------------------------------------
__global__ __launch_bounds__(64, 1) void gru_text_f(
    const float* __restrict__ gi2, const float* __restrict__ Whh,
    const float* __restrict__ bhh, const float* __restrict__ Wa,
    const float* __restrict__ va, float* __restrict__ news)
{
    __shared__ __align__(16) float hrow[16 * 68];
    __shared__ __align__(16) unsigned char waT[Hn * 128];

    const int s = blockIdx.x, l = threadIdx.x;
    const int lr = l & 15, lg = l >> 4;

    const float* Whhs = Whh + (size_t)s * Hn * G3;
    bfu bwhh[2][12];
    #pragma unroll
    for (int ks = 0; ks < 2; ++ks)
        #pragma unroll
        for (int nt = 0; nt < 12; ++nt) {
            const float* p = Whhs + (size_t)(ks * 32 + lg * 8) * G3 + nt * 16 + lr;
            float b0 = p[0], b1 = p[G3], b2 = p[2 * G3], b3 = p[3 * G3];
            float b4 = p[4 * G3], b5 = p[5 * G3], b6 = p[6 * G3], b7 = p[7 * G3];
            bwhh[ks][nt].u[0] = cvtpk(b0, b1); bwhh[ks][nt].u[1] = cvtpk(b2, b3);
            bwhh[ks][nt].u[2] = cvtpk(b4, b5); bwhh[ks][nt].u[3] = cvtpk(b6, b7);
        }
    float bhh_l[12];
    #pragma unroll
    for (int nt = 0; nt < 12; ++nt) bhh_l[nt] = bhh[(size_t)s * G3 + nt * 16 + lr];
    float va_l[4];
    #pragma unroll
    for (int nt = 0; nt < 4; ++nt) va_l[nt] = va[(size_t)s * Hn + nt * 16 + lr];

    {
        const float* Was = Wa + (size_t)s * Hn * Hn;
        for (int r = 0; r < 64; ++r) {
            int e = l + r * 64, i = e >> 6, k = e & 63;
            *(unsigned short*)(waT + k * 128 + ((2 * i) ^ ((k & 7) << 4))) = f2bf(Was[e]);
        }
        #pragma unroll
        for (int r = 0; r < 17; ++r) hrow[l + r * 64] = 0.f;
    }
    __builtin_amdgcn_wave_barrier();

    int dayoff[4];
    #pragma unroll
    for (int rr = 0; rr < 4; ++rr) {
        int d = lg * 4 + rr; if (d > 9) d = 9;
        dayoff[rr] = d * 192 + lr;
    }
    const float* gbase = gi2 + (size_t)s * 40 * 1920;

    float val[48], valn[48];
    #pragma unroll
    for (int j = 0; j < 48; ++j) val[j] = gbase[dayoff[j & 3] + (j >> 2) * 16];

    bf8_t a0f, a1f;
    {   bfu z0; z0.u[0] = 0; z0.u[1] = 0; z0.u[2] = 0; z0.u[3] = 0; a0f = z0.v; a1f = z0.v; }

    float h[4][4], accv[4][4], den[4], m[4];
    #pragma unroll
    for (int nt = 0; nt < 4; ++nt)
        #pragma unroll
        for (int rr = 0; rr < 4; ++rr) { h[nt][rr] = 0.f; accv[nt][rr] = 0.f; }
    #pragma unroll
    for (int rr = 0; rr < 4; ++rr) { den[rr] = 0.f; m[rr] = -1e30f; }

    for (int t = 0; t < Tn; ++t) {
        f4_t acc[12];
        #pragma unroll
        for (int nt = 0; nt < 12; ++nt)
            acc[nt] = (f4_t){bhh_l[nt], bhh_l[nt], bhh_l[nt], bhh_l[nt]};
        __builtin_amdgcn_s_setprio(1);
        #pragma unroll
        for (int nt = 0; nt < 12; ++nt) {
            acc[nt] = __builtin_amdgcn_mfma_f32_16x16x32_bf16(a0f, bwhh[0][nt].v, acc[nt], 0, 0, 0);
            acc[nt] = __builtin_amdgcn_mfma_f32_16x16x32_bf16(a1f, bwhh[1][nt].v, acc[nt], 0, 0, 0);
        }
        __builtin_amdgcn_s_setprio(0);
        {
            const int tn = (t < Tn - 1) ? t + 1 : t;
            const float* gb = gbase + (size_t)tn * 1920;
            #pragma unroll
            for (int j = 0; j < 48; ++j) valn[j] = gb[dayoff[j & 3] + (j >> 2) * 16];
        }
        #pragma unroll
        for (int nt = 0; nt < 4; ++nt)
            #pragma unroll
            for (int rr = 0; rr < 4; ++rr) {
                float r = sigmoidf_(val[nt * 4 + rr] + acc[nt][rr]);
                float z = sigmoidf_(val[(nt + 4) * 4 + rr] + acc[nt + 4][rr]);
                float n = tanhf_(val[(nt + 8) * 4 + rr] + r * acc[nt + 8][rr]);
                h[nt][rr] = (1.f - z) * n + z * h[nt][rr];
            }
        __builtin_amdgcn_wave_barrier();
        #pragma unroll
        for (int rr = 0; rr < 4; ++rr) {
            int day = lg * 4 + rr;
            if (day < Dn) {
                #pragma unroll
                for (int nt = 0; nt < 4; ++nt) hrow[day * 68 + nt * 16 + lr] = h[nt][rr];
            }
        }
        __builtin_amdgcn_wave_barrier();
        {
            const float* hp = hrow + lr * 68 + lg * 8;
            f4_t x0 = *(const f4_t*)hp,        x1 = *(const f4_t*)(hp + 4);
            f4_t y0 = *(const f4_t*)(hp + 32), y1 = *(const f4_t*)(hp + 36);
            bfu t0, t1;
            t0.u[0] = cvtpk(x0[0], x0[1]); t0.u[1] = cvtpk(x0[2], x0[3]);
            t0.u[2] = cvtpk(x1[0], x1[1]); t0.u[3] = cvtpk(x1[2], x1[3]);
            t1.u[0] = cvtpk(y0[0], y0[1]); t1.u[1] = cvtpk(y0[2], y0[3]);
            t1.u[2] = cvtpk(y1[0], y1[1]); t1.u[3] = cvtpk(y1[2], y1[3]);
            a0f = t0.v; a1f = t1.v;
        }
        f4_t sc[4];
        #pragma unroll
        for (int nt = 0; nt < 4; ++nt) sc[nt] = (f4_t){0.f, 0.f, 0.f, 0.f};
        __builtin_amdgcn_s_setprio(1);
        #pragma unroll
        for (int ks = 0; ks < 2; ++ks) {
            bf8_t av = ks ? a1f : a0f;
            #pragma unroll
            for (int nt = 0; nt < 4; ++nt) {
                bf8_t bwv = *(const bf8_t*)(waT + (nt * 16 + lr) * 128
                                            + ((ks * 64 + lg * 16) ^ ((lr & 7) << 4)));
                sc[nt] = __builtin_amdgcn_mfma_f32_16x16x32_bf16(av, bwv, sc[nt], 0, 0, 0);
            }
        }
        __builtin_amdgcn_s_setprio(0);
        float pr[4];
        #pragma unroll
        for (int rr = 0; rr < 4; ++rr) {
            pr[rr] = tanhf_(sc[0][rr]) * va_l[0] + tanhf_(sc[1][rr]) * va_l[1]
                   + tanhf_(sc[2][rr]) * va_l[2] + tanhf_(sc[3][rr]) * va_l[3];
            pr[rr] += __shfl_xor(pr[rr], 1);
            pr[rr] += __shfl_xor(pr[rr], 2);
            pr[rr] += __shfl_xor(pr[rr], 4);
            pr[rr] += __shfl_xor(pr[rr], 8);
        }
        #pragma unroll
        for (int rr = 0; rr < 4; ++rr) {
            float mn = fmaxf(m[rr], pr[rr]);
            float s0 = __expf(m[rr] - mn);
            float p = __expf(pr[rr] - mn);
            den[rr] = den[rr] * s0 + p;
            #pragma unroll
            for (int nt = 0; nt < 4; ++nt)
                accv[nt][rr] = accv[nt][rr] * s0 + p * h[nt][rr];
            m[rr] = mn;
        }
        #pragma unroll
        for (int j = 0; j < 48; ++j) val[j] = valn[j];
    }
    #pragma unroll
    for (int rr = 0; rr < 4; ++rr) {
        int day = lg * 4 + rr;
        if (day < Dn) {
            float inv = 1.f / den[rr];
            #pragma unroll
            for (int nt = 0; nt < 4; ++nt)
                news[((size_t)s * Dn + day) * Hn + nt * 16 + lr] = accv[nt][rr] * inv;
        }
    }
}

// ---------------------------------------------------------------------------
// day_finish: day-sequence GRU over news -> tvec (reg), then
// combined = tanh(tvec . u + bb), then q/k/out1. One 64-thr block per stock.
// ---------------------------------------------------------------------------
__global__ __launch_bounds__(64, 1) void day_finish(
    const float* __restrict__ news,
    const float* __restrict__ Wih_s, const float* __restrict__ Whh_s,
    const float* __restrict__ bih_s, const float* __restrict__ bhh_s,
    const float* __restrict__ Wa_s, const float* __restrict__ va_s,
    const float* __restrict__ u, const float* __restrict__ bb,
    const float* __restrict__ Wq, const float* __restrict__ bq,
    const float* __restrict__ Wk, const float* __restrict__ bk,
    const float* __restrict__ Wbl, const float* __restrict__ bbl,
    float* __restrict__ combined, float* __restrict__ qg,
    float* __restrict__ kg, float* __restrict__ out1)
{
    __shared__ __align__(16) unsigned char sm[60928];
    unsigned char* whh2 = sm;
    unsigned char* wih2 = sm + 24576;
    unsigned char* wa2 = sm + 49152;
    float* newsL = (float*)(sm + 57600);
    float* hbuf  = (float*)(sm + 60320);

    const int s = blockIdx.x, l = threadIdx.x;
    float tvv;

    {
        const float* W2 = Whh_s + (size_t)s * Hn * G3;
        const float* X2 = Wih_s + (size_t)s * Hn * G3;
        for (int r = 0; r < 192; ++r) {
            int e = l + r * 64, i = e / G3, j = e - i * G3;
            int off = j * 128 + ((2 * i) ^ ((j & 7) << 4));
            *(unsigned short*)(whh2 + off) = f2bf(W2[e]);
            *(unsigned short*)(wih2 + off) = f2bf(X2[e]);
        }
        const float* A2 = Wa_s + (size_t)s * Hn * Hn;
        for (int r = 0; r < 64; ++r) {
            int e = l + r * 64, i = e >> 6, k = e & 63;
            *(unsigned short*)(wa2 + k * 128 + ((2 * i) ^ ((k & 7) << 4))) = f2bf(A2[e]);
        }
        #pragma unroll
        for (int d = 0; d < Dn; ++d) newsL[d * 68 + l] = news[((size_t)s * Dn + d) * Hn + l];
        hbuf[l] = 0.f;
        if (l < 4) hbuf[64 + l] = 0.f;
    }
    __builtin_amdgcn_wave_barrier();
    {
        const float bi0 = bih_s[(size_t)s * G3 + l];
        const float bi1 = bih_s[(size_t)s * G3 + 64 + l];
        const float bi2 = bih_s[(size_t)s * G3 + 128 + l];
        const float bh0 = bhh_s[(size_t)s * G3 + l];
        const float bh1 = bhh_s[(size_t)s * G3 + 64 + l];
        const float bh2 = bhh_s[(size_t)s * G3 + 128 + l];
        const float vak = va_s[(size_t)s * Hn + l];
        const int swl = (l & 7) << 4;
        float h2 = 0.f, m2 = -1e30f, den2 = 0.f, av2 = 0.f;
        for (int t = 0; t < Dn; ++t) {
            float gh0 = bh0, gh1 = bh1, gh2 = bh2;
            float gg0 = bi0, gg1 = bi1, gg2 = bi2;
            #pragma unroll
            for (int ic = 0; ic < 8; ++ic) {
                const int off = (ic * 16) ^ swl;
                f4_t hA = *(const f4_t*)&hbuf[ic * 8];
                f4_t hB = *(const f4_t*)&hbuf[ic * 8 + 4];
                f4_t nA = *(const f4_t*)&newsL[t * 68 + ic * 8];
                f4_t nB = *(const f4_t*)&newsL[t * 68 + ic * 8 + 4];
                uint4 w0 = *(const uint4*)(whh2 + l * 128 + off);
                uint4 w1 = *(const uint4*)(whh2 + (l + 64) * 128 + off);
                uint4 w2 = *(const uint4*)(whh2 + (l + 128) * 128 + off);
                uint4 x0 = *(const uint4*)(wih2 + l * 128 + off);
                uint4 x1 = *(const uint4*)(wih2 + (l + 64) * 128 + off);
                uint4 x2 = *(const uint4*)(wih2 + (l + 128) * 128 + off);
                gh0 += dot8(w0, hA, hB); gh1 += dot8(w1, hA, hB); gh2 += dot8(w2, hA, hB);
                gg0 += dot8(x0, nA, nB); gg1 += dot8(x1, nA, nB); gg2 += dot8(x2, nA, nB);
            }
            float r = sigmoidf_(gg0 + gh0);
            float z = sigmoidf_(gg1 + gh1);
            float n = tanhf_(gg2 + r * gh2);
            h2 = (1.f - z) * n + z * h2;
            __builtin_amdgcn_wave_barrier();
            hbuf[l] = h2;
            __builtin_amdgcn_wave_barrier();
            float sk = 0.f;
            #pragma unroll
            for (int ic = 0; ic < 8; ++ic) {
                const int off = (ic * 16) ^ swl;
                uint4 wv = *(const uint4*)(wa2 + l * 128 + off);
                f4_t hA = *(const f4_t*)&hbuf[ic * 8];
                f4_t hB = *(const f4_t*)&hbuf[ic * 8 + 4];
                sk += dot8(wv, hA, hB);
            }
            float term = tanhf_(sk) * vak;
            #pragma unroll
            for (int off = 32; off; off >>= 1) term += __shfl_xor(term, off);
            float mn = fmaxf(m2, term);
            float s0 = __expf(m2 - mn);
            float p = __expf(term - mn);
            den2 = den2 * s0 + p;
            av2 = av2 * s0 + p * h2;
            m2 = mn;
        }
        tvv = av2 / den2;
    }
    __builtin_amdgcn_wave_barrier();

    float* uL = (float*)sm;              // [64][65]
    float* tvL = (float*)(sm + 16640);
    float* cl  = (float*)(sm + 16960);
    tvL[l] = tvv;
    const float* ub = u + (size_t)s * 4096;
    #pragma unroll 8
    for (int i = 0; i < 64; ++i) uL[i * 65 + l] = ub[i * 64 + l];
    __builtin_amdgcn_wave_barrier();
    {
        float a = bb[s * Hn + l];
        #pragma unroll 8
        for (int i = 0; i < 64; ++i) a += tvL[i] * uL[l * 65 + i];
        float c = tanhf_(a);
        cl[l] = c;
        combined[s * Hn + l] = c;
    }
    __builtin_amdgcn_wave_barrier();
    {
        float aq = bq[l], ak = bk[l];
        for (int i = 0; i < Hn; i++) {
            float ci = cl[i];
            aq += ci * Wq[i * Hn + l];
            ak += ci * Wk[i * Hn + l];
        }
        qg[s * Hn + l] = aq; kg[s * Hn + l] = ak;
        if (l < 2) {
            float a = bbl[s * 2 + l];
            for (int i = 0; i < Hn; i++) a += cl[i] * Wbl[(size_t)s * Hn * 2 + i * 2 + l];
            out1[s * 2 + l] = tanhf_(a);
        }
    }
}

// ---------------------------------------------------------------------------
// Cross-stock MHSA + elu head + blend + softmax.
// ---------------------------------------------------------------------------
__global__ __launch_bounds__(256) void mhsa(
    const float* __restrict__ qg, const float* __restrict__ kg,
    const float* __restrict__ combined, const float* __restrict__ Wf,
    const float* __restrict__ bfp, const float* __restrict__ out1,
    float* __restrict__ dout)
{
    __shared__ __align__(16) float ql[Hn];
    __shared__ float sl[NHn][Sn];
    __shared__ float hsum[NHn];
    __shared__ float ao[Hn];
    __shared__ float red2[8];
    __shared__ float red3[4][Hn];

    const int sq = blockIdx.x, tid = threadIdx.x;
    if (tid < Hn) ql[tid] = qg[sq * Hn + tid];
    __syncthreads();

    for (int id = tid; id < Sn * NHn; id += 256) {
        int t = id >> 2, h = id & 3;
        const float* kp = &kg[t * Hn + h * 16];
        float a = 0.f;
        #pragma unroll
        for (int x = 0; x < 16; x += 4) {
            f4_t kv = *(const f4_t*)&kp[x];
            f4_t qv = *(const f4_t*)&ql[h * 16 + x];
            a += kv[0] * qv[0] + kv[1] * qv[1] + kv[2] * qv[2] + kv[3] * qv[3];
        }
        sl[h][t] = a * 0.25f;
    }
    __syncthreads();
    for (int h = 0; h < NHn; ++h) {
        float m = -1e30f;
        for (int t = tid; t < Sn; t += 256) m = fmaxf(m, sl[h][t]);
        for (int o = 32; o; o >>= 1) m = fmaxf(m, __shfl_xor(m, o));
        if ((tid & 63) == 0) red2[tid >> 6] = m;
        __syncthreads();
        m = fmaxf(fmaxf(red2[0], red2[1]), fmaxf(red2[2], red2[3]));
        float ps = 0.f;
        for (int t = tid; t < Sn; t += 256) { float p = __expf(sl[h][t] - m); sl[h][t] = p; ps += p; }
        for (int o = 32; o; o >>= 1) ps += __shfl_xor(ps, o);
        if ((tid & 63) == 0) red2[4 + (tid >> 6)] = ps;
        __syncthreads();
        if (tid == 0) hsum[h] = red2[4] + red2[5] + red2[6] + red2[7];
        __syncthreads();
    }
    {
        const int q = tid >> 6, j = tid & 63, h = j >> 4;
        float a = 0.f;
        for (int t = q * 125; t < q * 125 + 125; ++t) a += sl[h][t] * combined[t * Hn + j];
        red3[q][j] = a;
    }
    __syncthreads();
    if (tid < Hn)
        ao[tid] = (red3[0][tid] + red3[1][tid] + red3[2][tid] + red3[3][tid]) / hsum[tid >> 4];
    __syncthreads();
    if (tid == 0) {
        float l0 = bfp[0], l1 = bfp[1];
        for (int j = 0; j < Hn; j++) { float v = ao[j]; l0 += v * Wf[j * 2]; l1 += v * Wf[j * 2 + 1]; }
        l0 = l0 > 0.f ? l0 : __expf(l0) - 1.f;
        l1 = l1 > 0.f ? l1 : __expf(l1) - 1.f;
        l0 += out1[sq * 2]; l1 += out1[sq * 2 + 1];
        float m = fmaxf(l0, l1);
        float e0 = __expf(l0 - m), e1 = __expf(l1 - m);
        float inv = 1.f / (e0 + e1);
        dout[1 + sq * 2] = e0 * inv;
        dout[2 + sq * 2] = e1 * inv;
    }
}

__global__ __launch_bounds__(512) void loss_k(float* __restrict__ dout,
                                              const int* __restrict__ label)
{
    __shared__ float red[512];
    const int tid = threadIdx.x;
    float a = 0.f;
    if (tid < Sn) {
        float p0 = dout[1 + 2 * tid], p1 = dout[2 + 2 * tid];
        float m = fmaxf(p0, p1);
        float lse = m + __logf(__expf(p0 - m) + __expf(p1 - m));
        float pl = label[tid] ? p1 : p0;
        a = -(pl - lse);
    }
    red[tid] = a;
    __syncthreads();
    for (int o = 256; o; o >>= 1) {
        if (tid < o) red[tid] += red[tid + o];
        __syncthreads();
    }
    if (tid == 0) dout[0] = red[0] / (float)Sn;
}

extern "C" void kernel_launch(void* const* d_in, const int* in_sizes, int n_in,
                              void* d_out, int out_size, void* d_ws, size_t ws_size,
                              hipStream_t stream)
{
    const float* text  = (const float*)d_in[0];
    const float* price = (const float*)d_in[1];
    const int*   label = (const int*)  d_in[2];
    const float* Wih_p = (const float*)d_in[5];
    const float* Whh_p = (const float*)d_in[6];
    const float* bih_p = (const float*)d_in[7];
    const float* bhh_p = (const float*)d_in[8];
    const float* Wa_p  = (const float*)d_in[9];
    const float* va_p  = (const float*)d_in[10];
    const float* Wih_t = (const float*)d_in[11];
    const float* Whh_t = (const float*)d_in[12];
    const float* bih_t = (const float*)d_in[13];
    const float* bhh_t = (const float*)d_in[14];
    const float* Wa_t  = (const float*)d_in[15];
    const float* va_t  = (const float*)d_in[16];
    const float* Wih_s = (const float*)d_in[17];
    const float* Whh_s = (const float*)d_in[18];
    const float* bih_s = (const float*)d_in[19];
    const float* bhh_s = (const float*)d_in[20];
    const float* Wa_s  = (const float*)d_in[21];
    const float* va_s  = (const float*)d_in[22];
    const float* Wb    = (const float*)d_in[23];
    const float* bb    = (const float*)d_in[24];
    const float* Wbl   = (const float*)d_in[25];
    const float* bbl   = (const float*)d_in[26];
    const float* Wq    = (const float*)d_in[27];
    const float* bq    = (const float*)d_in[28];
    const float* Wk    = (const float*)d_in[29];
    const float* bk    = (const float*)d_in[30];
    const float* Wf    = (const float*)d_in[31];
    const float* bf_   = (const float*)d_in[32];

    float* ws = (float*)d_ws;
    float* news     = ws;              // 320000
    float* xprice   = ws + 320000;     // 32000
    float* combined = ws + 384000;     // 32000
    float* qg       = ws + 416000;     // 32000
    float* kg       = ws + 448000;     // 32000
    float* out1     = ws + 480000;     // 1000
    float* u        = ws + 481000;     // 2,048,000 (8.2 MB)
    float* gi2      = ws + 2529000;    // 38,400,000 (153.6 MB)
    float* dout = (float*)d_out;

    price_gru<<<Sn, 64, 0, stream>>>(price, Wih_p, Whh_p, bih_p, bhh_p, Wa_p, va_p, xprice);
    mega_fused<<<6500, 256, 0, stream>>>(text, Wih_t, bih_t, gi2, Wb, xprice, u);
    gru_text_f<<<Sn, 64, 0, stream>>>(gi2, Whh_t, bhh_t, Wa_t, va_t, news);
    day_finish<<<Sn, 64, 0, stream>>>(news,
                                      Wih_s, Whh_s, bih_s, bhh_s, Wa_s, va_s,
                                      u, bb, Wq, bq, Wk, bk, Wbl, bbl,
                                      combined, qg, kg, out1);
    mhsa<<<Sn, 256, 0, stream>>>(qg, kg, combined, Wf, bf_, out1, dout);
    loss_k<<<1, 512, 0, stream>>>(dout, label);
}